// Round 3
// baseline (718.889 us; speedup 1.0000x reference)
//
#include <hip/hip_runtime.h>
#include <hip/hip_bf16.h>

using bf16_t = __bf16;
typedef __bf16 bf16x8 __attribute__((ext_vector_type(8)));
typedef __bf16 bf16x4 __attribute__((ext_vector_type(4)));
typedef __bf16 bf16x2 __attribute__((ext_vector_type(2)));
typedef float  f32x4  __attribute__((ext_vector_type(4)));
typedef float  f32x16 __attribute__((ext_vector_type(16)));
typedef unsigned u32x4 __attribute__((ext_vector_type(4)));

#define MFMA16(a,b,c) __builtin_amdgcn_mfma_f32_16x16x32_bf16((a),(b),(c),0,0,0)
#define MFMA32(a,b,c) __builtin_amdgcn_mfma_f32_32x32x16_bf16((a),(b),(c),0,0,0)

__device__ __forceinline__ void load_lds16(const void* g, void* l) {
  __builtin_amdgcn_global_load_lds(
      (const __attribute__((address_space(1))) unsigned int*)g,
      (__attribute__((address_space(3))) unsigned int*)l, 16, 0, 0);
}

__device__ __forceinline__ unsigned pack_bf16(float a, float b) {
  union { bf16x2 v; unsigned u; } c;
  c.v[0] = (bf16_t)a; c.v[1] = (bf16_t)b;
  return c.u;
}

__device__ __forceinline__ float fast_exp2(float x) {
#if __has_builtin(__builtin_amdgcn_exp2f)
  return __builtin_amdgcn_exp2f(x);
#else
  return exp2f(x);
#endif
}

// ---------------------------------------------------------------------------
// fp32 -> bf16 elementwise convert (x). 4 elems/thread.
// ---------------------------------------------------------------------------
__global__ __launch_bounds__(256) void cvt_f2b(const float* __restrict__ in,
                                               bf16_t* __restrict__ out)
{
  const size_t i = ((size_t)blockIdx.x * 256 + threadIdx.x) * 4;
  f32x4 d = *(const f32x4*)(in + i);
  bf16x4 o;
#pragma unroll
  for (int j = 0; j < 4; ++j) o[j] = (bf16_t)d[j];
  *(bf16x4*)(out + i) = o;
}

// ---------------------------------------------------------------------------
// fp32 [R][C] -> bf16 [C][R] transposed convert (weights). 64x64 LDS tile.
// ---------------------------------------------------------------------------
__global__ __launch_bounds__(256) void cvt_transpose(const float* __restrict__ in,
                                                     bf16_t* __restrict__ out,
                                                     int R, int C)
{
  __shared__ __align__(16) bf16_t t[64 * 80];
  const int r0 = blockIdx.y * 64, c0 = blockIdx.x * 64;
  const int rr = threadIdx.x >> 4;          // 0..15
  const int c4 = (threadIdx.x & 15) * 4;    // 0..60
#pragma unroll
  for (int i = 0; i < 4; ++i) {
    const int r = rr + i * 16;
    f32x4 d = *(const f32x4*)(in + (size_t)(r0 + r) * C + c0 + c4);
#pragma unroll
    for (int j = 0; j < 4; ++j) t[(c4 + j) * 80 + r] = (bf16_t)d[j];
  }
  __syncthreads();
  const int a  = threadIdx.x >> 3;          // 0..31
  const int bc = (threadIdx.x & 7) * 8;
#pragma unroll
  for (int half = 0; half < 2; ++half) {
    const int cc = a + half * 32;
    bf16x8 d = *(const bf16x8*)&t[cc * 80 + bc];
    *(bf16x8*)(out + (size_t)(c0 + cc) * R + r0 + bc) = d;
  }
}

// ---------------------------------------------------------------------------
// m97-class GEMM: C[M,N] = A[M,K] @ B[K,N] (+scale), B given as BT[N,K].
// 128x128 tile, BK=32, 4 waves each 64x64 (4x4 of 16x16x32 MFMA).
// ---------------------------------------------------------------------------
template <typename OutT>
__global__ __launch_bounds__(256) void gemm128(const bf16_t* __restrict__ A,
                                               const bf16_t* __restrict__ BT,
                                               OutT* __restrict__ C,
                                               int M, int N, int K, float scale,
                                               long long zB, long long zC)
{
  __shared__ __align__(16) bf16_t As[128 * 32];
  __shared__ __align__(16) bf16_t Bs[128 * 32];
  const int tid = threadIdx.x;
  BT += (size_t)blockIdx.z * zB;
  C  += (size_t)blockIdx.z * zC;
  const int m0 = blockIdx.y * 128, n0 = blockIdx.x * 128;
  const int lane = tid & 63, w = tid >> 6;
  const int quad = lane >> 4, l15 = lane & 15;
  const int wm = (w >> 1) * 64, wn = (w & 1) * 64;
  const int s_row = tid >> 2;
  const int g_off = ((tid & 3) ^ (s_row & 3)) * 8;   // swizzled global chunk
  const int quadp = (quad ^ (l15 & 3)) * 8;          // swizzled frag offset
  const bf16_t* Ap0 = A  + (size_t)(m0 + s_row) * K + g_off;
  const bf16_t* Ap1 = A  + (size_t)(m0 + 64 + s_row) * K + g_off;
  const bf16_t* Bp0 = BT + (size_t)(n0 + s_row) * K + g_off;
  const bf16_t* Bp1 = BT + (size_t)(n0 + 64 + s_row) * K + g_off;

  f32x4 acc[4][4] = {};

  for (int k0 = 0; k0 < K; k0 += 32) {
    __syncthreads();
    load_lds16(Ap0 + k0, As + tid * 8);
    load_lds16(Ap1 + k0, As + tid * 8 + 2048);
    load_lds16(Bp0 + k0, Bs + tid * 8);
    load_lds16(Bp1 + k0, Bs + tid * 8 + 2048);
    __syncthreads();
    bf16x8 af[4], bfr[4];
#pragma unroll
    for (int fi = 0; fi < 4; ++fi)
      af[fi] = *(const bf16x8*)&As[(wm + fi * 16 + l15) * 32 + quadp];
#pragma unroll
    for (int fj = 0; fj < 4; ++fj)
      bfr[fj] = *(const bf16x8*)&Bs[(wn + fj * 16 + l15) * 32 + quadp];
#pragma unroll
    for (int fi = 0; fi < 4; ++fi)
#pragma unroll
      for (int fj = 0; fj < 4; ++fj)
        acc[fi][fj] = MFMA16(af[fi], bfr[fj], acc[fi][fj]);
  }

#pragma unroll
  for (int fi = 0; fi < 4; ++fi)
#pragma unroll
    for (int fj = 0; fj < 4; ++fj)
#pragma unroll
      for (int r = 0; r < 4; ++r) {
        const int row = m0 + wm + fi * 16 + quad * 4 + r;
        const int col = n0 + wn + fj * 16 + l15;
        C[(size_t)row * N + col] = (OutT)(acc[fi][fj][r] * scale);
      }
}

// ---------------------------------------------------------------------------
// latent_prev fp32 (2,2048,512) -> bf16 latent rows [0,2048) of (2,4096,512)
// ---------------------------------------------------------------------------
__global__ __launch_bounds__(256) void copy_prev_f(const float* __restrict__ prev,
                                                   bf16_t* __restrict__ latent)
{
  const size_t v    = (size_t)blockIdx.x * 256 + threadIdx.x;
  const size_t flat = v * 4;
  const size_t per  = (size_t)2048 * 512;
  const size_t b    = flat / per, rem = flat % per;
  f32x4 d = *(const f32x4*)(prev + flat);
  bf16x4 o;
#pragma unroll
  for (int j = 0; j < 4; ++j) o[j] = (bf16_t)d[j];
  *(bf16x4*)(latent + b * ((size_t)4096 * 512) + rem) = o;
}

// ---------------------------------------------------------------------------
// LayerNorm over 512 (fp32 stats), bf16 in, fp32 g/b, bf16 out into latent
// rows [2048,4096).
// ---------------------------------------------------------------------------
__global__ __launch_bounds__(256) void ln_kernel(const bf16_t* __restrict__ in,
                                                 const float* __restrict__ g_,
                                                 const float* __restrict__ b_,
                                                 bf16_t* __restrict__ latent)
{
  const int row = blockIdx.x;             // 0..4095 (= b*2048 + t)
  const int tid = threadIdx.x;
  const float x0 = (float)in[(size_t)row * 512 + tid];
  const float x1 = (float)in[(size_t)row * 512 + 256 + tid];
  float s  = x0 + x1;
  float sq = x0 * x0 + x1 * x1;
#pragma unroll
  for (int off = 1; off < 64; off <<= 1) {
    s  += __shfl_xor(s, off);
    sq += __shfl_xor(sq, off);
  }
  __shared__ float red[8];
  const int w = tid >> 6;
  if ((tid & 63) == 0) { red[w] = s; red[4 + w] = sq; }
  __syncthreads();
  s  = red[0] + red[1] + red[2] + red[3];
  sq = red[4] + red[5] + red[6] + red[7];
  const float mu   = s * (1.0f / 512.0f);
  const float var  = sq * (1.0f / 512.0f) - mu * mu;
  const float rstd = rsqrtf(var + 1e-5f);
  const int b = row >> 11, tt = row & 2047;
  bf16_t* outp = latent + ((size_t)b * 4096 + 2048 + tt) * 512;
  outp[tid]       = (bf16_t)((x0 - mu) * rstd * g_[tid]       + b_[tid]);
  outp[tid + 256] = (bf16_t)((x1 - mu) * rstd * g_[tid + 256] + b_[tid + 256]);
}

// ---------------------------------------------------------------------------
// Flash attention v4. 4 waves; per-lane query column; K staged (dbuf LDS),
// V read DIRECT from global (L2-resident; staged layout decoded to
//   vT[feat=ft*32+l31][s0+kc*16+h5*8], 1-deep software pipeline).
// SPLIT: key range split in two equal-tile halves; partials (o/l bf16, m/l
// f32) written per half; combined by attn_combine. Grid is XCD-swizzled so
// each XCD owns 2 heads (K/V working set = 4MB = L2). Non-SPLIT fallback
// processes the full range and writes normalized output directly.
// Softmax in log2 domain; defer-max THR=8; tree max; setprio on MFMA.
// LDS: K dbuf = 2*8192 elems; epilogue overlay needs 17408 elems (34.8KB).
// ---------------------------------------------------------------------------
template <bool SPLIT>
__global__ __launch_bounds__(256, 3) void attn4(const bf16_t* q,
                                                const bf16_t* k,
                                                const bf16_t* vT,
                                                bf16_t* out0, bf16_t* out1,
                                                float2* ml)
{
  __shared__ __align__(16) bf16_t smem[17408];      // Ks0|Ks1 + epilogue

  const int tid = threadIdx.x;
  const int lane = tid & 63, w = tid >> 6;
  const int l31 = lane & 31, h5 = lane >> 5;

  int qt, h, b, half;
  if (SPLIT) {
    // XCD-swizzle: 1024 blocks; XCD g owns heads {g, g+8}.
    const int g = blockIdx.x & 7, j = blockIdx.x >> 3;
    h = g + 8 * (j >> 6);
    const int r = j & 63;
    qt = r & 15;
    b  = (r >> 4) & 1;
    half = r >> 5;
  } else {
    qt = blockIdx.x & 15;
    h  = (blockIdx.x >> 4) & 15;
    b  = blockIdx.x >> 8;
    if (b) qt = 15 - qt;                            // balance pairing
    half = 0;
  }
  const int q0 = qt * 128;
  const int qg = q0 + l31 * 4 + w;                  // this lane's query row
  const int qlim = 2048 + q0;

  const int ntot = 34 + 2 * qt;                     // 64-key tiles (even)
  const int nt0  = SPLIT ? (ntot >> 1) : ntot;
  const int tbeg = (SPLIT && half) ? nt0 : 0;
  const int tend = (SPLIT && !half) ? nt0 : ntot;

  // Q^T B-frags: B[k=feat fc*16+h5*8+j][n=q l31]
  bf16x8 qf[8];
  const bf16_t* qb = q + ((size_t)(b * 2048 + qg)) * 2048 + h * 128 + h5 * 8;
#pragma unroll
  for (int fc = 0; fc < 8; ++fc) qf[fc] = *(const bf16x8*)(qb + fc * 16);

  const bf16_t* kbase = k + ((size_t)b * 4096) * 2048 + h * 128;
  const bf16_t* vbase = vT + ((size_t)(b * 16 + h)) * 128 * 4096;
  const bf16_t* vlane = vbase + (size_t)l31 * 4096 + h5 * 8;

  // K staging map (slot = tid + 256p): tile layout [64 key][128 feat], chunk swz
  int ks_key[4], ks_go[4];
#pragma unroll
  for (int p = 0; p < 4; ++p) {
    const int slot = tid + 256 * p;
    const int key = slot >> 4, ph = slot & 15;
    ks_key[p] = key;
    ks_go[p]  = (((ph & 8) | ((ph & 7) ^ (key & 7)))) * 8;
  }
  // K frag read offsets (elems)
  int kfo[8];
#pragma unroll
  for (int fc = 0; fc < 8; ++fc) {
    const int L = fc * 2 + h5;
    kfo[fc] = l31 * 128 + ((L & 8) | ((L & 7) ^ (l31 & 7))) * 8;
  }

  f32x16 o[4] = {};
  float m = -1e30f, l = 0.f;

  // prologue: stage K tile tbeg into buffer 0
#pragma unroll
  for (int p = 0; p < 4; ++p)
    load_lds16(kbase + ((size_t)tbeg * 64 + ks_key[p]) * 2048 + ks_go[p],
               smem + (tid + 256 * p) * 8);
  __syncthreads();

  int cur = 0;
  for (int ti = tbeg; ti < tend; ++ti) {
    const int s0 = ti * 64;
    // stage next K tile into other buffer (DMA overlaps compute)
    if (ti + 1 < tend) {
      const int nxt = (cur ^ 1) * 8192;
#pragma unroll
      for (int p = 0; p < 4; ++p)
        load_lds16(kbase + ((size_t)(s0 + 64) + ks_key[p]) * 2048 + ks_go[p],
                   smem + nxt + (tid + 256 * p) * 8);
    }
    const bf16_t* Kc = smem + cur * 8192;

    // S^T tiles: rows = keys 32t + (i&3)+8*(i>>2)+4*h5, col = q = l31
    f32x16 st[2] = {};
    __builtin_amdgcn_s_setprio(1);
#pragma unroll
    for (int fc = 0; fc < 8; ++fc) {
      bf16x8 k0 = *(const bf16x8*)&Kc[kfo[fc]];
      bf16x8 k1 = *(const bf16x8*)&Kc[4096 + kfo[fc]];
      st[0] = MFMA32(k0, qf[fc], st[0]);
      st[1] = MFMA32(k1, qf[fc], st[1]);
    }
    __builtin_amdgcn_s_setprio(0);

    if (s0 + 63 > qlim) {                           // causal tail masking
#pragma unroll
      for (int t = 0; t < 2; ++t)
#pragma unroll
        for (int i = 0; i < 16; ++i) {
          const int key = s0 + 32 * t + (i & 3) + 8 * (i >> 2) + 4 * h5;
          if (key > 2048 + qg) st[t][i] = -1e30f;
        }
    }

    // tree max over this lane's 32 scores (depth 5)
    float gm[8];
#pragma unroll
    for (int t = 0; t < 2; ++t)
#pragma unroll
      for (int g = 0; g < 4; ++g)
        gm[t * 4 + g] = fmaxf(fmaxf(st[t][4 * g + 0], st[t][4 * g + 1]),
                              fmaxf(st[t][4 * g + 2], st[t][4 * g + 3]));
    float mt = fmaxf(fmaxf(fmaxf(gm[0], gm[1]), fmaxf(gm[2], gm[3])),
                     fmaxf(fmaxf(gm[4], gm[5]), fmaxf(gm[6], gm[7])));
    mt = fmaxf(mt, __shfl_xor(mt, 32));

    // defer-max: only rescale when max grew by >8 (log2 domain; p <= 2^8)
    if (__any(mt > m + 8.f)) {
      const float mnew = fmaxf(m, mt);
      const float alpha = fast_exp2(m - mnew);
#pragma unroll
      for (int ft = 0; ft < 4; ++ft)
#pragma unroll
        for (int i = 0; i < 16; ++i) o[ft][i] *= alpha;
      l *= alpha;
      m = mnew;
    }

    // V frag batch 0 (keys s0+h5*8..+8) — hides L2 latency under exp/pack
    bf16x8 vfrag[4][4];
#pragma unroll
    for (int ft = 0; ft < 4; ++ft)
      vfrag[0][ft] = *(const bf16x8*)(vlane + (size_t)ft * 131072 + s0);

    // exp2 + pack P; group g holds keys 32t + 8g + 4h5 + 0..3
    float rs = 0.f;
    unsigned up[2][4][2];
#pragma unroll
    for (int t = 0; t < 2; ++t)
#pragma unroll
      for (int g = 0; g < 4; ++g) {
        const float p0 = fast_exp2(st[t][4 * g + 0] - m);
        const float p1 = fast_exp2(st[t][4 * g + 1] - m);
        const float p2 = fast_exp2(st[t][4 * g + 2] - m);
        const float p3 = fast_exp2(st[t][4 * g + 3] - m);
        rs += (p0 + p1) + (p2 + p3);
        up[t][g][0] = pack_bf16(p0, p1);
        up[t][g][1] = pack_bf16(p2, p3);
      }
    rs += __shfl_xor(rs, 32);
    l += rs;

    // out^T += V^T · P^T ; P^T via half-exchange; V 1-deep pipelined
#pragma unroll
    for (int kc = 0; kc < 4; ++kc) {
      if (kc < 3) {
#pragma unroll
        for (int ft = 0; ft < 4; ++ft)
          vfrag[kc + 1][ft] =
              *(const bf16x8*)(vlane + (size_t)ft * 131072 + s0 + (kc + 1) * 16);
      }
      const int t = kc >> 1, gp = (kc & 1) * 2;
      const unsigned a0 = up[t][gp][0],     a1 = up[t][gp][1];
      const unsigned b0 = up[t][gp + 1][0], b1 = up[t][gp + 1][1];
      const unsigned xa0 = __shfl_xor(a0, 32), xa1 = __shfl_xor(a1, 32);
      const unsigned xb0 = __shfl_xor(b0, 32), xb1 = __shfl_xor(b1, 32);
      u32x4 uw;
      uw[0] = h5 ? xb0 : a0;
      uw[1] = h5 ? xb1 : a1;
      uw[2] = h5 ? b0 : xa0;
      uw[3] = h5 ? b1 : xa1;
      union { u32x4 u; bf16x8 v; } pc; pc.u = uw;
      const bf16x8 pf = pc.v;
      __builtin_amdgcn_s_setprio(1);
#pragma unroll
      for (int ft = 0; ft < 4; ++ft)
        o[ft] = MFMA32(vfrag[kc][ft], pf, o[ft]);
      __builtin_amdgcn_s_setprio(0);
    }

    __syncthreads();   // K reads done + next-tile DMA drained
    cur ^= 1;
  }

  // epilogue: normalize by own l, LDS transpose, coalesced store
  bf16_t* const outp = (SPLIT && half) ? out1 : out0;
  const float inv = 1.0f / l;
  const int rowp_w = w * 32 + l31;
#pragma unroll
  for (int ft = 0; ft < 4; ++ft)
#pragma unroll
    for (int g = 0; g < 4; ++g) {
      bf16x4 pk;
#pragma unroll
      for (int r = 0; r < 4; ++r) pk[r] = (bf16_t)(o[ft][4 * g + r] * inv);
      *(bf16x4*)&smem[rowp_w * 136 + ft * 32 + g * 8 + h5 * 4] = pk;
    }
  if (SPLIT && h5 == 0)
    ml[((size_t)((half * 2 + b) * 16 + h)) * 2048 + qg] = make_float2(m, l);
  __syncthreads();
#pragma unroll
  for (int p = 0; p < 8; ++p) {
    const int c = tid + 256 * p;
    const int rowp = c >> 4, chk = c & 15;
    const int ql = (rowp & 31) * 4 + (rowp >> 5);
    bf16x8 d = *(const bf16x8*)&smem[rowp * 136 + chk * 8];
    *(bf16x8*)(outp + ((size_t)(b * 2048 + q0 + ql)) * 2048 + h * 128 + chk * 8) = d;
  }
}

// ---------------------------------------------------------------------------
// Combine the two split-K halves: out = (w0*o0 + w1*o1)/(w0+w1),
// wi = li * 2^(mi - M). In-place on o0 (aout).
// ---------------------------------------------------------------------------
__global__ __launch_bounds__(256) void attn_combine(bf16_t* o0,
                                                    const bf16_t* o1,
                                                    const float2* ml)
{
  const int row = blockIdx.x;             // b*2048 + t
  const int tid = threadIdx.x;
  const int b = row >> 11, t = row & 2047;
  const int h = tid >> 4;
  const float2 v0 = ml[((size_t)(b * 16 + h)) * 2048 + t];
  const float2 v1 = ml[((size_t)((2 + b) * 16 + h)) * 2048 + t];
  const float M  = fmaxf(v0.x, v1.x);
  const float w0 = v0.y * fast_exp2(v0.x - M);
  const float w1 = v1.y * fast_exp2(v1.x - M);
  const float inv = 1.0f / (w0 + w1);
  const float a0 = w0 * inv, a1 = w1 * inv;
  const size_t base = (size_t)row * 2048 + tid * 8;
  bf16x8 x0 = *(const bf16x8*)(o0 + base);
  bf16x8 x1 = *(const bf16x8*)(o1 + base);
  bf16x8 r;
#pragma unroll
  for (int j = 0; j < 8; ++j)
    r[j] = (bf16_t)(a0 * (float)x0[j] + a1 * (float)x1[j]);
  *(bf16x8*)(o0 + base) = r;
}

// ---------------------------------------------------------------------------
extern "C" void kernel_launch(void* const* d_in, const int* in_sizes, int n_in,
                              void* d_out, int out_size, void* d_ws, size_t ws_size,
                              hipStream_t stream)
{
  (void)in_sizes; (void)n_in; (void)out_size;
  const float* x        = (const float*)d_in[0];
  const float* lat_prev = (const float*)d_in[1];
  const float* Wq       = (const float*)d_in[2];
  const float* Wdown    = (const float*)d_in[3];
  const float* Wk_up    = (const float*)d_in[4];
  const float* Wv_up    = (const float*)d_in[5];
  const float* ln_g     = (const float*)d_in[6];
  const float* ln_b     = (const float*)d_in[7];
  const float* Wo       = (const float*)d_in[8];
  float* out = (float*)d_out;

  char* p = (char*)d_ws;
  auto alloc = [&](size_t elems) { bf16_t* r = (bf16_t*)p; p += elems * 2; return r; };
  bf16_t* xb     = alloc((size_t)4096 * 2048);   // hosts WoT after x dead
  bf16_t* WqT    = alloc((size_t)2048 * 2048);
  bf16_t* WdT    = alloc((size_t)512 * 2048);
  bf16_t* qbuf   = alloc((size_t)4096 * 2048);
  bf16_t* latpre = alloc((size_t)4096 * 512);    // hosts WkT+WvT after LN
  bf16_t* latent = alloc((size_t)2 * 4096 * 512);
  bf16_t* kbuf   = alloc((size_t)8192 * 2048);
  bf16_t* vTb    = alloc((size_t)2 * 2048 * 4096);
  bf16_t* aout   = alloc((size_t)4096 * 2048);
  bf16_t* opart1 = alloc((size_t)4096 * 2048);   // split-K half-1 partial
  float2* mlbuf  = (float2*)p; p += (size_t)2 * 2 * 16 * 2048 * sizeof(float2);
  const size_t needed = (size_t)(p - (char*)d_ws);
  bf16_t* WoT  = xb;
  bf16_t* WkT  = latpre;
  bf16_t* WvT  = latpre + (size_t)2048 * 512;

  const dim3 B(256);
  // 1/sqrt(128) * log2(e): attention scores land in log2 domain
  const float qscale = 0.12751744561825988f;

  cvt_f2b<<<dim3(8192), B, 0, stream>>>(x, xb);
  cvt_transpose<<<dim3(32, 32), B, 0, stream>>>(Wq,    WqT, 2048, 2048);
  cvt_transpose<<<dim3(8,  32), B, 0, stream>>>(Wdown, WdT, 2048, 512);
  // q = (x@Wq) * qscale ; latpre = x@Wdown
  gemm128<bf16_t><<<dim3(16, 32), B, 0, stream>>>(xb, WqT, qbuf, 4096, 2048, 2048, qscale, 0, 0);
  gemm128<bf16_t><<<dim3(4,  32), B, 0, stream>>>(xb, WdT, latpre, 4096, 512, 2048, 1.0f, 0, 0);
  // latent cache
  copy_prev_f<<<dim3(2048), B, 0, stream>>>(lat_prev, latent);
  ln_kernel<<<dim3(4096), B, 0, stream>>>(latpre, ln_g, ln_b, latent);
  // weight transposes into dead regions (stream order enforces lifetimes)
  cvt_transpose<<<dim3(32, 32), B, 0, stream>>>(Wo,    WoT, 2048, 2048);
  cvt_transpose<<<dim3(32, 8),  B, 0, stream>>>(Wk_up, WkT, 512, 2048);
  cvt_transpose<<<dim3(32, 8),  B, 0, stream>>>(Wv_up, WvT, 512, 2048);
  // k = latent @ Wk_up  (rows b*4096+s)
  gemm128<bf16_t><<<dim3(16, 64), B, 0, stream>>>(latent, WkT, kbuf, 8192, 2048, 512, 1.0f, 0, 0);
  // vT_b = WvT @ latent_b^T  (BT = latent_b), batched over z
  gemm128<bf16_t><<<dim3(32, 16, 2), B, 0, stream>>>(WvT, latent, vTb, 2048, 4096, 512, 1.0f,
                                                     (long long)4096 * 512,
                                                     (long long)2048 * 4096);
  // attention
  if (ws_size == 0 || ws_size >= needed) {
    attn4<true><<<dim3(1024), B, 0, stream>>>(qbuf, kbuf, vTb, aout, opart1, mlbuf);
    attn_combine<<<dim3(4096), B, 0, stream>>>(aout, opart1, mlbuf);
  } else {
    attn4<false><<<dim3(512), B, 0, stream>>>(qbuf, kbuf, vTb, aout, nullptr, nullptr);
  }
  // output projection (fp32 out)
  gemm128<float><<<dim3(16, 32), B, 0, stream>>>(aout, WoT, out, 4096, 2048, 2048, 1.0f, 0, 0);
}

// Round 5
// 602.686 us; speedup vs baseline: 1.1928x; 1.1928x over previous
//
#include <hip/hip_runtime.h>
#include <hip/hip_bf16.h>

using bf16_t = __bf16;
typedef __bf16 bf16x8 __attribute__((ext_vector_type(8)));
typedef __bf16 bf16x4 __attribute__((ext_vector_type(4)));
typedef __bf16 bf16x2 __attribute__((ext_vector_type(2)));
typedef float  f32x4  __attribute__((ext_vector_type(4)));
typedef float  f32x16 __attribute__((ext_vector_type(16)));
typedef unsigned u32x4 __attribute__((ext_vector_type(4)));

#define MFMA16(a,b,c) __builtin_amdgcn_mfma_f32_16x16x32_bf16((a),(b),(c),0,0,0)
#define MFMA32(a,b,c) __builtin_amdgcn_mfma_f32_32x32x16_bf16((a),(b),(c),0,0,0)

__device__ __forceinline__ void load_lds16(const void* g, void* l) {
  __builtin_amdgcn_global_load_lds(
      (const __attribute__((address_space(1))) unsigned int*)g,
      (__attribute__((address_space(3))) unsigned int*)l, 16, 0, 0);
}

__device__ __forceinline__ unsigned pack_bf16(float a, float b) {
  union { bf16x2 v; unsigned u; } c;
  c.v[0] = (bf16_t)a; c.v[1] = (bf16_t)b;
  return c.u;
}

__device__ __forceinline__ float fast_exp2(float x) {
#if __has_builtin(__builtin_amdgcn_exp2f)
  return __builtin_amdgcn_exp2f(x);
#else
  return exp2f(x);
#endif
}

// ---------------------------------------------------------------------------
// fp32 -> bf16 elementwise convert (x). 4 elems/thread.
// ---------------------------------------------------------------------------
__global__ __launch_bounds__(256) void cvt_f2b(const float* __restrict__ in,
                                               bf16_t* __restrict__ out)
{
  const size_t i = ((size_t)blockIdx.x * 256 + threadIdx.x) * 4;
  f32x4 d = *(const f32x4*)(in + i);
  bf16x4 o;
#pragma unroll
  for (int j = 0; j < 4; ++j) o[j] = (bf16_t)d[j];
  *(bf16x4*)(out + i) = o;
}

// ---------------------------------------------------------------------------
// fp32 [R][C] -> bf16 [C][R] transposed convert (weights). 64x64 LDS tile.
// ---------------------------------------------------------------------------
__global__ __launch_bounds__(256) void cvt_transpose(const float* __restrict__ in,
                                                     bf16_t* __restrict__ out,
                                                     int R, int C)
{
  __shared__ __align__(16) bf16_t t[64 * 80];
  const int r0 = blockIdx.y * 64, c0 = blockIdx.x * 64;
  const int rr = threadIdx.x >> 4;          // 0..15
  const int c4 = (threadIdx.x & 15) * 4;    // 0..60
#pragma unroll
  for (int i = 0; i < 4; ++i) {
    const int r = rr + i * 16;
    f32x4 d = *(const f32x4*)(in + (size_t)(r0 + r) * C + c0 + c4);
#pragma unroll
    for (int j = 0; j < 4; ++j) t[(c4 + j) * 80 + r] = (bf16_t)d[j];
  }
  __syncthreads();
  const int a  = threadIdx.x >> 3;          // 0..31
  const int bc = (threadIdx.x & 7) * 8;
#pragma unroll
  for (int half = 0; half < 2; ++half) {
    const int cc = a + half * 32;
    bf16x8 d = *(const bf16x8*)&t[cc * 80 + bc];
    *(bf16x8*)(out + (size_t)(c0 + cc) * R + r0 + bc) = d;
  }
}

// ---------------------------------------------------------------------------
// m97-class GEMM: C[M,N] = A[M,K] @ B[K,N] (+scale), B given as BT[N,K].
// 128x128 tile, BK=32, 4 waves each 64x64 (4x4 of 16x16x32 MFMA).
// ---------------------------------------------------------------------------
template <typename OutT>
__global__ __launch_bounds__(256) void gemm128(const bf16_t* __restrict__ A,
                                               const bf16_t* __restrict__ BT,
                                               OutT* __restrict__ C,
                                               int M, int N, int K, float scale,
                                               long long zB, long long zC)
{
  __shared__ __align__(16) bf16_t As[128 * 32];
  __shared__ __align__(16) bf16_t Bs[128 * 32];
  const int tid = threadIdx.x;
  BT += (size_t)blockIdx.z * zB;
  C  += (size_t)blockIdx.z * zC;
  const int m0 = blockIdx.y * 128, n0 = blockIdx.x * 128;
  const int lane = tid & 63, w = tid >> 6;
  const int quad = lane >> 4, l15 = lane & 15;
  const int wm = (w >> 1) * 64, wn = (w & 1) * 64;
  const int s_row = tid >> 2;
  const int g_off = ((tid & 3) ^ (s_row & 3)) * 8;   // swizzled global chunk
  const int quadp = (quad ^ (l15 & 3)) * 8;          // swizzled frag offset
  const bf16_t* Ap0 = A  + (size_t)(m0 + s_row) * K + g_off;
  const bf16_t* Ap1 = A  + (size_t)(m0 + 64 + s_row) * K + g_off;
  const bf16_t* Bp0 = BT + (size_t)(n0 + s_row) * K + g_off;
  const bf16_t* Bp1 = BT + (size_t)(n0 + 64 + s_row) * K + g_off;

  f32x4 acc[4][4] = {};

  for (int k0 = 0; k0 < K; k0 += 32) {
    __syncthreads();
    load_lds16(Ap0 + k0, As + tid * 8);
    load_lds16(Ap1 + k0, As + tid * 8 + 2048);
    load_lds16(Bp0 + k0, Bs + tid * 8);
    load_lds16(Bp1 + k0, Bs + tid * 8 + 2048);
    __syncthreads();
    bf16x8 af[4], bfr[4];
#pragma unroll
    for (int fi = 0; fi < 4; ++fi)
      af[fi] = *(const bf16x8*)&As[(wm + fi * 16 + l15) * 32 + quadp];
#pragma unroll
    for (int fj = 0; fj < 4; ++fj)
      bfr[fj] = *(const bf16x8*)&Bs[(wn + fj * 16 + l15) * 32 + quadp];
#pragma unroll
    for (int fi = 0; fi < 4; ++fi)
#pragma unroll
      for (int fj = 0; fj < 4; ++fj)
        acc[fi][fj] = MFMA16(af[fi], bfr[fj], acc[fi][fj]);
  }

#pragma unroll
  for (int fi = 0; fi < 4; ++fi)
#pragma unroll
    for (int fj = 0; fj < 4; ++fj)
#pragma unroll
      for (int r = 0; r < 4; ++r) {
        const int row = m0 + wm + fi * 16 + quad * 4 + r;
        const int col = n0 + wn + fj * 16 + l15;
        C[(size_t)row * N + col] = (OutT)(acc[fi][fj][r] * scale);
      }
}

// ---------------------------------------------------------------------------
// latent_prev fp32 (2,2048,512) -> bf16 latent rows [0,2048) of (2,4096,512)
// ---------------------------------------------------------------------------
__global__ __launch_bounds__(256) void copy_prev_f(const float* __restrict__ prev,
                                                   bf16_t* __restrict__ latent)
{
  const size_t v    = (size_t)blockIdx.x * 256 + threadIdx.x;
  const size_t flat = v * 4;
  const size_t per  = (size_t)2048 * 512;
  const size_t b    = flat / per, rem = flat % per;
  f32x4 d = *(const f32x4*)(prev + flat);
  bf16x4 o;
#pragma unroll
  for (int j = 0; j < 4; ++j) o[j] = (bf16_t)d[j];
  *(bf16x4*)(latent + b * ((size_t)4096 * 512) + rem) = o;
}

// ---------------------------------------------------------------------------
// LayerNorm over 512 (fp32 stats), bf16 in, fp32 g/b, bf16 out into latent
// rows [2048,4096).
// ---------------------------------------------------------------------------
__global__ __launch_bounds__(256) void ln_kernel(const bf16_t* __restrict__ in,
                                                 const float* __restrict__ g_,
                                                 const float* __restrict__ b_,
                                                 bf16_t* __restrict__ latent)
{
  const int row = blockIdx.x;             // 0..4095 (= b*2048 + t)
  const int tid = threadIdx.x;
  const float x0 = (float)in[(size_t)row * 512 + tid];
  const float x1 = (float)in[(size_t)row * 512 + 256 + tid];
  float s  = x0 + x1;
  float sq = x0 * x0 + x1 * x1;
#pragma unroll
  for (int off = 1; off < 64; off <<= 1) {
    s  += __shfl_xor(s, off);
    sq += __shfl_xor(sq, off);
  }
  __shared__ float red[8];
  const int w = tid >> 6;
  if ((tid & 63) == 0) { red[w] = s; red[4 + w] = sq; }
  __syncthreads();
  s  = red[0] + red[1] + red[2] + red[3];
  sq = red[4] + red[5] + red[6] + red[7];
  const float mu   = s * (1.0f / 512.0f);
  const float var  = sq * (1.0f / 512.0f) - mu * mu;
  const float rstd = rsqrtf(var + 1e-5f);
  const int b = row >> 11, tt = row & 2047;
  bf16_t* outp = latent + ((size_t)b * 4096 + 2048 + tt) * 512;
  outp[tid]       = (bf16_t)((x0 - mu) * rstd * g_[tid]       + b_[tid]);
  outp[tid + 256] = (bf16_t)((x1 - mu) * rstd * g_[tid + 256] + b_[tid + 256]);
}

// ---------------------------------------------------------------------------
// Flash attention v5. 4 waves; per-lane query column. K double-buffered in
// LDS; V single-buffered in LDS (staged at iteration bottom, drained at the
// pre-PV barrier of the NEXT iteration, hidden under S^T+softmax).
// LDS = 48KB -> 3 blocks/CU. SPLIT: key range split in two equal-tile
// halves (1024 blocks fills the 3rd block slot); partials combined by
// attn_combine. XCD-swizzled grid: each XCD owns 2 heads (L2 locality,
// proven -75% FETCH). Softmax log2 domain; defer-max THR=8; tree max;
// setprio on MFMA clusters. All staging maps identical to the proven
// round-2 kernel. LDS elems: K0@0, K1@8192, V@16384 (8192), total 24576.
// ---------------------------------------------------------------------------
template <bool SPLIT>
__global__ __launch_bounds__(256) void attn5(const bf16_t* q,
                                             const bf16_t* k,
                                             const bf16_t* vT,
                                             bf16_t* out0, bf16_t* out1,
                                             float2* ml)
{
  __shared__ __align__(16) bf16_t smem[24576];      // K0|K1|V + epilogue overlay

  const int tid = threadIdx.x;
  const int lane = tid & 63, w = tid >> 6;
  const int l31 = lane & 31, h5 = lane >> 5;

  int qt, h, b, half;
  if (SPLIT) {
    // XCD-swizzle: 1024 blocks; XCD g owns heads {g, g+8}.
    const int g = blockIdx.x & 7, j = blockIdx.x >> 3;
    h = g + 8 * (j >> 6);
    const int r = j & 63;
    qt = r & 15;
    b  = (r >> 4) & 1;
    half = r >> 5;
  } else {
    qt = blockIdx.x & 15;
    h  = (blockIdx.x >> 4) & 15;
    b  = blockIdx.x >> 8;
    if (b) qt = 15 - qt;                            // balance pairing
    half = 0;
  }
  const int q0 = qt * 128;
  const int qg = q0 + l31 * 4 + w;                  // this lane's query row
  const int qlim = 2048 + q0;

  const int ntot = 34 + 2 * qt;                     // 64-key tiles (even)
  const int nt0  = SPLIT ? (ntot >> 1) : ntot;
  const int tbeg = (SPLIT && half) ? nt0 : 0;
  const int tend = (SPLIT && !half) ? nt0 : ntot;

  // Q^T B-frags: B[k=feat fc*16+h5*8+j][n=q l31]
  bf16x8 qf[8];
  const bf16_t* qb = q + ((size_t)(b * 2048 + qg)) * 2048 + h * 128 + h5 * 8;
#pragma unroll
  for (int fc = 0; fc < 8; ++fc) qf[fc] = *(const bf16x8*)(qb + fc * 16);

  const bf16_t* kbase = k + ((size_t)b * 4096) * 2048 + h * 128;
  const bf16_t* vbase = vT + ((size_t)(b * 16 + h)) * 128 * 4096;

  // staging maps (slot = tid + 256p) — identical to proven round-2 kernel
  int ks_key[4], ks_go[4], vs_feat[4], vs_go[4];
#pragma unroll
  for (int p = 0; p < 4; ++p) {
    const int slot = tid + 256 * p;
    const int key = slot >> 4, ph = slot & 15;
    ks_key[p] = key;
    ks_go[p]  = (((ph & 8) | ((ph & 7) ^ (key & 7)))) * 8;
    const int ft = slot >> 3, p2 = slot & 7;
    vs_feat[p] = ft;
    vs_go[p]   = (p2 ^ (ft & 7)) * 8;
  }
  // frag read offsets (elems)
  int kfo[8], vfo[4];
#pragma unroll
  for (int fc = 0; fc < 8; ++fc) {
    const int L = fc * 2 + h5;
    kfo[fc] = l31 * 128 + ((L & 8) | ((L & 7) ^ (l31 & 7))) * 8;
  }
#pragma unroll
  for (int kc = 0; kc < 4; ++kc) {
    const int L = kc * 2 + h5;
    vfo[kc] = l31 * 64 + (L ^ (l31 & 7)) * 8;
  }

  f32x16 o[4] = {};
  float m = -1e30f, l = 0.f;

  // prologue: stage K(tbeg) -> buf0, V(tbeg) -> vbuf
#pragma unroll
  for (int p = 0; p < 4; ++p) {
    load_lds16(kbase + ((size_t)tbeg * 64 + ks_key[p]) * 2048 + ks_go[p],
               smem + (tid + 256 * p) * 8);
    load_lds16(vbase + (size_t)vs_feat[p] * 4096 + tbeg * 64 + vs_go[p],
               smem + 16384 + (tid + 256 * p) * 8);
  }
  __syncthreads();                                  // tile tbeg resident

  int cur = 0;
  for (int ti = tbeg; ti < tend; ++ti) {
    const int s0 = ti * 64;
    const bool hasnext = (ti + 1 < tend);
    // stage next K tile into other buffer (DMA overlaps compute below)
    if (hasnext) {
      const int nxt = (cur ^ 1) * 8192;
#pragma unroll
      for (int p = 0; p < 4; ++p)
        load_lds16(kbase + ((size_t)(s0 + 64) + ks_key[p]) * 2048 + ks_go[p],
                   smem + nxt + (tid + 256 * p) * 8);
    }
    const bf16_t* Kc = smem + cur * 8192;

    // S^T tiles: rows = keys 32t + (i&3)+8*(i>>2)+4*h5, col = q = l31
    f32x16 st[2] = {};
    __builtin_amdgcn_s_setprio(1);
#pragma unroll
    for (int fc = 0; fc < 8; ++fc) {
      bf16x8 k0 = *(const bf16x8*)&Kc[kfo[fc]];
      bf16x8 k1 = *(const bf16x8*)&Kc[4096 + kfo[fc]];
      st[0] = MFMA32(k0, qf[fc], st[0]);
      st[1] = MFMA32(k1, qf[fc], st[1]);
    }
    __builtin_amdgcn_s_setprio(0);

    if (s0 + 63 > qlim) {                           // causal tail masking
#pragma unroll
      for (int t = 0; t < 2; ++t)
#pragma unroll
        for (int i = 0; i < 16; ++i) {
          const int key = s0 + 32 * t + (i & 3) + 8 * (i >> 2) + 4 * h5;
          if (key > 2048 + qg) st[t][i] = -1e30f;
        }
    }

    // tree max over this lane's 32 scores (depth 5)
    float gm[8];
#pragma unroll
    for (int t = 0; t < 2; ++t)
#pragma unroll
      for (int g = 0; g < 4; ++g)
        gm[t * 4 + g] = fmaxf(fmaxf(st[t][4 * g + 0], st[t][4 * g + 1]),
                              fmaxf(st[t][4 * g + 2], st[t][4 * g + 3]));
    float mt = fmaxf(fmaxf(fmaxf(gm[0], gm[1]), fmaxf(gm[2], gm[3])),
                     fmaxf(fmaxf(gm[4], gm[5]), fmaxf(gm[6], gm[7])));
    mt = fmaxf(mt, __shfl_xor(mt, 32));

    // defer-max: only rescale when max grew by >8 (log2 domain; p <= 2^8)
    if (__any(mt > m + 8.f)) {
      const float mnew = fmaxf(m, mt);
      const float alpha = fast_exp2(m - mnew);
#pragma unroll
      for (int ft = 0; ft < 4; ++ft)
#pragma unroll
        for (int i = 0; i < 16; ++i) o[ft][i] *= alpha;
      l *= alpha;
      m = mnew;
    }

    // exp2 + pack P; group g holds keys 32t + 8g + 4h5 + 0..3
    float rs = 0.f;
    unsigned up[2][4][2];
#pragma unroll
    for (int t = 0; t < 2; ++t)
#pragma unroll
      for (int g = 0; g < 4; ++g) {
        const float p0 = fast_exp2(st[t][4 * g + 0] - m);
        const float p1 = fast_exp2(st[t][4 * g + 1] - m);
        const float p2 = fast_exp2(st[t][4 * g + 2] - m);
        const float p3 = fast_exp2(st[t][4 * g + 3] - m);
        rs += (p0 + p1) + (p2 + p3);
        up[t][g][0] = pack_bf16(p0, p1);
        up[t][g][1] = pack_bf16(p2, p3);
      }
    rs += __shfl_xor(rs, 32);
    l += rs;

    __syncthreads();   // V_cur DMA drained (issued last iter); K_next also drains

    // out^T += V^T · P^T ; P^T B-frag built in-register via half-exchange
    const bf16_t* Vc = smem + 16384;
#pragma unroll
    for (int kc = 0; kc < 4; ++kc) {
      const int t = kc >> 1, gp = (kc & 1) * 2;
      const unsigned a0 = up[t][gp][0],     a1 = up[t][gp][1];
      const unsigned b0 = up[t][gp + 1][0], b1 = up[t][gp + 1][1];
      const unsigned xa0 = __shfl_xor(a0, 32), xa1 = __shfl_xor(a1, 32);
      const unsigned xb0 = __shfl_xor(b0, 32), xb1 = __shfl_xor(b1, 32);
      u32x4 uw;
      uw[0] = h5 ? xb0 : a0;
      uw[1] = h5 ? xb1 : a1;
      uw[2] = h5 ? b0 : xa0;
      uw[3] = h5 ? b1 : xa1;
      union { u32x4 u; bf16x8 v; } pc; pc.u = uw;
      const bf16x8 pf = pc.v;
      __builtin_amdgcn_s_setprio(1);
#pragma unroll
      for (int ft = 0; ft < 4; ++ft) {
        bf16x8 vf = *(const bf16x8*)&Vc[ft * 2048 + vfo[kc]];
        o[ft] = MFMA32(vf, pf, o[ft]);
      }
      __builtin_amdgcn_s_setprio(0);
    }

    __syncthreads();   // all V reads done -> safe to overwrite vbuf

    // stage next V tile (drains at next iteration's pre-PV barrier)
    if (hasnext) {
#pragma unroll
      for (int p = 0; p < 4; ++p)
        load_lds16(vbase + (size_t)vs_feat[p] * 4096 + (s0 + 64) + vs_go[p],
                   smem + 16384 + (tid + 256 * p) * 8);
    }
    cur ^= 1;
  }

  // epilogue: normalize by own l, LDS transpose, coalesced store
  bf16_t* const outp = (SPLIT && half) ? out1 : out0;
  const float inv = 1.0f / l;
  const int rowp_w = w * 32 + l31;
#pragma unroll
  for (int ft = 0; ft < 4; ++ft)
#pragma unroll
    for (int g = 0; g < 4; ++g) {
      bf16x4 pk;
#pragma unroll
      for (int r = 0; r < 4; ++r) pk[r] = (bf16_t)(o[ft][4 * g + r] * inv);
      *(bf16x4*)&smem[rowp_w * 136 + ft * 32 + g * 8 + h5 * 4] = pk;
    }
  if (SPLIT && h5 == 0)
    ml[((size_t)((half * 2 + b) * 16 + h)) * 2048 + qg] = make_float2(m, l);
  __syncthreads();
#pragma unroll
  for (int p = 0; p < 8; ++p) {
    const int c = tid + 256 * p;
    const int rowp = c >> 4, chk = c & 15;
    const int ql = (rowp & 31) * 4 + (rowp >> 5);
    bf16x8 d = *(const bf16x8*)&smem[rowp * 136 + chk * 8];
    *(bf16x8*)(outp + ((size_t)(b * 2048 + q0 + ql)) * 2048 + h * 128 + chk * 8) = d;
  }
}

// ---------------------------------------------------------------------------
// Combine the two split-K halves: out = (w0*o0 + w1*o1)/(w0+w1),
// wi = li * 2^(mi - M). In-place on o0 (aout).
// ---------------------------------------------------------------------------
__global__ __launch_bounds__(256) void attn_combine(bf16_t* o0,
                                                    const bf16_t* o1,
                                                    const float2* ml)
{
  const int row = blockIdx.x;             // b*2048 + t
  const int tid = threadIdx.x;
  const int b = row >> 11, t = row & 2047;
  const int h = tid >> 4;
  const float2 v0 = ml[((size_t)(b * 16 + h)) * 2048 + t];
  const float2 v1 = ml[((size_t)((2 + b) * 16 + h)) * 2048 + t];
  const float M  = fmaxf(v0.x, v1.x);
  const float w0 = v0.y * fast_exp2(v0.x - M);
  const float w1 = v1.y * fast_exp2(v1.x - M);
  const float inv = 1.0f / (w0 + w1);
  const float a0 = w0 * inv, a1 = w1 * inv;
  const size_t base = (size_t)row * 2048 + tid * 8;
  bf16x8 x0 = *(const bf16x8*)(o0 + base);
  bf16x8 x1 = *(const bf16x8*)(o1 + base);
  bf16x8 r;
#pragma unroll
  for (int j = 0; j < 8; ++j)
    r[j] = (bf16_t)(a0 * (float)x0[j] + a1 * (float)x1[j]);
  *(bf16x8*)(o0 + base) = r;
}

// ---------------------------------------------------------------------------
extern "C" void kernel_launch(void* const* d_in, const int* in_sizes, int n_in,
                              void* d_out, int out_size, void* d_ws, size_t ws_size,
                              hipStream_t stream)
{
  (void)in_sizes; (void)n_in; (void)out_size;
  const float* x        = (const float*)d_in[0];
  const float* lat_prev = (const float*)d_in[1];
  const float* Wq       = (const float*)d_in[2];
  const float* Wdown    = (const float*)d_in[3];
  const float* Wk_up    = (const float*)d_in[4];
  const float* Wv_up    = (const float*)d_in[5];
  const float* ln_g     = (const float*)d_in[6];
  const float* ln_b     = (const float*)d_in[7];
  const float* Wo       = (const float*)d_in[8];
  float* out = (float*)d_out;

  char* p = (char*)d_ws;
  auto alloc = [&](size_t elems) { bf16_t* r = (bf16_t*)p; p += elems * 2; return r; };
  bf16_t* xb     = alloc((size_t)4096 * 2048);   // hosts WoT after x dead
  bf16_t* WqT    = alloc((size_t)2048 * 2048);
  bf16_t* WdT    = alloc((size_t)512 * 2048);
  bf16_t* qbuf   = alloc((size_t)4096 * 2048);
  bf16_t* latpre = alloc((size_t)4096 * 512);    // hosts WkT+WvT after LN
  bf16_t* latent = alloc((size_t)2 * 4096 * 512);
  bf16_t* kbuf   = alloc((size_t)8192 * 2048);
  bf16_t* vTb    = alloc((size_t)2 * 2048 * 4096);
  bf16_t* aout   = alloc((size_t)4096 * 2048);
  bf16_t* opart1 = alloc((size_t)4096 * 2048);   // split-K half-1 partial
  float2* mlbuf  = (float2*)p; p += (size_t)2 * 2 * 16 * 2048 * sizeof(float2);
  const size_t needed = (size_t)(p - (char*)d_ws);
  bf16_t* WoT  = xb;
  bf16_t* WkT  = latpre;
  bf16_t* WvT  = latpre + (size_t)2048 * 512;

  const dim3 B(256);
  // 1/sqrt(128) * log2(e): attention scores land in log2 domain
  const float qscale = 0.12751744561825988f;

  cvt_f2b<<<dim3(8192), B, 0, stream>>>(x, xb);
  cvt_transpose<<<dim3(32, 32), B, 0, stream>>>(Wq,    WqT, 2048, 2048);
  cvt_transpose<<<dim3(8,  32), B, 0, stream>>>(Wdown, WdT, 2048, 512);
  // q = (x@Wq) * qscale ; latpre = x@Wdown
  gemm128<bf16_t><<<dim3(16, 32), B, 0, stream>>>(xb, WqT, qbuf, 4096, 2048, 2048, qscale, 0, 0);
  gemm128<bf16_t><<<dim3(4,  32), B, 0, stream>>>(xb, WdT, latpre, 4096, 512, 2048, 1.0f, 0, 0);
  // latent cache
  copy_prev_f<<<dim3(2048), B, 0, stream>>>(lat_prev, latent);
  ln_kernel<<<dim3(4096), B, 0, stream>>>(latpre, ln_g, ln_b, latent);
  // weight transposes into dead regions (stream order enforces lifetimes)
  cvt_transpose<<<dim3(32, 32), B, 0, stream>>>(Wo,    WoT, 2048, 2048);
  cvt_transpose<<<dim3(32, 8),  B, 0, stream>>>(Wk_up, WkT, 512, 2048);
  cvt_transpose<<<dim3(32, 8),  B, 0, stream>>>(Wv_up, WvT, 512, 2048);
  // k = latent @ Wk_up  (rows b*4096+s)
  gemm128<bf16_t><<<dim3(16, 64), B, 0, stream>>>(latent, WkT, kbuf, 8192, 2048, 512, 1.0f, 0, 0);
  // vT_b = WvT @ latent_b^T  (BT = latent_b), batched over z
  gemm128<bf16_t><<<dim3(32, 16, 2), B, 0, stream>>>(WvT, latent, vTb, 2048, 4096, 512, 1.0f,
                                                     (long long)4096 * 512,
                                                     (long long)2048 * 4096);
  // attention
  if (ws_size == 0 || ws_size >= needed) {
    attn5<true><<<dim3(1024), B, 0, stream>>>(qbuf, kbuf, vTb, aout, opart1, mlbuf);
    attn_combine<<<dim3(4096), B, 0, stream>>>(aout, opart1, mlbuf);
  } else {
    attn5<false><<<dim3(512), B, 0, stream>>>(qbuf, kbuf, vTb, aout, nullptr, nullptr);
  }
  // output projection (fp32 out)
  gemm128<float><<<dim3(16, 32), B, 0, stream>>>(aout, WoT, out, 4096, 2048, 2048, 1.0f, 0, 0);
}

// Round 6
// 590.385 us; speedup vs baseline: 1.2177x; 1.0208x over previous
//
#include <hip/hip_runtime.h>
#include <hip/hip_bf16.h>

using bf16_t = __bf16;
typedef __bf16 bf16x8 __attribute__((ext_vector_type(8)));
typedef __bf16 bf16x4 __attribute__((ext_vector_type(4)));
typedef __bf16 bf16x2 __attribute__((ext_vector_type(2)));
typedef float  f32x4  __attribute__((ext_vector_type(4)));
typedef float  f32x16 __attribute__((ext_vector_type(16)));
typedef unsigned u32x4 __attribute__((ext_vector_type(4)));

#define MFMA16(a,b,c) __builtin_amdgcn_mfma_f32_16x16x32_bf16((a),(b),(c),0,0,0)
#define MFMA32(a,b,c) __builtin_amdgcn_mfma_f32_32x32x16_bf16((a),(b),(c),0,0,0)

__device__ __forceinline__ void load_lds16(const void* g, void* l) {
  __builtin_amdgcn_global_load_lds(
      (const __attribute__((address_space(1))) unsigned int*)g,
      (__attribute__((address_space(3))) unsigned int*)l, 16, 0, 0);
}

__device__ __forceinline__ unsigned pack_bf16(float a, float b) {
  union { bf16x2 v; unsigned u; } c;
  c.v[0] = (bf16_t)a; c.v[1] = (bf16_t)b;
  return c.u;
}

__device__ __forceinline__ float fast_exp2(float x) {
#if __has_builtin(__builtin_amdgcn_exp2f)
  return __builtin_amdgcn_exp2f(x);
#else
  return exp2f(x);
#endif
}

// ---------------------------------------------------------------------------
// fp32 -> bf16 elementwise convert (x). 4 elems/thread.
// ---------------------------------------------------------------------------
__global__ __launch_bounds__(256) void cvt_f2b(const float* __restrict__ in,
                                               bf16_t* __restrict__ out)
{
  const size_t i = ((size_t)blockIdx.x * 256 + threadIdx.x) * 4;
  f32x4 d = *(const f32x4*)(in + i);
  bf16x4 o;
#pragma unroll
  for (int j = 0; j < 4; ++j) o[j] = (bf16_t)d[j];
  *(bf16x4*)(out + i) = o;
}

// ---------------------------------------------------------------------------
// fp32 [R][C] -> bf16 [C][R] transposed convert (weights). 64x64 LDS tile.
// ---------------------------------------------------------------------------
__global__ __launch_bounds__(256) void cvt_transpose(const float* __restrict__ in,
                                                     bf16_t* __restrict__ out,
                                                     int R, int C)
{
  __shared__ __align__(16) bf16_t t[64 * 80];
  const int r0 = blockIdx.y * 64, c0 = blockIdx.x * 64;
  const int rr = threadIdx.x >> 4;          // 0..15
  const int c4 = (threadIdx.x & 15) * 4;    // 0..60
#pragma unroll
  for (int i = 0; i < 4; ++i) {
    const int r = rr + i * 16;
    f32x4 d = *(const f32x4*)(in + (size_t)(r0 + r) * C + c0 + c4);
#pragma unroll
    for (int j = 0; j < 4; ++j) t[(c4 + j) * 80 + r] = (bf16_t)d[j];
  }
  __syncthreads();
  const int a  = threadIdx.x >> 3;          // 0..31
  const int bc = (threadIdx.x & 7) * 8;
#pragma unroll
  for (int half = 0; half < 2; ++half) {
    const int cc = a + half * 32;
    bf16x8 d = *(const bf16x8*)&t[cc * 80 + bc];
    *(bf16x8*)(out + (size_t)(c0 + cc) * R + r0 + bc) = d;
  }
}

// ---------------------------------------------------------------------------
// m97-class GEMM: C[M,N] = A[M,K] @ B[K,N] (+scale), B given as BT[N,K].
// 128x128 tile, BK=32, 4 waves each 64x64 (4x4 of 16x16x32 MFMA).
// ---------------------------------------------------------------------------
template <typename OutT>
__global__ __launch_bounds__(256) void gemm128(const bf16_t* __restrict__ A,
                                               const bf16_t* __restrict__ BT,
                                               OutT* __restrict__ C,
                                               int M, int N, int K, float scale,
                                               long long zB, long long zC)
{
  __shared__ __align__(16) bf16_t As[128 * 32];
  __shared__ __align__(16) bf16_t Bs[128 * 32];
  const int tid = threadIdx.x;
  BT += (size_t)blockIdx.z * zB;
  C  += (size_t)blockIdx.z * zC;
  const int m0 = blockIdx.y * 128, n0 = blockIdx.x * 128;
  const int lane = tid & 63, w = tid >> 6;
  const int quad = lane >> 4, l15 = lane & 15;
  const int wm = (w >> 1) * 64, wn = (w & 1) * 64;
  const int s_row = tid >> 2;
  const int g_off = ((tid & 3) ^ (s_row & 3)) * 8;   // swizzled global chunk
  const int quadp = (quad ^ (l15 & 3)) * 8;          // swizzled frag offset
  const bf16_t* Ap0 = A  + (size_t)(m0 + s_row) * K + g_off;
  const bf16_t* Ap1 = A  + (size_t)(m0 + 64 + s_row) * K + g_off;
  const bf16_t* Bp0 = BT + (size_t)(n0 + s_row) * K + g_off;
  const bf16_t* Bp1 = BT + (size_t)(n0 + 64 + s_row) * K + g_off;

  f32x4 acc[4][4] = {};

  for (int k0 = 0; k0 < K; k0 += 32) {
    __syncthreads();
    load_lds16(Ap0 + k0, As + tid * 8);
    load_lds16(Ap1 + k0, As + tid * 8 + 2048);
    load_lds16(Bp0 + k0, Bs + tid * 8);
    load_lds16(Bp1 + k0, Bs + tid * 8 + 2048);
    __syncthreads();
    bf16x8 af[4], bfr[4];
#pragma unroll
    for (int fi = 0; fi < 4; ++fi)
      af[fi] = *(const bf16x8*)&As[(wm + fi * 16 + l15) * 32 + quadp];
#pragma unroll
    for (int fj = 0; fj < 4; ++fj)
      bfr[fj] = *(const bf16x8*)&Bs[(wn + fj * 16 + l15) * 32 + quadp];
#pragma unroll
    for (int fi = 0; fi < 4; ++fi)
#pragma unroll
      for (int fj = 0; fj < 4; ++fj)
        acc[fi][fj] = MFMA16(af[fi], bfr[fj], acc[fi][fj]);
  }

#pragma unroll
  for (int fi = 0; fi < 4; ++fi)
#pragma unroll
    for (int fj = 0; fj < 4; ++fj)
#pragma unroll
      for (int r = 0; r < 4; ++r) {
        const int row = m0 + wm + fi * 16 + quad * 4 + r;
        const int col = n0 + wn + fj * 16 + l15;
        C[(size_t)row * N + col] = (OutT)(acc[fi][fj][r] * scale);
      }
}

// ---------------------------------------------------------------------------
// latent_prev fp32 (2,2048,512) -> bf16 latent rows [0,2048) of (2,4096,512)
// ---------------------------------------------------------------------------
__global__ __launch_bounds__(256) void copy_prev_f(const float* __restrict__ prev,
                                                   bf16_t* __restrict__ latent)
{
  const size_t v    = (size_t)blockIdx.x * 256 + threadIdx.x;
  const size_t flat = v * 4;
  const size_t per  = (size_t)2048 * 512;
  const size_t b    = flat / per, rem = flat % per;
  f32x4 d = *(const f32x4*)(prev + flat);
  bf16x4 o;
#pragma unroll
  for (int j = 0; j < 4; ++j) o[j] = (bf16_t)d[j];
  *(bf16x4*)(latent + b * ((size_t)4096 * 512) + rem) = o;
}

// ---------------------------------------------------------------------------
// LayerNorm over 512 (fp32 stats), bf16 in, fp32 g/b, bf16 out into latent
// rows [2048,4096).
// ---------------------------------------------------------------------------
__global__ __launch_bounds__(256) void ln_kernel(const bf16_t* __restrict__ in,
                                                 const float* __restrict__ g_,
                                                 const float* __restrict__ b_,
                                                 bf16_t* __restrict__ latent)
{
  const int row = blockIdx.x;             // 0..4095 (= b*2048 + t)
  const int tid = threadIdx.x;
  const float x0 = (float)in[(size_t)row * 512 + tid];
  const float x1 = (float)in[(size_t)row * 512 + 256 + tid];
  float s  = x0 + x1;
  float sq = x0 * x0 + x1 * x1;
#pragma unroll
  for (int off = 1; off < 64; off <<= 1) {
    s  += __shfl_xor(s, off);
    sq += __shfl_xor(sq, off);
  }
  __shared__ float red[8];
  const int w = tid >> 6;
  if ((tid & 63) == 0) { red[w] = s; red[4 + w] = sq; }
  __syncthreads();
  s  = red[0] + red[1] + red[2] + red[3];
  sq = red[4] + red[5] + red[6] + red[7];
  const float mu   = s * (1.0f / 512.0f);
  const float var  = sq * (1.0f / 512.0f) - mu * mu;
  const float rstd = rsqrtf(var + 1e-5f);
  const int b = row >> 11, tt = row & 2047;
  bf16_t* outp = latent + ((size_t)b * 4096 + 2048 + tt) * 512;
  outp[tid]       = (bf16_t)((x0 - mu) * rstd * g_[tid]       + b_[tid]);
  outp[tid + 256] = (bf16_t)((x1 - mu) * rstd * g_[tid + 256] + b_[tid + 256]);
}

// ---------------------------------------------------------------------------
// Flash attention v6: one-tile software pipeline. Per iteration i:
//   sync (drains K(i+1), V(i) DMA — exactly the tiles consumed this iter)
//   issue K(i+2), V(i+1) DMA
//   QK^T(i+1)  [16 MFMA, background]
//   PV(i)      [16 MFMA + 16 shfl, background, P(i) packed last iter]
//   mask/max(i+1)  [VALU, overlaps in-flight MFMAs]
//   rare defer-max rescale (after PV(i) -- math identical to eager order)
//   exp2/pack(i+1) -> up  [VALU, overlaps PV MFMAs; WAR on up is safe
//                          because PV's reads issued earlier in order]
// K and V both double-buffered: K0|K1|V0|V1 = 64KB LDS, 2 blocks/CU.
// Grid 512, XCD-grouped: XCD g owns heads {g, g+8} (proven -75% FETCH).
// Softmax log2 domain; defer-max THR=8; tree max; setprio on MFMA.
// ---------------------------------------------------------------------------
__global__ __launch_bounds__(256) void attn6(const bf16_t* __restrict__ q,
                                             const bf16_t* __restrict__ k,
                                             const bf16_t* __restrict__ vT,
                                             bf16_t* __restrict__ out)
{
  __shared__ __align__(16) bf16_t smem[32768];      // K0|K1|V0|V1 + epilogue

  const int tid = threadIdx.x;
  const int lane = tid & 63, w = tid >> 6;
  const int l31 = lane & 31, h5 = lane >> 5;

  // XCD grouping: XCD g = bid&7 owns heads {g, g+8}; b flips qt for balance.
  const int g = blockIdx.x & 7, j = blockIdx.x >> 3;
  int qt = j & 15;
  const int b = (j >> 4) & 1, hsel = j >> 5;
  const int h = g + 8 * hsel;
  if (b) qt = 15 - qt;

  const int q0 = qt * 128;
  const int qg = q0 + l31 * 4 + w;                  // this lane's query row
  const int qlim = 2048 + q0;
  const int nt = 34 + 2 * qt;                       // 64-key tiles (even)

  // Q^T B-frags: B[k=feat fc*16+h5*8+j][n=q l31]
  bf16x8 qf[8];
  const bf16_t* qb = q + ((size_t)(b * 2048 + qg)) * 2048 + h * 128 + h5 * 8;
#pragma unroll
  for (int fc = 0; fc < 8; ++fc) qf[fc] = *(const bf16x8*)(qb + fc * 16);

  const bf16_t* kbase = k + ((size_t)b * 4096) * 2048 + h * 128;
  const bf16_t* vbase = vT + ((size_t)(b * 16 + h)) * 128 * 4096;

  // staging maps (slot = tid + 256p) — proven round-2 maps
  int ks_key[4], ks_go[4], vs_feat[4], vs_go[4];
#pragma unroll
  for (int p = 0; p < 4; ++p) {
    const int slot = tid + 256 * p;
    const int key = slot >> 4, ph = slot & 15;
    ks_key[p] = key;
    ks_go[p]  = (((ph & 8) | ((ph & 7) ^ (key & 7)))) * 8;
    const int ft = slot >> 3, p2 = slot & 7;
    vs_feat[p] = ft;
    vs_go[p]   = (p2 ^ (ft & 7)) * 8;
  }
  // frag read offsets (elems)
  int kfo[8], vfo[4];
#pragma unroll
  for (int fc = 0; fc < 8; ++fc) {
    const int L = fc * 2 + h5;
    kfo[fc] = l31 * 128 + ((L & 8) | ((L & 7) ^ (l31 & 7))) * 8;
  }
#pragma unroll
  for (int kc = 0; kc < 4; ++kc) {
    const int L = kc * 2 + h5;
    vfo[kc] = l31 * 64 + (L ^ (l31 & 7)) * 8;
  }

  // LDS slot bases (elems): K slot s @ s*8192, V slot s @ 16384 + s*8192
  auto stageK = [&](int t, int slot) {
#pragma unroll
    for (int p = 0; p < 4; ++p)
      load_lds16(kbase + ((size_t)t * 64 + ks_key[p]) * 2048 + ks_go[p],
                 smem + slot * 8192 + (tid + 256 * p) * 8);
  };
  auto stageV = [&](int t, int slot) {
#pragma unroll
    for (int p = 0; p < 4; ++p)
      load_lds16(vbase + (size_t)vs_feat[p] * 4096 + t * 64 + vs_go[p],
                 smem + 16384 + slot * 8192 + (tid + 256 * p) * 8);
  };

  f32x16 o[4] = {};
  float m = 0.f, l = 0.f;
  unsigned up[2][4][2];                             // packed P of tile in flight

  // QK^T of one tile from K slot -> st
  auto qk = [&](int slot, f32x16* st) {
    const bf16_t* Kc = smem + slot * 8192;
    __builtin_amdgcn_s_setprio(1);
#pragma unroll
    for (int fc = 0; fc < 8; ++fc) {
      bf16x8 k0 = *(const bf16x8*)&Kc[kfo[fc]];
      bf16x8 k1 = *(const bf16x8*)&Kc[4096 + kfo[fc]];
      st[0] = MFMA32(k0, qf[fc], st[0]);
      st[1] = MFMA32(k1, qf[fc], st[1]);
    }
    __builtin_amdgcn_s_setprio(0);
  };

  // PV of the in-flight tile (P in up) from V slot
  auto pv = [&](int slot) {
    const bf16_t* Vc = smem + 16384 + slot * 8192;
#pragma unroll
    for (int kc = 0; kc < 4; ++kc) {
      const int t = kc >> 1, gp = (kc & 1) * 2;
      const unsigned a0 = up[t][gp][0],     a1 = up[t][gp][1];
      const unsigned b0 = up[t][gp + 1][0], b1 = up[t][gp + 1][1];
      const unsigned xa0 = __shfl_xor(a0, 32), xa1 = __shfl_xor(a1, 32);
      const unsigned xb0 = __shfl_xor(b0, 32), xb1 = __shfl_xor(b1, 32);
      u32x4 uw;
      uw[0] = h5 ? xb0 : a0;
      uw[1] = h5 ? xb1 : a1;
      uw[2] = h5 ? b0 : xa0;
      uw[3] = h5 ? b1 : xa1;
      union { u32x4 u; bf16x8 v; } pc; pc.u = uw;
      const bf16x8 pf = pc.v;
      __builtin_amdgcn_s_setprio(1);
#pragma unroll
      for (int ft = 0; ft < 4; ++ft) {
        bf16x8 vf = *(const bf16x8*)&Vc[ft * 2048 + vfo[kc]];
        o[ft] = MFMA32(vf, pf, o[ft]);
      }
      __builtin_amdgcn_s_setprio(0);
    }
  };

  // mask tile (s0) scores in st
  auto maskst = [&](int s0, f32x16* st) {
    if (s0 + 63 > qlim) {
#pragma unroll
      for (int t = 0; t < 2; ++t)
#pragma unroll
        for (int i = 0; i < 16; ++i) {
          const int key = s0 + 32 * t + (i & 3) + 8 * (i >> 2) + 4 * h5;
          if (key > 2048 + qg) st[t][i] = -1e30f;
        }
    }
  };

  // tree max (depth 5) + cross-half
  auto maxst = [&](const f32x16* st) {
    float gm[8];
#pragma unroll
    for (int t = 0; t < 2; ++t)
#pragma unroll
      for (int gg = 0; gg < 4; ++gg)
        gm[t * 4 + gg] = fmaxf(fmaxf(st[t][4 * gg + 0], st[t][4 * gg + 1]),
                               fmaxf(st[t][4 * gg + 2], st[t][4 * gg + 3]));
    float mt = fmaxf(fmaxf(fmaxf(gm[0], gm[1]), fmaxf(gm[2], gm[3])),
                     fmaxf(fmaxf(gm[4], gm[5]), fmaxf(gm[6], gm[7])));
    return fmaxf(mt, __shfl_xor(mt, 32));
  };

  // exp2 + pack -> up, returns row-sum contribution
  auto exppack = [&](const f32x16* st) {
    float rs = 0.f;
#pragma unroll
    for (int t = 0; t < 2; ++t)
#pragma unroll
      for (int gg = 0; gg < 4; ++gg) {
        const float p0 = fast_exp2(st[t][4 * gg + 0] - m);
        const float p1 = fast_exp2(st[t][4 * gg + 1] - m);
        const float p2 = fast_exp2(st[t][4 * gg + 2] - m);
        const float p3 = fast_exp2(st[t][4 * gg + 3] - m);
        rs += (p0 + p1) + (p2 + p3);
        up[t][gg][0] = pack_bf16(p0, p1);
        up[t][gg][1] = pack_bf16(p2, p3);
      }
    rs += __shfl_xor(rs, 32);
    return rs;
  };

  // ---- prologue: tiles 0 (and K of 1) staged; softmax(0) packed ----
  stageK(0, 0);
  stageV(0, 0);
  if (nt > 1) stageK(1, 1);
  __syncthreads();
  {
    f32x16 st[2] = {};
    qk(0, st);
    // tile 0 never needs causal mask (qlim >= 2048 > 63)
    m = maxst(st);
    l = exppack(st);
  }

  // ---- pipelined main loop: iter i does QK(i+1) ∥ PV(i) ----
  for (int i = 0; i + 1 < nt; ++i) {
    __syncthreads();              // drains K(i+1), V(i); prev reads done
    if (i + 2 < nt) stageK(i + 2, i & 1);
    stageV(i + 1, (i + 1) & 1);

    f32x16 st[2] = {};
    qk((i + 1) & 1, st);          // MFMA x16, background
    pv(i & 1);                    // MFMA x16 + shfl, background (old up)

    maskst((i + 1) * 64, st);     // VALU (waits st chains only)
    const float mt = maxst(st);
    if (__any(mt > m + 8.f)) {    // rare: rescale AFTER PV(i) (math-equal)
      const float mnew = fmaxf(m, mt);
      const float alpha = fast_exp2(m - mnew);
#pragma unroll
      for (int ft = 0; ft < 4; ++ft)
#pragma unroll
        for (int ii = 0; ii < 16; ++ii) o[ft][ii] *= alpha;
      l *= alpha;
      m = mnew;
    }
    l += exppack(st);             // VALU under PV MFMA shadow; WAR-safe
  }

  // ---- epilogue: last PV, normalize, LDS transpose, coalesced store ----
  __syncthreads();                // drain V(nt-1)
  pv((nt - 1) & 1);               // nt even -> reads V slot 1 (no overlay clash)

  const float inv = 1.0f / l;
  const int rowp_w = w * 32 + l31;
#pragma unroll
  for (int ft = 0; ft < 4; ++ft)
#pragma unroll
    for (int gg = 0; gg < 4; ++gg) {
      bf16x4 pk;
#pragma unroll
      for (int r = 0; r < 4; ++r) pk[r] = (bf16_t)(o[ft][4 * gg + r] * inv);
      *(bf16x4*)&smem[rowp_w * 136 + ft * 32 + gg * 8 + h5 * 4] = pk;
    }
  __syncthreads();
#pragma unroll
  for (int p = 0; p < 8; ++p) {
    const int c = tid + 256 * p;
    const int rowp = c >> 4, chk = c & 15;
    const int ql = (rowp & 31) * 4 + (rowp >> 5);
    bf16x8 d = *(const bf16x8*)&smem[rowp * 136 + chk * 8];
    *(bf16x8*)(out + ((size_t)(b * 2048 + q0 + ql)) * 2048 + h * 128 + chk * 8) = d;
  }
}

// ---------------------------------------------------------------------------
extern "C" void kernel_launch(void* const* d_in, const int* in_sizes, int n_in,
                              void* d_out, int out_size, void* d_ws, size_t ws_size,
                              hipStream_t stream)
{
  (void)in_sizes; (void)n_in; (void)out_size; (void)ws_size;
  const float* x        = (const float*)d_in[0];
  const float* lat_prev = (const float*)d_in[1];
  const float* Wq       = (const float*)d_in[2];
  const float* Wdown    = (const float*)d_in[3];
  const float* Wk_up    = (const float*)d_in[4];
  const float* Wv_up    = (const float*)d_in[5];
  const float* ln_g     = (const float*)d_in[6];
  const float* ln_b     = (const float*)d_in[7];
  const float* Wo       = (const float*)d_in[8];
  float* out = (float*)d_out;

  char* p = (char*)d_ws;
  auto alloc = [&](size_t elems) { bf16_t* r = (bf16_t*)p; p += elems * 2; return r; };
  bf16_t* xb     = alloc((size_t)4096 * 2048);   // hosts WoT after x dead
  bf16_t* WqT    = alloc((size_t)2048 * 2048);
  bf16_t* WdT    = alloc((size_t)512 * 2048);
  bf16_t* qbuf   = alloc((size_t)4096 * 2048);
  bf16_t* latpre = alloc((size_t)4096 * 512);    // hosts WkT+WvT after LN
  bf16_t* latent = alloc((size_t)2 * 4096 * 512);
  bf16_t* kbuf   = alloc((size_t)8192 * 2048);
  bf16_t* vTb    = alloc((size_t)2 * 2048 * 4096);
  bf16_t* aout   = alloc((size_t)4096 * 2048);
  bf16_t* WoT  = xb;
  bf16_t* WkT  = latpre;
  bf16_t* WvT  = latpre + (size_t)2048 * 512;

  const dim3 B(256);
  // 1/sqrt(128) * log2(e): attention scores land in log2 domain
  const float qscale = 0.12751744561825988f;

  cvt_f2b<<<dim3(8192), B, 0, stream>>>(x, xb);
  cvt_transpose<<<dim3(32, 32), B, 0, stream>>>(Wq,    WqT, 2048, 2048);
  cvt_transpose<<<dim3(8,  32), B, 0, stream>>>(Wdown, WdT, 2048, 512);
  // q = (x@Wq) * qscale ; latpre = x@Wdown
  gemm128<bf16_t><<<dim3(16, 32), B, 0, stream>>>(xb, WqT, qbuf, 4096, 2048, 2048, qscale, 0, 0);
  gemm128<bf16_t><<<dim3(4,  32), B, 0, stream>>>(xb, WdT, latpre, 4096, 512, 2048, 1.0f, 0, 0);
  // latent cache
  copy_prev_f<<<dim3(2048), B, 0, stream>>>(lat_prev, latent);
  ln_kernel<<<dim3(4096), B, 0, stream>>>(latpre, ln_g, ln_b, latent);
  // weight transposes into dead regions (stream order enforces lifetimes)
  cvt_transpose<<<dim3(32, 32), B, 0, stream>>>(Wo,    WoT, 2048, 2048);
  cvt_transpose<<<dim3(32, 8),  B, 0, stream>>>(Wk_up, WkT, 512, 2048);
  cvt_transpose<<<dim3(32, 8),  B, 0, stream>>>(Wv_up, WvT, 512, 2048);
  // k = latent @ Wk_up  (rows b*4096+s)
  gemm128<bf16_t><<<dim3(16, 64), B, 0, stream>>>(latent, WkT, kbuf, 8192, 2048, 512, 1.0f, 0, 0);
  // vT_b = WvT @ latent_b^T  (BT = latent_b), batched over z
  gemm128<bf16_t><<<dim3(32, 16, 2), B, 0, stream>>>(WvT, latent, vTb, 2048, 4096, 512, 1.0f,
                                                     (long long)4096 * 512,
                                                     (long long)2048 * 4096);
  // attention (non-split, XCD head-grouped grid)
  attn6<<<dim3(512), B, 0, stream>>>(qbuf, kbuf, vTb, aout);
  // output projection (fp32 out)
  gemm128<float><<<dim3(16, 32), B, 0, stream>>>(aout, WoT, out, 4096, 2048, 2048, 1.0f, 0, 0);
}

// Round 7
// 578.697 us; speedup vs baseline: 1.2423x; 1.0202x over previous
//
#include <hip/hip_runtime.h>
#include <hip/hip_bf16.h>

using bf16_t = __bf16;
typedef __bf16 bf16x8 __attribute__((ext_vector_type(8)));
typedef __bf16 bf16x4 __attribute__((ext_vector_type(4)));
typedef __bf16 bf16x2 __attribute__((ext_vector_type(2)));
typedef float  f32x4  __attribute__((ext_vector_type(4)));
typedef float  f32x16 __attribute__((ext_vector_type(16)));
typedef unsigned u32x4 __attribute__((ext_vector_type(4)));

#define MFMA16(a,b,c) __builtin_amdgcn_mfma_f32_16x16x32_bf16((a),(b),(c),0,0,0)
#define MFMA32(a,b,c) __builtin_amdgcn_mfma_f32_32x32x16_bf16((a),(b),(c),0,0,0)

__device__ __forceinline__ void load_lds16(const void* g, void* l) {
  __builtin_amdgcn_global_load_lds(
      (const __attribute__((address_space(1))) unsigned int*)g,
      (__attribute__((address_space(3))) unsigned int*)l, 16, 0, 0);
}

__device__ __forceinline__ unsigned pack_bf16(float a, float b) {
  union { bf16x2 v; unsigned u; } c;
  c.v[0] = (bf16_t)a; c.v[1] = (bf16_t)b;
  return c.u;
}

__device__ __forceinline__ float fast_exp2(float x) {
#if __has_builtin(__builtin_amdgcn_exp2f)
  return __builtin_amdgcn_exp2f(x);
#else
  return exp2f(x);
#endif
}

// ---------------------------------------------------------------------------
// fp32 -> bf16 elementwise convert (x). 4 elems/thread.
// ---------------------------------------------------------------------------
__global__ __launch_bounds__(256) void cvt_f2b(const float* __restrict__ in,
                                               bf16_t* __restrict__ out)
{
  const size_t i = ((size_t)blockIdx.x * 256 + threadIdx.x) * 4;
  f32x4 d = *(const f32x4*)(in + i);
  bf16x4 o;
#pragma unroll
  for (int j = 0; j < 4; ++j) o[j] = (bf16_t)d[j];
  *(bf16x4*)(out + i) = o;
}

// ---------------------------------------------------------------------------
// fp32 [R][C] -> bf16 [C][R] transposed convert (weights). 64x64 LDS tile.
// ---------------------------------------------------------------------------
__global__ __launch_bounds__(256) void cvt_transpose(const float* __restrict__ in,
                                                     bf16_t* __restrict__ out,
                                                     int R, int C)
{
  __shared__ __align__(16) bf16_t t[64 * 80];
  const int r0 = blockIdx.y * 64, c0 = blockIdx.x * 64;
  const int rr = threadIdx.x >> 4;          // 0..15
  const int c4 = (threadIdx.x & 15) * 4;    // 0..60
#pragma unroll
  for (int i = 0; i < 4; ++i) {
    const int r = rr + i * 16;
    f32x4 d = *(const f32x4*)(in + (size_t)(r0 + r) * C + c0 + c4);
#pragma unroll
    for (int j = 0; j < 4; ++j) t[(c4 + j) * 80 + r] = (bf16_t)d[j];
  }
  __syncthreads();
  const int a  = threadIdx.x >> 3;          // 0..31
  const int bc = (threadIdx.x & 7) * 8;
#pragma unroll
  for (int half = 0; half < 2; ++half) {
    const int cc = a + half * 32;
    bf16x8 d = *(const bf16x8*)&t[cc * 80 + bc];
    *(bf16x8*)(out + (size_t)(c0 + cc) * R + r0 + bc) = d;
  }
}

// ---------------------------------------------------------------------------
// m97-class GEMM: C[M,N] = A[M,K] @ B[K,N] (+scale), B given as BT[N,K].
// 128x128 tile, BK=32, 4 waves each 64x64 (4x4 of 16x16x32 MFMA).
// ---------------------------------------------------------------------------
template <typename OutT>
__global__ __launch_bounds__(256) void gemm128(const bf16_t* __restrict__ A,
                                               const bf16_t* __restrict__ BT,
                                               OutT* __restrict__ C,
                                               int M, int N, int K, float scale,
                                               long long zB, long long zC)
{
  __shared__ __align__(16) bf16_t As[128 * 32];
  __shared__ __align__(16) bf16_t Bs[128 * 32];
  const int tid = threadIdx.x;
  BT += (size_t)blockIdx.z * zB;
  C  += (size_t)blockIdx.z * zC;
  const int m0 = blockIdx.y * 128, n0 = blockIdx.x * 128;
  const int lane = tid & 63, w = tid >> 6;
  const int quad = lane >> 4, l15 = lane & 15;
  const int wm = (w >> 1) * 64, wn = (w & 1) * 64;
  const int s_row = tid >> 2;
  const int g_off = ((tid & 3) ^ (s_row & 3)) * 8;   // swizzled global chunk
  const int quadp = (quad ^ (l15 & 3)) * 8;          // swizzled frag offset
  const bf16_t* Ap0 = A  + (size_t)(m0 + s_row) * K + g_off;
  const bf16_t* Ap1 = A  + (size_t)(m0 + 64 + s_row) * K + g_off;
  const bf16_t* Bp0 = BT + (size_t)(n0 + s_row) * K + g_off;
  const bf16_t* Bp1 = BT + (size_t)(n0 + 64 + s_row) * K + g_off;

  f32x4 acc[4][4] = {};

  for (int k0 = 0; k0 < K; k0 += 32) {
    __syncthreads();
    load_lds16(Ap0 + k0, As + tid * 8);
    load_lds16(Ap1 + k0, As + tid * 8 + 2048);
    load_lds16(Bp0 + k0, Bs + tid * 8);
    load_lds16(Bp1 + k0, Bs + tid * 8 + 2048);
    __syncthreads();
    bf16x8 af[4], bfr[4];
#pragma unroll
    for (int fi = 0; fi < 4; ++fi)
      af[fi] = *(const bf16x8*)&As[(wm + fi * 16 + l15) * 32 + quadp];
#pragma unroll
    for (int fj = 0; fj < 4; ++fj)
      bfr[fj] = *(const bf16x8*)&Bs[(wn + fj * 16 + l15) * 32 + quadp];
#pragma unroll
    for (int fi = 0; fi < 4; ++fi)
#pragma unroll
      for (int fj = 0; fj < 4; ++fj)
        acc[fi][fj] = MFMA16(af[fi], bfr[fj], acc[fi][fj]);
  }

#pragma unroll
  for (int fi = 0; fi < 4; ++fi)
#pragma unroll
    for (int fj = 0; fj < 4; ++fj)
#pragma unroll
      for (int r = 0; r < 4; ++r) {
        const int row = m0 + wm + fi * 16 + quad * 4 + r;
        const int col = n0 + wn + fj * 16 + l15;
        C[(size_t)row * N + col] = (OutT)(acc[fi][fj][r] * scale);
      }
}

// ---------------------------------------------------------------------------
// latent_prev fp32 (2,2048,512) -> bf16 latent rows [0,2048) of (2,4096,512)
// ---------------------------------------------------------------------------
__global__ __launch_bounds__(256) void copy_prev_f(const float* __restrict__ prev,
                                                   bf16_t* __restrict__ latent)
{
  const size_t v    = (size_t)blockIdx.x * 256 + threadIdx.x;
  const size_t flat = v * 4;
  const size_t per  = (size_t)2048 * 512;
  const size_t b    = flat / per, rem = flat % per;
  f32x4 d = *(const f32x4*)(prev + flat);
  bf16x4 o;
#pragma unroll
  for (int j = 0; j < 4; ++j) o[j] = (bf16_t)d[j];
  *(bf16x4*)(latent + b * ((size_t)4096 * 512) + rem) = o;
}

// ---------------------------------------------------------------------------
// LayerNorm over 512 (fp32 stats), bf16 in, fp32 g/b, bf16 out into latent
// rows [2048,4096).
// ---------------------------------------------------------------------------
__global__ __launch_bounds__(256) void ln_kernel(const bf16_t* __restrict__ in,
                                                 const float* __restrict__ g_,
                                                 const float* __restrict__ b_,
                                                 bf16_t* __restrict__ latent)
{
  const int row = blockIdx.x;             // 0..4095 (= b*2048 + t)
  const int tid = threadIdx.x;
  const float x0 = (float)in[(size_t)row * 512 + tid];
  const float x1 = (float)in[(size_t)row * 512 + 256 + tid];
  float s  = x0 + x1;
  float sq = x0 * x0 + x1 * x1;
#pragma unroll
  for (int off = 1; off < 64; off <<= 1) {
    s  += __shfl_xor(s, off);
    sq += __shfl_xor(sq, off);
  }
  __shared__ float red[8];
  const int w = tid >> 6;
  if ((tid & 63) == 0) { red[w] = s; red[4 + w] = sq; }
  __syncthreads();
  s  = red[0] + red[1] + red[2] + red[3];
  sq = red[4] + red[5] + red[6] + red[7];
  const float mu   = s * (1.0f / 512.0f);
  const float var  = sq * (1.0f / 512.0f) - mu * mu;
  const float rstd = rsqrtf(var + 1e-5f);
  const int b = row >> 11, tt = row & 2047;
  bf16_t* outp = latent + ((size_t)b * 4096 + 2048 + tt) * 512;
  outp[tid]       = (bf16_t)((x0 - mu) * rstd * g_[tid]       + b_[tid]);
  outp[tid + 256] = (bf16_t)((x1 - mu) * rstd * g_[tid + 256] + b_[tid + 256]);
}

// ---------------------------------------------------------------------------
// Flash attention v7 = round-2 attn3 inner loop (fastest measured, 237us)
// with ONLY the grid mapping changed:
//   grid 512 (1D). XCD g = bid&7 owns heads {g, g+8} (L2 locality, -80%
//   FETCH). Within an XCD, j = bid>>3 in [0,64): lower half (hsel=0) gets
//   qt = j&15; upper half (hsel=1) gets qt = 15-(j&15). Under round-robin
//   dispatch, blocks j and j+32 co-reside on one CU -> each CU's pair of
//   blocks sums to exactly 98 key-tiles (34+2qt) + (64-2qt): per-CU load
//   now uniform (was pair-max up to 64 vs mean 49).
// K/V double-buffered via global_load_lds; per-lane query column; softmax
// log2 domain, defer-max THR=8, tree max, setprio on MFMA clusters.
// LDS element offsets (bf16): Ks = cur*8192, Vs = 16384 + cur*8192.
// ---------------------------------------------------------------------------
__global__ __launch_bounds__(256) void attn7(const bf16_t* __restrict__ q,
                                             const bf16_t* __restrict__ k,
                                             const bf16_t* __restrict__ vT,
                                             bf16_t* __restrict__ out)
{
  __shared__ __align__(16) bf16_t smem[32768];      // Ks0|Ks1|Vs0|Vs1 overlay

  const int tid = threadIdx.x;
  const int lane = tid & 63, w = tid >> 6;
  const int l31 = lane & 31, h5 = lane >> 5;

  // balanced XCD mapping (see header comment)
  const int g = blockIdx.x & 7, j = blockIdx.x >> 3;
  const int jl = j & 31, hsel = j >> 5;
  int qt = jl & 15;
  const int b = jl >> 4;
  if (hsel) qt = 15 - qt;
  const int h = g + 8 * hsel;

  const int q0 = qt * 128;
  const int qg = q0 + l31 * 4 + w;                  // this lane's query row

  // Q^T B-frags: B[k=feat fc*16+h5*8+j][n=q l31]
  bf16x8 qf[8];
  const bf16_t* qb = q + ((size_t)(b * 2048 + qg)) * 2048 + h * 128 + h5 * 8;
#pragma unroll
  for (int fc = 0; fc < 8; ++fc) qf[fc] = *(const bf16x8*)(qb + fc * 16);

  const bf16_t* kbase = k + ((size_t)b * 4096) * 2048 + h * 128;
  const bf16_t* vbase = vT + ((size_t)(b * 16 + h)) * 128 * 4096;

  // staging maps (slot = tid + 256p)
  int ks_key[4], ks_go[4], vs_feat[4], vs_go[4];
#pragma unroll
  for (int p = 0; p < 4; ++p) {
    const int slot = tid + 256 * p;
    const int key = slot >> 4, ph = slot & 15;
    ks_key[p] = key;
    ks_go[p]  = (((ph & 8) | ((ph & 7) ^ (key & 7)))) * 8;
    const int ft = slot >> 3, p2 = slot & 7;
    vs_feat[p] = ft;
    vs_go[p]   = (p2 ^ (ft & 7)) * 8;
  }
  // frag read offsets (elems)
  int kfo[8], vfo[4];
#pragma unroll
  for (int fc = 0; fc < 8; ++fc) {
    const int L = fc * 2 + h5;
    kfo[fc] = l31 * 128 + ((L & 8) | ((L & 7) ^ (l31 & 7))) * 8;
  }
#pragma unroll
  for (int kc = 0; kc < 4; ++kc) {
    const int L = kc * 2 + h5;
    vfo[kc] = l31 * 64 + (L ^ (l31 & 7)) * 8;
  }

  f32x16 o[4] = {};
  float m = -1e30f, l = 0.f;
  const int send = 2048 + q0 + 128;

  // prologue: stage tile 0 into buffer 0
#pragma unroll
  for (int p = 0; p < 4; ++p) {
    load_lds16(kbase + (size_t)ks_key[p] * 2048 + ks_go[p],
               smem + (tid + 256 * p) * 8);
    load_lds16(vbase + (size_t)vs_feat[p] * 4096 + vs_go[p],
               smem + 16384 + (tid + 256 * p) * 8);
  }
  __syncthreads();                                  // tile 0 resident

  int cur = 0;
  for (int s0 = 0; s0 < send; s0 += 64) {
    // stage next tile into the other buffer (DMA overlaps compute below)
    const int s1 = s0 + 64;
    if (s1 < send) {
      const int nxt = (cur ^ 1) * 8192;
#pragma unroll
      for (int p = 0; p < 4; ++p) {
        load_lds16(kbase + (size_t)(s1 + ks_key[p]) * 2048 + ks_go[p],
                   smem + nxt + (tid + 256 * p) * 8);
        load_lds16(vbase + (size_t)vs_feat[p] * 4096 + s1 + vs_go[p],
                   smem + 16384 + nxt + (tid + 256 * p) * 8);
      }
    }
    const bf16_t* Kc = smem + cur * 8192;
    const bf16_t* Vc = smem + 16384 + cur * 8192;

    // S^T tiles: rows = keys 32t + (i&3)+8*(i>>2)+4*h5, col = q = l31
    f32x16 st[2] = {};
    __builtin_amdgcn_s_setprio(1);
#pragma unroll
    for (int fc = 0; fc < 8; ++fc) {
      bf16x8 k0 = *(const bf16x8*)&Kc[kfo[fc]];
      bf16x8 k1 = *(const bf16x8*)&Kc[4096 + kfo[fc]];
      st[0] = MFMA32(k0, qf[fc], st[0]);
      st[1] = MFMA32(k1, qf[fc], st[1]);
    }
    __builtin_amdgcn_s_setprio(0);

    if (s0 + 63 > 2048 + q0) {                      // causal tail masking
#pragma unroll
      for (int t = 0; t < 2; ++t)
#pragma unroll
        for (int i = 0; i < 16; ++i) {
          const int key = s0 + 32 * t + (i & 3) + 8 * (i >> 2) + 4 * h5;
          if (key > 2048 + qg) st[t][i] = -1e30f;
        }
    }

    // tree max over this lane's 32 scores (depth 5, not 31)
    float gm[8];
#pragma unroll
    for (int t = 0; t < 2; ++t)
#pragma unroll
      for (int gg = 0; gg < 4; ++gg)
        gm[t * 4 + gg] = fmaxf(fmaxf(st[t][4 * gg + 0], st[t][4 * gg + 1]),
                               fmaxf(st[t][4 * gg + 2], st[t][4 * gg + 3]));
    float mt = fmaxf(fmaxf(fmaxf(gm[0], gm[1]), fmaxf(gm[2], gm[3])),
                     fmaxf(fmaxf(gm[4], gm[5]), fmaxf(gm[6], gm[7])));
    mt = fmaxf(mt, __shfl_xor(mt, 32));

    // defer-max: only rescale when max grew by >8 (log2 domain; p <= 2^8)
    if (__any(mt > m + 8.f)) {
      const float mnew = fmaxf(m, mt);
      const float alpha = fast_exp2(m - mnew);
#pragma unroll
      for (int ft = 0; ft < 4; ++ft)
#pragma unroll
        for (int i = 0; i < 16; ++i) o[ft][i] *= alpha;
      l *= alpha;
      m = mnew;
    }

    // exp2 + pack P into u32 pairs; group g holds keys 32t + 8g + 4h5 + 0..3
    float rs = 0.f;
    unsigned up[2][4][2];
#pragma unroll
    for (int t = 0; t < 2; ++t)
#pragma unroll
      for (int gg = 0; gg < 4; ++gg) {
        const float p0 = fast_exp2(st[t][4 * gg + 0] - m);
        const float p1 = fast_exp2(st[t][4 * gg + 1] - m);
        const float p2 = fast_exp2(st[t][4 * gg + 2] - m);
        const float p3 = fast_exp2(st[t][4 * gg + 3] - m);
        rs += (p0 + p1) + (p2 + p3);
        up[t][gg][0] = pack_bf16(p0, p1);
        up[t][gg][1] = pack_bf16(p2, p3);
      }
    rs += __shfl_xor(rs, 32);
    l += rs;

    // out^T += V^T · P^T ; P^T B-frag built in-register via half-exchange
#pragma unroll
    for (int kc = 0; kc < 4; ++kc) {
      const int t = kc >> 1, gp = (kc & 1) * 2;
      const unsigned a0 = up[t][gp][0],     a1 = up[t][gp][1];
      const unsigned b0 = up[t][gp + 1][0], b1 = up[t][gp + 1][1];
      const unsigned xa0 = __shfl_xor(a0, 32), xa1 = __shfl_xor(a1, 32);
      const unsigned xb0 = __shfl_xor(b0, 32), xb1 = __shfl_xor(b1, 32);
      u32x4 uw;
      uw[0] = h5 ? xb0 : a0;
      uw[1] = h5 ? xb1 : a1;
      uw[2] = h5 ? b0 : xa0;
      uw[3] = h5 ? b1 : xa1;
      union { u32x4 u; bf16x8 v; } pc; pc.u = uw;
      const bf16x8 pf = pc.v;
      __builtin_amdgcn_s_setprio(1);
#pragma unroll
      for (int ft = 0; ft < 4; ++ft) {
        bf16x8 vf = *(const bf16x8*)&Vc[ft * 2048 + vfo[kc]];
        o[ft] = MFMA32(vf, pf, o[ft]);
      }
      __builtin_amdgcn_s_setprio(0);
    }

    __syncthreads();   // compute reads done + next-tile DMA drained
    cur ^= 1;
  }

  // epilogue: normalize, LDS transpose, coalesced store (smem overlay)
  const float inv = 1.0f / l;
  const int rowp_w = w * 32 + l31;
#pragma unroll
  for (int ft = 0; ft < 4; ++ft)
#pragma unroll
    for (int gg = 0; gg < 4; ++gg) {
      bf16x4 pk;
#pragma unroll
      for (int r = 0; r < 4; ++r) pk[r] = (bf16_t)(o[ft][4 * gg + r] * inv);
      *(bf16x4*)&smem[rowp_w * 136 + ft * 32 + gg * 8 + h5 * 4] = pk;
    }
  __syncthreads();
#pragma unroll
  for (int p = 0; p < 8; ++p) {
    const int c = tid + 256 * p;
    const int rowp = c >> 4, chk = c & 15;
    const int ql = (rowp & 31) * 4 + (rowp >> 5);
    bf16x8 d = *(const bf16x8*)&smem[rowp * 136 + chk * 8];
    *(bf16x8*)(out + ((size_t)(b * 2048 + q0 + ql)) * 2048 + h * 128 + chk * 8) = d;
  }
}

// ---------------------------------------------------------------------------
extern "C" void kernel_launch(void* const* d_in, const int* in_sizes, int n_in,
                              void* d_out, int out_size, void* d_ws, size_t ws_size,
                              hipStream_t stream)
{
  (void)in_sizes; (void)n_in; (void)out_size; (void)ws_size;
  const float* x        = (const float*)d_in[0];
  const float* lat_prev = (const float*)d_in[1];
  const float* Wq       = (const float*)d_in[2];
  const float* Wdown    = (const float*)d_in[3];
  const float* Wk_up    = (const float*)d_in[4];
  const float* Wv_up    = (const float*)d_in[5];
  const float* ln_g     = (const float*)d_in[6];
  const float* ln_b     = (const float*)d_in[7];
  const float* Wo       = (const float*)d_in[8];
  float* out = (float*)d_out;

  char* p = (char*)d_ws;
  auto alloc = [&](size_t elems) { bf16_t* r = (bf16_t*)p; p += elems * 2; return r; };
  bf16_t* xb     = alloc((size_t)4096 * 2048);   // hosts WoT after x dead
  bf16_t* WqT    = alloc((size_t)2048 * 2048);
  bf16_t* WdT    = alloc((size_t)512 * 2048);
  bf16_t* qbuf   = alloc((size_t)4096 * 2048);
  bf16_t* latpre = alloc((size_t)4096 * 512);    // hosts WkT+WvT after LN
  bf16_t* latent = alloc((size_t)2 * 4096 * 512);
  bf16_t* kbuf   = alloc((size_t)8192 * 2048);
  bf16_t* vTb    = alloc((size_t)2 * 2048 * 4096);
  bf16_t* aout   = alloc((size_t)4096 * 2048);
  bf16_t* WoT  = xb;
  bf16_t* WkT  = latpre;
  bf16_t* WvT  = latpre + (size_t)2048 * 512;

  const dim3 B(256);
  // 1/sqrt(128) * log2(e): attention scores land in log2 domain
  const float qscale = 0.12751744561825988f;

  cvt_f2b<<<dim3(8192), B, 0, stream>>>(x, xb);
  cvt_transpose<<<dim3(32, 32), B, 0, stream>>>(Wq,    WqT, 2048, 2048);
  cvt_transpose<<<dim3(8,  32), B, 0, stream>>>(Wdown, WdT, 2048, 512);
  // q = (x@Wq) * qscale ; latpre = x@Wdown
  gemm128<bf16_t><<<dim3(16, 32), B, 0, stream>>>(xb, WqT, qbuf, 4096, 2048, 2048, qscale, 0, 0);
  gemm128<bf16_t><<<dim3(4,  32), B, 0, stream>>>(xb, WdT, latpre, 4096, 512, 2048, 1.0f, 0, 0);
  // latent cache
  copy_prev_f<<<dim3(2048), B, 0, stream>>>(lat_prev, latent);
  ln_kernel<<<dim3(4096), B, 0, stream>>>(latpre, ln_g, ln_b, latent);
  // weight transposes into dead regions (stream order enforces lifetimes)
  cvt_transpose<<<dim3(32, 32), B, 0, stream>>>(Wo,    WoT, 2048, 2048);
  cvt_transpose<<<dim3(32, 8),  B, 0, stream>>>(Wk_up, WkT, 512, 2048);
  cvt_transpose<<<dim3(32, 8),  B, 0, stream>>>(Wv_up, WvT, 512, 2048);
  // k = latent @ Wk_up  (rows b*4096+s)
  gemm128<bf16_t><<<dim3(16, 64), B, 0, stream>>>(latent, WkT, kbuf, 8192, 2048, 512, 1.0f, 0, 0);
  // vT_b = WvT @ latent_b^T  (BT = latent_b), batched over z
  gemm128<bf16_t><<<dim3(32, 16, 2), B, 0, stream>>>(WvT, latent, vTb, 2048, 4096, 512, 1.0f,
                                                     (long long)4096 * 512,
                                                     (long long)2048 * 4096);
  // attention (XCD-grouped, CU-pair-balanced grid)
  attn7<<<dim3(512), B, 0, stream>>>(qbuf, kbuf, vTb, aout);
  // output projection (fp32 out)
  gemm128<float><<<dim3(16, 32), B, 0, stream>>>(aout, WoT, out, 4096, 2048, 2048, 1.0f, 0, 0);
}

// Round 8
// 532.279 us; speedup vs baseline: 1.3506x; 1.0872x over previous
//
#include <hip/hip_runtime.h>
#include <hip/hip_bf16.h>

using bf16_t = __bf16;
typedef __bf16 bf16x8 __attribute__((ext_vector_type(8)));
typedef __bf16 bf16x4 __attribute__((ext_vector_type(4)));
typedef __bf16 bf16x2 __attribute__((ext_vector_type(2)));
typedef float  f32x4  __attribute__((ext_vector_type(4)));
typedef float  f32x16 __attribute__((ext_vector_type(16)));
typedef unsigned u32x4 __attribute__((ext_vector_type(4)));

#define MFMA16(a,b,c) __builtin_amdgcn_mfma_f32_16x16x32_bf16((a),(b),(c),0,0,0)
#define MFMA32(a,b,c) __builtin_amdgcn_mfma_f32_32x32x16_bf16((a),(b),(c),0,0,0)

__device__ __forceinline__ void load_lds16(const void* g, void* l) {
  __builtin_amdgcn_global_load_lds(
      (const __attribute__((address_space(1))) unsigned int*)g,
      (__attribute__((address_space(3))) unsigned int*)l, 16, 0, 0);
}

__device__ __forceinline__ unsigned pack_bf16(float a, float b) {
  union { bf16x2 v; unsigned u; } c;
  c.v[0] = (bf16_t)a; c.v[1] = (bf16_t)b;
  return c.u;
}

__device__ __forceinline__ float fast_exp2(float x) {
#if __has_builtin(__builtin_amdgcn_exp2f)
  return __builtin_amdgcn_exp2f(x);
#else
  return exp2f(x);
#endif
}

// XCD-chunked block remap (T1). HW round-robins linear block id across the
// 8 XCDs (xcd = id%8); remap so each XCD executes a CONTIGUOUS chunk of the
// tile space -> neighbor tiles (shared A row-panels / B col-panels) hit the
// same per-XCD L2. Exact when nwg%8==0 (all grids here); else identity.
__device__ __forceinline__ void xcd_remap(unsigned& bx, unsigned& by,
                                          unsigned& bz)
{
  const unsigned nxy = gridDim.x * gridDim.y;
  const unsigned nwg = nxy * gridDim.z;
  unsigned wg = (blockIdx.z * gridDim.y + blockIdx.y) * gridDim.x + blockIdx.x;
  if ((nwg & 7u) == 0u)
    wg = (wg & 7u) * (nwg >> 3) + (wg >> 3);
  bz = wg / nxy; wg -= bz * nxy;
  by = wg / gridDim.x;
  bx = wg - by * gridDim.x;
}

// ---------------------------------------------------------------------------
// fp32 -> bf16 elementwise convert (x). 4 elems/thread.
// ---------------------------------------------------------------------------
__global__ __launch_bounds__(256) void cvt_f2b(const float* __restrict__ in,
                                               bf16_t* __restrict__ out)
{
  const size_t i = ((size_t)blockIdx.x * 256 + threadIdx.x) * 4;
  f32x4 d = *(const f32x4*)(in + i);
  bf16x4 o;
#pragma unroll
  for (int j = 0; j < 4; ++j) o[j] = (bf16_t)d[j];
  *(bf16x4*)(out + i) = o;
}

// ---------------------------------------------------------------------------
// fp32 [R][C] -> bf16 [C][R] transposed convert (weights). 64x64 LDS tile.
// ---------------------------------------------------------------------------
__global__ __launch_bounds__(256) void cvt_transpose(const float* __restrict__ in,
                                                     bf16_t* __restrict__ out,
                                                     int R, int C)
{
  __shared__ __align__(16) bf16_t t[64 * 80];
  const int r0 = blockIdx.y * 64, c0 = blockIdx.x * 64;
  const int rr = threadIdx.x >> 4;          // 0..15
  const int c4 = (threadIdx.x & 15) * 4;    // 0..60
#pragma unroll
  for (int i = 0; i < 4; ++i) {
    const int r = rr + i * 16;
    f32x4 d = *(const f32x4*)(in + (size_t)(r0 + r) * C + c0 + c4);
#pragma unroll
    for (int j = 0; j < 4; ++j) t[(c4 + j) * 80 + r] = (bf16_t)d[j];
  }
  __syncthreads();
  const int a  = threadIdx.x >> 3;          // 0..31
  const int bc = (threadIdx.x & 7) * 8;
#pragma unroll
  for (int half = 0; half < 2; ++half) {
    const int cc = a + half * 32;
    bf16x8 d = *(const bf16x8*)&t[cc * 80 + bc];
    *(bf16x8*)(out + (size_t)(c0 + cc) * R + r0 + bc) = d;
  }
}

// ---------------------------------------------------------------------------
// m97-class GEMM: C[M,N] = A[M,K] @ B[K,N] (+scale), B given as BT[N,K].
// 128x128 tile, BK=32, 4 waves each 64x64 (4x4 of 16x16x32 MFMA).
// XCD-chunked block swizzle for per-XCD L2 panel reuse.
// ---------------------------------------------------------------------------
template <typename OutT>
__global__ __launch_bounds__(256) void gemm128(const bf16_t* __restrict__ A,
                                               const bf16_t* __restrict__ BT,
                                               OutT* __restrict__ C,
                                               int M, int N, int K, float scale,
                                               long long zB, long long zC)
{
  __shared__ __align__(16) bf16_t As[128 * 32];
  __shared__ __align__(16) bf16_t Bs[128 * 32];
  const int tid = threadIdx.x;
  unsigned bx, by, bz;
  xcd_remap(bx, by, bz);
  BT += (size_t)bz * zB;
  C  += (size_t)bz * zC;
  const int m0 = by * 128, n0 = bx * 128;
  const int lane = tid & 63, w = tid >> 6;
  const int quad = lane >> 4, l15 = lane & 15;
  const int wm = (w >> 1) * 64, wn = (w & 1) * 64;
  const int s_row = tid >> 2;
  const int g_off = ((tid & 3) ^ (s_row & 3)) * 8;   // swizzled global chunk
  const int quadp = (quad ^ (l15 & 3)) * 8;          // swizzled frag offset
  const bf16_t* Ap0 = A  + (size_t)(m0 + s_row) * K + g_off;
  const bf16_t* Ap1 = A  + (size_t)(m0 + 64 + s_row) * K + g_off;
  const bf16_t* Bp0 = BT + (size_t)(n0 + s_row) * K + g_off;
  const bf16_t* Bp1 = BT + (size_t)(n0 + 64 + s_row) * K + g_off;

  f32x4 acc[4][4] = {};

  for (int k0 = 0; k0 < K; k0 += 32) {
    __syncthreads();
    load_lds16(Ap0 + k0, As + tid * 8);
    load_lds16(Ap1 + k0, As + tid * 8 + 2048);
    load_lds16(Bp0 + k0, Bs + tid * 8);
    load_lds16(Bp1 + k0, Bs + tid * 8 + 2048);
    __syncthreads();
    bf16x8 af[4], bfr[4];
#pragma unroll
    for (int fi = 0; fi < 4; ++fi)
      af[fi] = *(const bf16x8*)&As[(wm + fi * 16 + l15) * 32 + quadp];
#pragma unroll
    for (int fj = 0; fj < 4; ++fj)
      bfr[fj] = *(const bf16x8*)&Bs[(wn + fj * 16 + l15) * 32 + quadp];
#pragma unroll
    for (int fi = 0; fi < 4; ++fi)
#pragma unroll
      for (int fj = 0; fj < 4; ++fj)
        acc[fi][fj] = MFMA16(af[fi], bfr[fj], acc[fi][fj]);
  }

#pragma unroll
  for (int fi = 0; fi < 4; ++fi)
#pragma unroll
    for (int fj = 0; fj < 4; ++fj)
#pragma unroll
      for (int r = 0; r < 4; ++r) {
        const int row = m0 + wm + fi * 16 + quad * 4 + r;
        const int col = n0 + wn + fj * 16 + l15;
        C[(size_t)row * N + col] = (OutT)(acc[fi][fj][r] * scale);
      }
}

// ---------------------------------------------------------------------------
// Fused q + latpre GEMM: A[4096,2048] @ [WqT;WdT] (stacked BT, 2560 rows).
// n-tiles 0..15 -> qbuf (stride 2048, *qscale); 16..19 -> latpre (stride 512).
// Fills the GPU for the latpre columns (was a separate 128-block launch).
// ---------------------------------------------------------------------------
__global__ __launch_bounds__(256) void gemm128_dual(const bf16_t* __restrict__ A,
                                                    const bf16_t* __restrict__ BT,
                                                    bf16_t* __restrict__ C1,
                                                    bf16_t* __restrict__ C2,
                                                    float qscale)
{
  __shared__ __align__(16) bf16_t As[128 * 32];
  __shared__ __align__(16) bf16_t Bs[128 * 32];
  const int tid = threadIdx.x;
  unsigned bx, by, bz;
  xcd_remap(bx, by, bz);
  const int K = 2048;
  const int m0 = by * 128, n0 = bx * 128;
  const int lane = tid & 63, w = tid >> 6;
  const int quad = lane >> 4, l15 = lane & 15;
  const int wm = (w >> 1) * 64, wn = (w & 1) * 64;
  const int s_row = tid >> 2;
  const int g_off = ((tid & 3) ^ (s_row & 3)) * 8;
  const int quadp = (quad ^ (l15 & 3)) * 8;
  const bf16_t* Ap0 = A  + (size_t)(m0 + s_row) * K + g_off;
  const bf16_t* Ap1 = A  + (size_t)(m0 + 64 + s_row) * K + g_off;
  const bf16_t* Bp0 = BT + (size_t)(n0 + s_row) * K + g_off;
  const bf16_t* Bp1 = BT + (size_t)(n0 + 64 + s_row) * K + g_off;

  f32x4 acc[4][4] = {};

  for (int k0 = 0; k0 < K; k0 += 32) {
    __syncthreads();
    load_lds16(Ap0 + k0, As + tid * 8);
    load_lds16(Ap1 + k0, As + tid * 8 + 2048);
    load_lds16(Bp0 + k0, Bs + tid * 8);
    load_lds16(Bp1 + k0, Bs + tid * 8 + 2048);
    __syncthreads();
    bf16x8 af[4], bfr[4];
#pragma unroll
    for (int fi = 0; fi < 4; ++fi)
      af[fi] = *(const bf16x8*)&As[(wm + fi * 16 + l15) * 32 + quadp];
#pragma unroll
    for (int fj = 0; fj < 4; ++fj)
      bfr[fj] = *(const bf16x8*)&Bs[(wn + fj * 16 + l15) * 32 + quadp];
#pragma unroll
    for (int fi = 0; fi < 4; ++fi)
#pragma unroll
      for (int fj = 0; fj < 4; ++fj)
        acc[fi][fj] = MFMA16(af[fi], bfr[fj], acc[fi][fj]);
  }

  const bool isQ = (n0 < 2048);            // block-uniform
  const float sc = isQ ? qscale : 1.0f;
#pragma unroll
  for (int fi = 0; fi < 4; ++fi)
#pragma unroll
    for (int fj = 0; fj < 4; ++fj)
#pragma unroll
      for (int r = 0; r < 4; ++r) {
        const int row = m0 + wm + fi * 16 + quad * 4 + r;
        const int col = n0 + wn + fj * 16 + l15;
        if (isQ)
          C1[(size_t)row * 2048 + col] = (bf16_t)(acc[fi][fj][r] * sc);
        else
          C2[(size_t)row * 512 + (col - 2048)] = (bf16_t)(acc[fi][fj][r] * sc);
      }
}

// ---------------------------------------------------------------------------
// latent_prev fp32 (2,2048,512) -> bf16 latent rows [0,2048) of (2,4096,512)
// ---------------------------------------------------------------------------
__global__ __launch_bounds__(256) void copy_prev_f(const float* __restrict__ prev,
                                                   bf16_t* __restrict__ latent)
{
  const size_t v    = (size_t)blockIdx.x * 256 + threadIdx.x;
  const size_t flat = v * 4;
  const size_t per  = (size_t)2048 * 512;
  const size_t b    = flat / per, rem = flat % per;
  f32x4 d = *(const f32x4*)(prev + flat);
  bf16x4 o;
#pragma unroll
  for (int j = 0; j < 4; ++j) o[j] = (bf16_t)d[j];
  *(bf16x4*)(latent + b * ((size_t)4096 * 512) + rem) = o;
}

// ---------------------------------------------------------------------------
// LayerNorm over 512 (fp32 stats), bf16 in, fp32 g/b, bf16 out into latent
// rows [2048,4096).
// ---------------------------------------------------------------------------
__global__ __launch_bounds__(256) void ln_kernel(const bf16_t* __restrict__ in,
                                                 const float* __restrict__ g_,
                                                 const float* __restrict__ b_,
                                                 bf16_t* __restrict__ latent)
{
  const int row = blockIdx.x;             // 0..4095 (= b*2048 + t)
  const int tid = threadIdx.x;
  const float x0 = (float)in[(size_t)row * 512 + tid];
  const float x1 = (float)in[(size_t)row * 512 + 256 + tid];
  float s  = x0 + x1;
  float sq = x0 * x0 + x1 * x1;
#pragma unroll
  for (int off = 1; off < 64; off <<= 1) {
    s  += __shfl_xor(s, off);
    sq += __shfl_xor(sq, off);
  }
  __shared__ float red[8];
  const int w = tid >> 6;
  if ((tid & 63) == 0) { red[w] = s; red[4 + w] = sq; }
  __syncthreads();
  s  = red[0] + red[1] + red[2] + red[3];
  sq = red[4] + red[5] + red[6] + red[7];
  const float mu   = s * (1.0f / 512.0f);
  const float var  = sq * (1.0f / 512.0f) - mu * mu;
  const float rstd = rsqrtf(var + 1e-5f);
  const int b = row >> 11, tt = row & 2047;
  bf16_t* outp = latent + ((size_t)b * 4096 + 2048 + tt) * 512;
  outp[tid]       = (bf16_t)((x0 - mu) * rstd * g_[tid]       + b_[tid]);
  outp[tid + 256] = (bf16_t)((x1 - mu) * rstd * g_[tid + 256] + b_[tid + 256]);
}

// ---------------------------------------------------------------------------
// Flash attention v7 (round-7 kernel, 237.5us measured, UNCHANGED).
// ---------------------------------------------------------------------------
__global__ __launch_bounds__(256) void attn7(const bf16_t* __restrict__ q,
                                             const bf16_t* __restrict__ k,
                                             const bf16_t* __restrict__ vT,
                                             bf16_t* __restrict__ out)
{
  __shared__ __align__(16) bf16_t smem[32768];      // Ks0|Ks1|Vs0|Vs1 overlay

  const int tid = threadIdx.x;
  const int lane = tid & 63, w = tid >> 6;
  const int l31 = lane & 31, h5 = lane >> 5;

  // balanced XCD mapping
  const int g = blockIdx.x & 7, j = blockIdx.x >> 3;
  const int jl = j & 31, hsel = j >> 5;
  int qt = jl & 15;
  const int b = jl >> 4;
  if (hsel) qt = 15 - qt;
  const int h = g + 8 * hsel;

  const int q0 = qt * 128;
  const int qg = q0 + l31 * 4 + w;                  // this lane's query row

  // Q^T B-frags: B[k=feat fc*16+h5*8+j][n=q l31]
  bf16x8 qf[8];
  const bf16_t* qb = q + ((size_t)(b * 2048 + qg)) * 2048 + h * 128 + h5 * 8;
#pragma unroll
  for (int fc = 0; fc < 8; ++fc) qf[fc] = *(const bf16x8*)(qb + fc * 16);

  const bf16_t* kbase = k + ((size_t)b * 4096) * 2048 + h * 128;
  const bf16_t* vbase = vT + ((size_t)(b * 16 + h)) * 128 * 4096;

  // staging maps (slot = tid + 256p)
  int ks_key[4], ks_go[4], vs_feat[4], vs_go[4];
#pragma unroll
  for (int p = 0; p < 4; ++p) {
    const int slot = tid + 256 * p;
    const int key = slot >> 4, ph = slot & 15;
    ks_key[p] = key;
    ks_go[p]  = (((ph & 8) | ((ph & 7) ^ (key & 7)))) * 8;
    const int ft = slot >> 3, p2 = slot & 7;
    vs_feat[p] = ft;
    vs_go[p]   = (p2 ^ (ft & 7)) * 8;
  }
  // frag read offsets (elems)
  int kfo[8], vfo[4];
#pragma unroll
  for (int fc = 0; fc < 8; ++fc) {
    const int L = fc * 2 + h5;
    kfo[fc] = l31 * 128 + ((L & 8) | ((L & 7) ^ (l31 & 7))) * 8;
  }
#pragma unroll
  for (int kc = 0; kc < 4; ++kc) {
    const int L = kc * 2 + h5;
    vfo[kc] = l31 * 64 + (L ^ (l31 & 7)) * 8;
  }

  f32x16 o[4] = {};
  float m = -1e30f, l = 0.f;
  const int send = 2048 + q0 + 128;

  // prologue: stage tile 0 into buffer 0
#pragma unroll
  for (int p = 0; p < 4; ++p) {
    load_lds16(kbase + (size_t)ks_key[p] * 2048 + ks_go[p],
               smem + (tid + 256 * p) * 8);
    load_lds16(vbase + (size_t)vs_feat[p] * 4096 + vs_go[p],
               smem + 16384 + (tid + 256 * p) * 8);
  }
  __syncthreads();                                  // tile 0 resident

  int cur = 0;
  for (int s0 = 0; s0 < send; s0 += 64) {
    // stage next tile into the other buffer (DMA overlaps compute below)
    const int s1 = s0 + 64;
    if (s1 < send) {
      const int nxt = (cur ^ 1) * 8192;
#pragma unroll
      for (int p = 0; p < 4; ++p) {
        load_lds16(kbase + (size_t)(s1 + ks_key[p]) * 2048 + ks_go[p],
                   smem + nxt + (tid + 256 * p) * 8);
        load_lds16(vbase + (size_t)vs_feat[p] * 4096 + s1 + vs_go[p],
                   smem + 16384 + nxt + (tid + 256 * p) * 8);
      }
    }
    const bf16_t* Kc = smem + cur * 8192;
    const bf16_t* Vc = smem + 16384 + cur * 8192;

    // S^T tiles: rows = keys 32t + (i&3)+8*(i>>2)+4*h5, col = q = l31
    f32x16 st[2] = {};
    __builtin_amdgcn_s_setprio(1);
#pragma unroll
    for (int fc = 0; fc < 8; ++fc) {
      bf16x8 k0 = *(const bf16x8*)&Kc[kfo[fc]];
      bf16x8 k1 = *(const bf16x8*)&Kc[4096 + kfo[fc]];
      st[0] = MFMA32(k0, qf[fc], st[0]);
      st[1] = MFMA32(k1, qf[fc], st[1]);
    }
    __builtin_amdgcn_s_setprio(0);

    if (s0 + 63 > 2048 + q0) {                      // causal tail masking
#pragma unroll
      for (int t = 0; t < 2; ++t)
#pragma unroll
        for (int i = 0; i < 16; ++i) {
          const int key = s0 + 32 * t + (i & 3) + 8 * (i >> 2) + 4 * h5;
          if (key > 2048 + qg) st[t][i] = -1e30f;
        }
    }

    // tree max over this lane's 32 scores (depth 5)
    float gm[8];
#pragma unroll
    for (int t = 0; t < 2; ++t)
#pragma unroll
      for (int gg = 0; gg < 4; ++gg)
        gm[t * 4 + gg] = fmaxf(fmaxf(st[t][4 * gg + 0], st[t][4 * gg + 1]),
                               fmaxf(st[t][4 * gg + 2], st[t][4 * gg + 3]));
    float mt = fmaxf(fmaxf(fmaxf(gm[0], gm[1]), fmaxf(gm[2], gm[3])),
                     fmaxf(fmaxf(gm[4], gm[5]), fmaxf(gm[6], gm[7])));
    mt = fmaxf(mt, __shfl_xor(mt, 32));

    // defer-max: only rescale when max grew by >8 (log2 domain; p <= 2^8)
    if (__any(mt > m + 8.f)) {
      const float mnew = fmaxf(m, mt);
      const float alpha = fast_exp2(m - mnew);
#pragma unroll
      for (int ft = 0; ft < 4; ++ft)
#pragma unroll
        for (int i = 0; i < 16; ++i) o[ft][i] *= alpha;
      l *= alpha;
      m = mnew;
    }

    // exp2 + pack P into u32 pairs; group g holds keys 32t + 8g + 4h5 + 0..3
    float rs = 0.f;
    unsigned up[2][4][2];
#pragma unroll
    for (int t = 0; t < 2; ++t)
#pragma unroll
      for (int gg = 0; gg < 4; ++gg) {
        const float p0 = fast_exp2(st[t][4 * gg + 0] - m);
        const float p1 = fast_exp2(st[t][4 * gg + 1] - m);
        const float p2 = fast_exp2(st[t][4 * gg + 2] - m);
        const float p3 = fast_exp2(st[t][4 * gg + 3] - m);
        rs += (p0 + p1) + (p2 + p3);
        up[t][gg][0] = pack_bf16(p0, p1);
        up[t][gg][1] = pack_bf16(p2, p3);
      }
    rs += __shfl_xor(rs, 32);
    l += rs;

    // out^T += V^T · P^T ; P^T B-frag built in-register via half-exchange
#pragma unroll
    for (int kc = 0; kc < 4; ++kc) {
      const int t = kc >> 1, gp = (kc & 1) * 2;
      const unsigned a0 = up[t][gp][0],     a1 = up[t][gp][1];
      const unsigned b0 = up[t][gp + 1][0], b1 = up[t][gp + 1][1];
      const unsigned xa0 = __shfl_xor(a0, 32), xa1 = __shfl_xor(a1, 32);
      const unsigned xb0 = __shfl_xor(b0, 32), xb1 = __shfl_xor(b1, 32);
      u32x4 uw;
      uw[0] = h5 ? xb0 : a0;
      uw[1] = h5 ? xb1 : a1;
      uw[2] = h5 ? b0 : xa0;
      uw[3] = h5 ? b1 : xa1;
      union { u32x4 u; bf16x8 v; } pc; pc.u = uw;
      const bf16x8 pf = pc.v;
      __builtin_amdgcn_s_setprio(1);
#pragma unroll
      for (int ft = 0; ft < 4; ++ft) {
        bf16x8 vf = *(const bf16x8*)&Vc[ft * 2048 + vfo[kc]];
        o[ft] = MFMA32(vf, pf, o[ft]);
      }
      __builtin_amdgcn_s_setprio(0);
    }

    __syncthreads();   // compute reads done + next-tile DMA drained
    cur ^= 1;
  }

  // epilogue: normalize, LDS transpose, coalesced store (smem overlay)
  const float inv = 1.0f / l;
  const int rowp_w = w * 32 + l31;
#pragma unroll
  for (int ft = 0; ft < 4; ++ft)
#pragma unroll
    for (int gg = 0; gg < 4; ++gg) {
      bf16x4 pk;
#pragma unroll
      for (int r = 0; r < 4; ++r) pk[r] = (bf16_t)(o[ft][4 * gg + r] * inv);
      *(bf16x4*)&smem[rowp_w * 136 + ft * 32 + gg * 8 + h5 * 4] = pk;
    }
  __syncthreads();
#pragma unroll
  for (int p = 0; p < 8; ++p) {
    const int c = tid + 256 * p;
    const int rowp = c >> 4, chk = c & 15;
    const int ql = (rowp & 31) * 4 + (rowp >> 5);
    bf16x8 d = *(const bf16x8*)&smem[rowp * 136 + chk * 8];
    *(bf16x8*)(out + ((size_t)(b * 2048 + q0 + ql)) * 2048 + h * 128 + chk * 8) = d;
  }
}

// ---------------------------------------------------------------------------
extern "C" void kernel_launch(void* const* d_in, const int* in_sizes, int n_in,
                              void* d_out, int out_size, void* d_ws, size_t ws_size,
                              hipStream_t stream)
{
  (void)in_sizes; (void)n_in; (void)out_size; (void)ws_size;
  const float* x        = (const float*)d_in[0];
  const float* lat_prev = (const float*)d_in[1];
  const float* Wq       = (const float*)d_in[2];
  const float* Wdown    = (const float*)d_in[3];
  const float* Wk_up    = (const float*)d_in[4];
  const float* Wv_up    = (const float*)d_in[5];
  const float* ln_g     = (const float*)d_in[6];
  const float* ln_b     = (const float*)d_in[7];
  const float* Wo       = (const float*)d_in[8];
  float* out = (float*)d_out;

  char* p = (char*)d_ws;
  auto alloc = [&](size_t elems) { bf16_t* r = (bf16_t*)p; p += elems * 2; return r; };
  bf16_t* xb     = alloc((size_t)4096 * 2048);   // hosts WoT after x dead
  bf16_t* WqT    = alloc((size_t)2048 * 2048);   // WqT+WdT contiguous: stacked BT
  bf16_t* WdT    = alloc((size_t)512 * 2048);
  bf16_t* qbuf   = alloc((size_t)4096 * 2048);
  bf16_t* latpre = alloc((size_t)4096 * 512);    // hosts WkT+WvT after LN
  bf16_t* latent = alloc((size_t)2 * 4096 * 512);
  bf16_t* kbuf   = alloc((size_t)8192 * 2048);
  bf16_t* vTb    = alloc((size_t)2 * 2048 * 4096);
  bf16_t* aout   = alloc((size_t)4096 * 2048);
  bf16_t* WoT  = xb;
  bf16_t* WkT  = latpre;
  bf16_t* WvT  = latpre + (size_t)2048 * 512;

  const dim3 B(256);
  // 1/sqrt(128) * log2(e): attention scores land in log2 domain
  const float qscale = 0.12751744561825988f;

  cvt_f2b<<<dim3(8192), B, 0, stream>>>(x, xb);
  cvt_transpose<<<dim3(32, 32), B, 0, stream>>>(Wq,    WqT, 2048, 2048);
  cvt_transpose<<<dim3(8,  32), B, 0, stream>>>(Wdown, WdT, 2048, 512);
  // fused: q = (x@Wq)*qscale ; latpre = x@Wdown  (stacked BT = [WqT;WdT])
  gemm128_dual<<<dim3(20, 32), B, 0, stream>>>(xb, WqT, qbuf, latpre, qscale);
  // latent cache
  copy_prev_f<<<dim3(2048), B, 0, stream>>>(lat_prev, latent);
  ln_kernel<<<dim3(4096), B, 0, stream>>>(latpre, ln_g, ln_b, latent);
  // weight transposes into dead regions (stream order enforces lifetimes)
  cvt_transpose<<<dim3(32, 32), B, 0, stream>>>(Wo,    WoT, 2048, 2048);
  cvt_transpose<<<dim3(32, 8),  B, 0, stream>>>(Wk_up, WkT, 512, 2048);
  cvt_transpose<<<dim3(32, 8),  B, 0, stream>>>(Wv_up, WvT, 512, 2048);
  // k = latent @ Wk_up  (rows b*4096+s)
  gemm128<bf16_t><<<dim3(16, 64), B, 0, stream>>>(latent, WkT, kbuf, 8192, 2048, 512, 1.0f, 0, 0);
  // vT_b = WvT @ latent_b^T  (BT = latent_b), batched over z
  gemm128<bf16_t><<<dim3(32, 16, 2), B, 0, stream>>>(WvT, latent, vTb, 2048, 4096, 512, 1.0f,
                                                     (long long)4096 * 512,
                                                     (long long)2048 * 4096);
  // attention (XCD-grouped, CU-pair-balanced grid) — unchanged
  attn7<<<dim3(512), B, 0, stream>>>(qbuf, kbuf, vTb, aout);
  // output projection (fp32 out)
  gemm128<float><<<dim3(16, 32), B, 0, stream>>>(aout, WoT, out, 4096, 2048, 2048, 1.0f, 0, 0);
}

// Round 10
// 530.453 us; speedup vs baseline: 1.3552x; 1.0034x over previous
//
#include <hip/hip_runtime.h>
#include <hip/hip_bf16.h>

using bf16_t = __bf16;
typedef __bf16 bf16x8 __attribute__((ext_vector_type(8)));
typedef __bf16 bf16x4 __attribute__((ext_vector_type(4)));
typedef __bf16 bf16x2 __attribute__((ext_vector_type(2)));
typedef float  f32x4  __attribute__((ext_vector_type(4)));
typedef float  f32x16 __attribute__((ext_vector_type(16)));
typedef unsigned u32x4 __attribute__((ext_vector_type(4)));

#define MFMA16(a,b,c) __builtin_amdgcn_mfma_f32_16x16x32_bf16((a),(b),(c),0,0,0)
#define MFMA32(a,b,c) __builtin_amdgcn_mfma_f32_32x32x16_bf16((a),(b),(c),0,0,0)

__device__ __forceinline__ void load_lds16(const void* g, void* l) {
  __builtin_amdgcn_global_load_lds(
      (const __attribute__((address_space(1))) unsigned int*)g,
      (__attribute__((address_space(3))) unsigned int*)l, 16, 0, 0);
}

__device__ __forceinline__ unsigned pack_bf16(float a, float b) {
  union { bf16x2 v; unsigned u; } c;
  c.v[0] = (bf16_t)a; c.v[1] = (bf16_t)b;
  return c.u;
}

__device__ __forceinline__ float fast_exp2(float x) {
#if __has_builtin(__builtin_amdgcn_exp2f)
  return __builtin_amdgcn_exp2f(x);
#else
  return exp2f(x);
#endif
}

// XCD-chunked block remap (T1). HW round-robins linear block id across the
// 8 XCDs (xcd = id%8); remap so each XCD executes a CONTIGUOUS chunk of the
// tile space -> neighbor tiles (shared A row-panels / B col-panels) hit the
// same per-XCD L2. Exact when nwg%8==0 (all grids here); else identity.
__device__ __forceinline__ void xcd_remap(unsigned& bx, unsigned& by,
                                          unsigned& bz)
{
  const unsigned nxy = gridDim.x * gridDim.y;
  const unsigned nwg = nxy * gridDim.z;
  unsigned wg = (blockIdx.z * gridDim.y + blockIdx.y) * gridDim.x + blockIdx.x;
  if ((nwg & 7u) == 0u)
    wg = (wg & 7u) * (nwg >> 3) + (wg >> 3);
  bz = wg / nxy; wg -= bz * nxy;
  by = wg / gridDim.x;
  bx = wg - by * gridDim.x;
}

// ---------------------------------------------------------------------------
// fp32 -> bf16 elementwise convert (x). 4 elems/thread.
// ---------------------------------------------------------------------------
__global__ __launch_bounds__(256) void cvt_f2b(const float* __restrict__ in,
                                               bf16_t* __restrict__ out)
{
  const size_t i = ((size_t)blockIdx.x * 256 + threadIdx.x) * 4;
  f32x4 d = *(const f32x4*)(in + i);
  bf16x4 o;
#pragma unroll
  for (int j = 0; j < 4; ++j) o[j] = (bf16_t)d[j];
  *(bf16x4*)(out + i) = o;
}

// ---------------------------------------------------------------------------
// fp32 [R][C] -> bf16 [C][R] transposed convert (weights). 64x64 LDS tile.
// ---------------------------------------------------------------------------
__global__ __launch_bounds__(256) void cvt_transpose(const float* __restrict__ in,
                                                     bf16_t* __restrict__ out,
                                                     int R, int C)
{
  __shared__ __align__(16) bf16_t t[64 * 80];
  const int r0 = blockIdx.y * 64, c0 = blockIdx.x * 64;
  const int rr = threadIdx.x >> 4;          // 0..15
  const int c4 = (threadIdx.x & 15) * 4;    // 0..60
#pragma unroll
  for (int i = 0; i < 4; ++i) {
    const int r = rr + i * 16;
    f32x4 d = *(const f32x4*)(in + (size_t)(r0 + r) * C + c0 + c4);
#pragma unroll
    for (int j = 0; j < 4; ++j) t[(c4 + j) * 80 + r] = (bf16_t)d[j];
  }
  __syncthreads();
  const int a  = threadIdx.x >> 3;          // 0..31
  const int bc = (threadIdx.x & 7) * 8;
#pragma unroll
  for (int half = 0; half < 2; ++half) {
    const int cc = a + half * 32;
    bf16x8 d = *(const bf16x8*)&t[cc * 80 + bc];
    *(bf16x8*)(out + (size_t)(c0 + cc) * R + r0 + bc) = d;
  }
}

// ---------------------------------------------------------------------------
// m97-class GEMM, BK=64: C[M,N] = A[M,K] @ B[K,N] (+scale), B as BT[N,K].
// 128x128 tile, 4 waves each 64x64 (4x4 of 16x16x32 MFMA), two MFMA
// sub-steps per staged tile (halves barrier count vs BK=32; frags scoped
// per sub-step so VGPR profile is unchanged; LDS 32KB/block).
// Staging swizzle: LDS(row, c) holds global chunk c^(row&7) (src-side
// pre-swizzle, linear LDS dest); frag read at chunk (kk*4+quad)^(l15&7).
// XCD-chunked block swizzle for per-XCD L2 panel reuse.
// ---------------------------------------------------------------------------
template <typename OutT>
__global__ __launch_bounds__(256) void gemm128(const bf16_t* __restrict__ A,
                                               const bf16_t* __restrict__ BT,
                                               OutT* __restrict__ C,
                                               int M, int N, int K, float scale,
                                               long long zB, long long zC)
{
  __shared__ __align__(16) bf16_t As[128 * 64];
  __shared__ __align__(16) bf16_t Bs[128 * 64];
  const int tid = threadIdx.x;
  unsigned bx, by, bz;
  xcd_remap(bx, by, bz);
  BT += (size_t)bz * zB;
  C  += (size_t)bz * zC;
  const int m0 = by * 128, n0 = bx * 128;
  const int lane = tid & 63, w = tid >> 6;
  const int quad = lane >> 4, l15 = lane & 15;
  const int wm = (w >> 1) * 64, wn = (w & 1) * 64;
  const int s_row = tid >> 3;                        // 0..31 (+32p)
  const int g_off = ((tid & 7) ^ (s_row & 7)) * 8;   // swizzled source chunk
  const bf16_t* Ap = A  + (size_t)(m0 + s_row) * K + g_off;
  const bf16_t* Bp = BT + (size_t)(n0 + s_row) * K + g_off;
  const int cpos0 = (quad ^ (l15 & 7)) * 8;          // kk=0 frag chunk
  const int cpos1 = ((4 + quad) ^ (l15 & 7)) * 8;    // kk=1 frag chunk

  f32x4 acc[4][4] = {};

  for (int k0 = 0; k0 < K; k0 += 64) {
    __syncthreads();
#pragma unroll
    for (int p = 0; p < 4; ++p) {
      load_lds16(Ap + (size_t)(32 * p) * K + k0, As + (tid + 256 * p) * 8);
      load_lds16(Bp + (size_t)(32 * p) * K + k0, Bs + (tid + 256 * p) * 8);
    }
    __syncthreads();
#pragma unroll
    for (int kk = 0; kk < 2; ++kk) {
      const int cp = kk ? cpos1 : cpos0;
      bf16x8 af[4], bfr[4];
#pragma unroll
      for (int fi = 0; fi < 4; ++fi)
        af[fi] = *(const bf16x8*)&As[(wm + fi * 16 + l15) * 64 + cp];
#pragma unroll
      for (int fj = 0; fj < 4; ++fj)
        bfr[fj] = *(const bf16x8*)&Bs[(wn + fj * 16 + l15) * 64 + cp];
#pragma unroll
      for (int fi = 0; fi < 4; ++fi)
#pragma unroll
        for (int fj = 0; fj < 4; ++fj)
          acc[fi][fj] = MFMA16(af[fi], bfr[fj], acc[fi][fj]);
    }
  }

#pragma unroll
  for (int fi = 0; fi < 4; ++fi)
#pragma unroll
    for (int fj = 0; fj < 4; ++fj)
#pragma unroll
      for (int r = 0; r < 4; ++r) {
        const int row = m0 + wm + fi * 16 + quad * 4 + r;
        const int col = n0 + wn + fj * 16 + l15;
        C[(size_t)row * N + col] = (OutT)(acc[fi][fj][r] * scale);
      }
}

// ---------------------------------------------------------------------------
// Fused q + latpre GEMM (BK=64 body): A[4096,2048] @ [WqT;WdT] (2560 rows).
// n-tiles 0..15 -> qbuf (stride 2048, *qscale); 16..19 -> latpre (stride 512).
// ---------------------------------------------------------------------------
__global__ __launch_bounds__(256) void gemm128_dual(const bf16_t* __restrict__ A,
                                                    const bf16_t* __restrict__ BT,
                                                    bf16_t* __restrict__ C1,
                                                    bf16_t* __restrict__ C2,
                                                    float qscale)
{
  __shared__ __align__(16) bf16_t As[128 * 64];
  __shared__ __align__(16) bf16_t Bs[128 * 64];
  const int tid = threadIdx.x;
  unsigned bx, by, bz;
  xcd_remap(bx, by, bz);
  const int K = 2048;
  const int m0 = by * 128, n0 = bx * 128;
  const int lane = tid & 63, w = tid >> 6;
  const int quad = lane >> 4, l15 = lane & 15;
  const int wm = (w >> 1) * 64, wn = (w & 1) * 64;
  const int s_row = tid >> 3;
  const int g_off = ((tid & 7) ^ (s_row & 7)) * 8;
  const bf16_t* Ap = A  + (size_t)(m0 + s_row) * K + g_off;
  const bf16_t* Bp = BT + (size_t)(n0 + s_row) * K + g_off;
  const int cpos0 = (quad ^ (l15 & 7)) * 8;
  const int cpos1 = ((4 + quad) ^ (l15 & 7)) * 8;

  f32x4 acc[4][4] = {};

  for (int k0 = 0; k0 < K; k0 += 64) {
    __syncthreads();
#pragma unroll
    for (int p = 0; p < 4; ++p) {
      load_lds16(Ap + (size_t)(32 * p) * K + k0, As + (tid + 256 * p) * 8);
      load_lds16(Bp + (size_t)(32 * p) * K + k0, Bs + (tid + 256 * p) * 8);
    }
    __syncthreads();
#pragma unroll
    for (int kk = 0; kk < 2; ++kk) {
      const int cp = kk ? cpos1 : cpos0;
      bf16x8 af[4], bfr[4];
#pragma unroll
      for (int fi = 0; fi < 4; ++fi)
        af[fi] = *(const bf16x8*)&As[(wm + fi * 16 + l15) * 64 + cp];
#pragma unroll
      for (int fj = 0; fj < 4; ++fj)
        bfr[fj] = *(const bf16x8*)&Bs[(wn + fj * 16 + l15) * 64 + cp];
#pragma unroll
      for (int fi = 0; fi < 4; ++fi)
#pragma unroll
        for (int fj = 0; fj < 4; ++fj)
          acc[fi][fj] = MFMA16(af[fi], bfr[fj], acc[fi][fj]);
    }
  }

  const bool isQ = (n0 < 2048);            // block-uniform
  const float sc = isQ ? qscale : 1.0f;
#pragma unroll
  for (int fi = 0; fi < 4; ++fi)
#pragma unroll
    for (int fj = 0; fj < 4; ++fj)
#pragma unroll
      for (int r = 0; r < 4; ++r) {
        const int row = m0 + wm + fi * 16 + quad * 4 + r;
        const int col = n0 + wn + fj * 16 + l15;
        if (isQ)
          C1[(size_t)row * 2048 + col] = (bf16_t)(acc[fi][fj][r] * sc);
        else
          C2[(size_t)row * 512 + (col - 2048)] = (bf16_t)(acc[fi][fj][r] * sc);
      }
}

// ---------------------------------------------------------------------------
// Fused: blocks [0,4096): LayerNorm over 512 (bf16 in, fp32 g/b) -> latent
// rows [2048,4096). Blocks [4096,6144): latent_prev fp32 -> bf16 latent
// rows [0,2048). Disjoint outputs; saves a launch.
// ---------------------------------------------------------------------------
__global__ __launch_bounds__(256) void ln_copy(const bf16_t* __restrict__ in,
                                               const float* __restrict__ g_,
                                               const float* __restrict__ b_,
                                               const float* __restrict__ prev,
                                               bf16_t* __restrict__ latent)
{
  const int tid = threadIdx.x;
  if (blockIdx.x >= 4096) {
    const size_t v    = (size_t)(blockIdx.x - 4096) * 256 + tid;
    const size_t flat = v * 4;
    const size_t per  = (size_t)2048 * 512;
    const size_t b    = flat / per, rem = flat % per;
    f32x4 d = *(const f32x4*)(prev + flat);
    bf16x4 o;
#pragma unroll
    for (int j = 0; j < 4; ++j) o[j] = (bf16_t)d[j];
    *(bf16x4*)(latent + b * ((size_t)4096 * 512) + rem) = o;
    return;
  }
  const int row = blockIdx.x;             // 0..4095 (= b*2048 + t)
  const float x0 = (float)in[(size_t)row * 512 + tid];
  const float x1 = (float)in[(size_t)row * 512 + 256 + tid];
  float s  = x0 + x1;
  float sq = x0 * x0 + x1 * x1;
#pragma unroll
  for (int off = 1; off < 64; off <<= 1) {
    s  += __shfl_xor(s, off);
    sq += __shfl_xor(sq, off);
  }
  __shared__ float red[8];
  const int w = tid >> 6;
  if ((tid & 63) == 0) { red[w] = s; red[4 + w] = sq; }
  __syncthreads();
  s  = red[0] + red[1] + red[2] + red[3];
  sq = red[4] + red[5] + red[6] + red[7];
  const float mu   = s * (1.0f / 512.0f);
  const float var  = sq * (1.0f / 512.0f) - mu * mu;
  const float rstd = rsqrtf(var + 1e-5f);
  const int b = row >> 11, tt = row & 2047;
  bf16_t* outp = latent + ((size_t)b * 4096 + 2048 + tt) * 512;
  outp[tid]       = (bf16_t)((x0 - mu) * rstd * g_[tid]       + b_[tid]);
  outp[tid + 256] = (bf16_t)((x1 - mu) * rstd * g_[tid + 256] + b_[tid + 256]);
}

// ---------------------------------------------------------------------------
// Flash attention v7 (round-7 kernel, 236.5us measured, UNCHANGED).
// ---------------------------------------------------------------------------
__global__ __launch_bounds__(256) void attn7(const bf16_t* __restrict__ q,
                                             const bf16_t* __restrict__ k,
                                             const bf16_t* __restrict__ vT,
                                             bf16_t* __restrict__ out)
{
  __shared__ __align__(16) bf16_t smem[32768];      // Ks0|Ks1|Vs0|Vs1 overlay

  const int tid = threadIdx.x;
  const int lane = tid & 63, w = tid >> 6;
  const int l31 = lane & 31, h5 = lane >> 5;

  // balanced XCD mapping
  const int g = blockIdx.x & 7, j = blockIdx.x >> 3;
  const int jl = j & 31, hsel = j >> 5;
  int qt = jl & 15;
  const int b = jl >> 4;
  if (hsel) qt = 15 - qt;
  const int h = g + 8 * hsel;

  const int q0 = qt * 128;
  const int qg = q0 + l31 * 4 + w;                  // this lane's query row

  // Q^T B-frags: B[k=feat fc*16+h5*8+j][n=q l31]
  bf16x8 qf[8];
  const bf16_t* qb = q + ((size_t)(b * 2048 + qg)) * 2048 + h * 128 + h5 * 8;
#pragma unroll
  for (int fc = 0; fc < 8; ++fc) qf[fc] = *(const bf16x8*)(qb + fc * 16);

  const bf16_t* kbase = k + ((size_t)b * 4096) * 2048 + h * 128;
  const bf16_t* vbase = vT + ((size_t)(b * 16 + h)) * 128 * 4096;

  // staging maps (slot = tid + 256p)
  int ks_key[4], ks_go[4], vs_feat[4], vs_go[4];
#pragma unroll
  for (int p = 0; p < 4; ++p) {
    const int slot = tid + 256 * p;
    const int key = slot >> 4, ph = slot & 15;
    ks_key[p] = key;
    ks_go[p]  = (((ph & 8) | ((ph & 7) ^ (key & 7)))) * 8;
    const int ft = slot >> 3, p2 = slot & 7;
    vs_feat[p] = ft;
    vs_go[p]   = (p2 ^ (ft & 7)) * 8;
  }
  // frag read offsets (elems)
  int kfo[8], vfo[4];
#pragma unroll
  for (int fc = 0; fc < 8; ++fc) {
    const int L = fc * 2 + h5;
    kfo[fc] = l31 * 128 + ((L & 8) | ((L & 7) ^ (l31 & 7))) * 8;
  }
#pragma unroll
  for (int kc = 0; kc < 4; ++kc) {
    const int L = kc * 2 + h5;
    vfo[kc] = l31 * 64 + (L ^ (l31 & 7)) * 8;
  }

  f32x16 o[4] = {};
  float m = -1e30f, l = 0.f;
  const int send = 2048 + q0 + 128;

  // prologue: stage tile 0 into buffer 0
#pragma unroll
  for (int p = 0; p < 4; ++p) {
    load_lds16(kbase + (size_t)ks_key[p] * 2048 + ks_go[p],
               smem + (tid + 256 * p) * 8);
    load_lds16(vbase + (size_t)vs_feat[p] * 4096 + vs_go[p],
               smem + 16384 + (tid + 256 * p) * 8);
  }
  __syncthreads();                                  // tile 0 resident

  int cur = 0;
  for (int s0 = 0; s0 < send; s0 += 64) {
    // stage next tile into the other buffer (DMA overlaps compute below)
    const int s1 = s0 + 64;
    if (s1 < send) {
      const int nxt = (cur ^ 1) * 8192;
#pragma unroll
      for (int p = 0; p < 4; ++p) {
        load_lds16(kbase + (size_t)(s1 + ks_key[p]) * 2048 + ks_go[p],
                   smem + nxt + (tid + 256 * p) * 8);
        load_lds16(vbase + (size_t)vs_feat[p] * 4096 + s1 + vs_go[p],
                   smem + 16384 + nxt + (tid + 256 * p) * 8);
      }
    }
    const bf16_t* Kc = smem + cur * 8192;
    const bf16_t* Vc = smem + 16384 + cur * 8192;

    // S^T tiles: rows = keys 32t + (i&3)+8*(i>>2)+4*h5, col = q = l31
    f32x16 st[2] = {};
    __builtin_amdgcn_s_setprio(1);
#pragma unroll
    for (int fc = 0; fc < 8; ++fc) {
      bf16x8 k0 = *(const bf16x8*)&Kc[kfo[fc]];
      bf16x8 k1 = *(const bf16x8*)&Kc[4096 + kfo[fc]];
      st[0] = MFMA32(k0, qf[fc], st[0]);
      st[1] = MFMA32(k1, qf[fc], st[1]);
    }
    __builtin_amdgcn_s_setprio(0);

    if (s0 + 63 > 2048 + q0) {                      // causal tail masking
#pragma unroll
      for (int t = 0; t < 2; ++t)
#pragma unroll
        for (int i = 0; i < 16; ++i) {
          const int key = s0 + 32 * t + (i & 3) + 8 * (i >> 2) + 4 * h5;
          if (key > 2048 + qg) st[t][i] = -1e30f;
        }
    }

    // tree max over this lane's 32 scores (depth 5)
    float gm[8];
#pragma unroll
    for (int t = 0; t < 2; ++t)
#pragma unroll
      for (int gg = 0; gg < 4; ++gg)
        gm[t * 4 + gg] = fmaxf(fmaxf(st[t][4 * gg + 0], st[t][4 * gg + 1]),
                               fmaxf(st[t][4 * gg + 2], st[t][4 * gg + 3]));
    float mt = fmaxf(fmaxf(fmaxf(gm[0], gm[1]), fmaxf(gm[2], gm[3])),
                     fmaxf(fmaxf(gm[4], gm[5]), fmaxf(gm[6], gm[7])));
    mt = fmaxf(mt, __shfl_xor(mt, 32));

    // defer-max: only rescale when max grew by >8 (log2 domain; p <= 2^8)
    if (__any(mt > m + 8.f)) {
      const float mnew = fmaxf(m, mt);
      const float alpha = fast_exp2(m - mnew);
#pragma unroll
      for (int ft = 0; ft < 4; ++ft)
#pragma unroll
        for (int i = 0; i < 16; ++i) o[ft][i] *= alpha;
      l *= alpha;
      m = mnew;
    }

    // exp2 + pack P into u32 pairs; group g holds keys 32t + 8g + 4h5 + 0..3
    float rs = 0.f;
    unsigned up[2][4][2];
#pragma unroll
    for (int t = 0; t < 2; ++t)
#pragma unroll
      for (int gg = 0; gg < 4; ++gg) {
        const float p0 = fast_exp2(st[t][4 * gg + 0] - m);
        const float p1 = fast_exp2(st[t][4 * gg + 1] - m);
        const float p2 = fast_exp2(st[t][4 * gg + 2] - m);
        const float p3 = fast_exp2(st[t][4 * gg + 3] - m);
        rs += (p0 + p1) + (p2 + p3);
        up[t][gg][0] = pack_bf16(p0, p1);
        up[t][gg][1] = pack_bf16(p2, p3);
      }
    rs += __shfl_xor(rs, 32);
    l += rs;

    // out^T += V^T · P^T ; P^T B-frag built in-register via half-exchange
#pragma unroll
    for (int kc = 0; kc < 4; ++kc) {
      const int t = kc >> 1, gp = (kc & 1) * 2;
      const unsigned a0 = up[t][gp][0],     a1 = up[t][gp][1];
      const unsigned b0 = up[t][gp + 1][0], b1 = up[t][gp + 1][1];
      const unsigned xa0 = __shfl_xor(a0, 32), xa1 = __shfl_xor(a1, 32);
      const unsigned xb0 = __shfl_xor(b0, 32), xb1 = __shfl_xor(b1, 32);
      u32x4 uw;
      uw[0] = h5 ? xb0 : a0;
      uw[1] = h5 ? xb1 : a1;
      uw[2] = h5 ? b0 : xa0;
      uw[3] = h5 ? b1 : xa1;
      union { u32x4 u; bf16x8 v; } pc; pc.u = uw;
      const bf16x8 pf = pc.v;
      __builtin_amdgcn_s_setprio(1);
#pragma unroll
      for (int ft = 0; ft < 4; ++ft) {
        bf16x8 vf = *(const bf16x8*)&Vc[ft * 2048 + vfo[kc]];
        o[ft] = MFMA32(vf, pf, o[ft]);
      }
      __builtin_amdgcn_s_setprio(0);
    }

    __syncthreads();   // compute reads done + next-tile DMA drained
    cur ^= 1;
  }

  // epilogue: normalize, LDS transpose, coalesced store (smem overlay)
  const float inv = 1.0f / l;
  const int rowp_w = w * 32 + l31;
#pragma unroll
  for (int ft = 0; ft < 4; ++ft)
#pragma unroll
    for (int gg = 0; gg < 4; ++gg) {
      bf16x4 pk;
#pragma unroll
      for (int r = 0; r < 4; ++r) pk[r] = (bf16_t)(o[ft][4 * gg + r] * inv);
      *(bf16x4*)&smem[rowp_w * 136 + ft * 32 + gg * 8 + h5 * 4] = pk;
    }
  __syncthreads();
#pragma unroll
  for (int p = 0; p < 8; ++p) {
    const int c = tid + 256 * p;
    const int rowp = c >> 4, chk = c & 15;
    const int ql = (rowp & 31) * 4 + (rowp >> 5);
    bf16x8 d = *(const bf16x8*)&smem[rowp * 136 + chk * 8];
    *(bf16x8*)(out + ((size_t)(b * 2048 + q0 + ql)) * 2048 + h * 128 + chk * 8) = d;
  }
}

// ---------------------------------------------------------------------------
extern "C" void kernel_launch(void* const* d_in, const int* in_sizes, int n_in,
                              void* d_out, int out_size, void* d_ws, size_t ws_size,
                              hipStream_t stream)
{
  (void)in_sizes; (void)n_in; (void)out_size; (void)ws_size;
  const float* x        = (const float*)d_in[0];
  const float* lat_prev = (const float*)d_in[1];
  const float* Wq       = (const float*)d_in[2];
  const float* Wdown    = (const float*)d_in[3];
  const float* Wk_up    = (const float*)d_in[4];
  const float* Wv_up    = (const float*)d_in[5];
  const float* ln_g     = (const float*)d_in[6];
  const float* ln_b     = (const float*)d_in[7];
  const float* Wo       = (const float*)d_in[8];
  float* out = (float*)d_out;

  char* p = (char*)d_ws;
  auto alloc = [&](size_t elems) { bf16_t* r = (bf16_t*)p; p += elems * 2; return r; };
  bf16_t* xb     = alloc((size_t)4096 * 2048);   // hosts WoT after x dead
  bf16_t* WqT    = alloc((size_t)2048 * 2048);   // WqT+WdT contiguous: stacked BT
  bf16_t* WdT    = alloc((size_t)512 * 2048);
  bf16_t* qbuf   = alloc((size_t)4096 * 2048);
  bf16_t* latpre = alloc((size_t)4096 * 512);    // hosts WkT+WvT after LN
  bf16_t* latent = alloc((size_t)2 * 4096 * 512);
  bf16_t* kbuf   = alloc((size_t)8192 * 2048);
  bf16_t* vTb    = alloc((size_t)2 * 2048 * 4096);
  bf16_t* aout   = alloc((size_t)4096 * 2048);
  bf16_t* WoT  = xb;
  bf16_t* WkT  = latpre;
  bf16_t* WvT  = latpre + (size_t)2048 * 512;

  const dim3 B(256);
  // 1/sqrt(128) * log2(e): attention scores land in log2 domain
  const float qscale = 0.12751744561825988f;

  cvt_f2b<<<dim3(8192), B, 0, stream>>>(x, xb);
  cvt_transpose<<<dim3(32, 32), B, 0, stream>>>(Wq,    WqT, 2048, 2048);
  cvt_transpose<<<dim3(8,  32), B, 0, stream>>>(Wdown, WdT, 2048, 512);
  // fused: q = (x@Wq)*qscale ; latpre = x@Wdown  (stacked BT = [WqT;WdT])
  gemm128_dual<<<dim3(20, 32), B, 0, stream>>>(xb, WqT, qbuf, latpre, qscale);
  // latent cache: LN rows + prev copy in one launch
  ln_copy<<<dim3(6144), B, 0, stream>>>(latpre, ln_g, ln_b, lat_prev, latent);
  // weight transposes into dead regions (stream order enforces lifetimes)
  cvt_transpose<<<dim3(32, 32), B, 0, stream>>>(Wo,    WoT, 2048, 2048);
  cvt_transpose<<<dim3(32, 8),  B, 0, stream>>>(Wk_up, WkT, 512, 2048);
  cvt_transpose<<<dim3(32, 8),  B, 0, stream>>>(Wv_up, WvT, 512, 2048);
  // k = latent @ Wk_up  (rows b*4096+s)
  gemm128<bf16_t><<<dim3(16, 64), B, 0, stream>>>(latent, WkT, kbuf, 8192, 2048, 512, 1.0f, 0, 0);
  // vT_b = WvT @ latent_b^T  (BT = latent_b), batched over z
  gemm128<bf16_t><<<dim3(32, 16, 2), B, 0, stream>>>(WvT, latent, vTb, 2048, 4096, 512, 1.0f,
                                                     (long long)4096 * 512,
                                                     (long long)2048 * 4096);
  // attention (XCD-grouped, CU-pair-balanced grid) — unchanged
  attn7<<<dim3(512), B, 0, stream>>>(qbuf, kbuf, vTb, aout);
  // output projection (fp32 out)
  gemm128<float><<<dim3(16, 32), B, 0, stream>>>(aout, WoT, out, 4096, 2048, 2048, 1.0f, 0, 0);
}

// Round 11
// 506.818 us; speedup vs baseline: 1.4184x; 1.0466x over previous
//
#include <hip/hip_runtime.h>
#include <hip/hip_bf16.h>

using bf16_t = __bf16;
typedef __bf16 bf16x8 __attribute__((ext_vector_type(8)));
typedef __bf16 bf16x4 __attribute__((ext_vector_type(4)));
typedef __bf16 bf16x2 __attribute__((ext_vector_type(2)));
typedef float  f32x4  __attribute__((ext_vector_type(4)));
typedef float  f32x16 __attribute__((ext_vector_type(16)));
typedef unsigned u32x4 __attribute__((ext_vector_type(4)));

#define MFMA16(a,b,c) __builtin_amdgcn_mfma_f32_16x16x32_bf16((a),(b),(c),0,0,0)
#define MFMA32(a,b,c) __builtin_amdgcn_mfma_f32_32x32x16_bf16((a),(b),(c),0,0,0)

__device__ __forceinline__ void load_lds16(const void* g, void* l) {
  __builtin_amdgcn_global_load_lds(
      (const __attribute__((address_space(1))) unsigned int*)g,
      (__attribute__((address_space(3))) unsigned int*)l, 16, 0, 0);
}

__device__ __forceinline__ unsigned pack_bf16(float a, float b) {
  union { bf16x2 v; unsigned u; } c;
  c.v[0] = (bf16_t)a; c.v[1] = (bf16_t)b;
  return c.u;
}

__device__ __forceinline__ float fast_exp2(float x) {
#if __has_builtin(__builtin_amdgcn_exp2f)
  return __builtin_amdgcn_exp2f(x);
#else
  return exp2f(x);
#endif
}

// XCD-chunked block remap (T1); exact when nwg%8==0 (all grids here).
__device__ __forceinline__ void xcd_remap(unsigned& bx, unsigned& by,
                                          unsigned& bz)
{
  const unsigned nxy = gridDim.x * gridDim.y;
  const unsigned nwg = nxy * gridDim.z;
  unsigned wg = (blockIdx.z * gridDim.y + blockIdx.y) * gridDim.x + blockIdx.x;
  if ((nwg & 7u) == 0u)
    wg = (wg & 7u) * (nwg >> 3) + (wg >> 3);
  bz = wg / nxy; wg -= bz * nxy;
  by = wg / gridDim.x;
  bx = wg - by * gridDim.x;
}

// ---------------------------------------------------------------------------
// Mega-preprocess: one launch for ALL independent prep work.
//   [0,8192)      : x fp32 -> bf16 (xb)
//   [8192,9216)   : Wq    [2048,2048] -> WqT
//   [9216,9472)   : Wdown [2048,512]  -> WdT
//   [9472,10496)  : Wo    [2048,2048] -> WoT
//   [10496,10752) : Wk_up [512,2048]  -> WkT
//   [10752,11008) : Wv_up [512,2048]  -> WvT
//   [11008,13056) : latent_prev fp32 -> bf16 latent rows [0,2048)
// Replaces 7 serialized launches (tiny transposes now co-resident).
// ---------------------------------------------------------------------------
__device__ __forceinline__ void transpose_body(const float* __restrict__ in,
                                               bf16_t* __restrict__ out,
                                               int R, int C, int bx, int by,
                                               int tid, bf16_t* t)
{
  const int r0 = by * 64, c0 = bx * 64;
  const int rr = tid >> 4;                  // 0..15
  const int c4 = (tid & 15) * 4;            // 0..60
#pragma unroll
  for (int i = 0; i < 4; ++i) {
    const int r = rr + i * 16;
    f32x4 d = *(const f32x4*)(in + (size_t)(r0 + r) * C + c0 + c4);
#pragma unroll
    for (int j = 0; j < 4; ++j) t[(c4 + j) * 80 + r] = (bf16_t)d[j];
  }
  __syncthreads();
  const int a  = tid >> 3;                  // 0..31
  const int bc = (tid & 7) * 8;
#pragma unroll
  for (int half = 0; half < 2; ++half) {
    const int cc = a + half * 32;
    bf16x8 d = *(const bf16x8*)&t[cc * 80 + bc];
    *(bf16x8*)(out + (size_t)(c0 + cc) * R + r0 + bc) = d;
  }
}

__global__ __launch_bounds__(256) void prep_all(
    const float* __restrict__ x,     bf16_t* __restrict__ xb,
    const float* __restrict__ Wq,    bf16_t* __restrict__ WqT,
    const float* __restrict__ Wdown, bf16_t* __restrict__ WdT,
    const float* __restrict__ Wo,    bf16_t* __restrict__ WoT,
    const float* __restrict__ Wk,    bf16_t* __restrict__ WkT,
    const float* __restrict__ Wv,    bf16_t* __restrict__ WvT,
    const float* __restrict__ prev,  bf16_t* __restrict__ latent)
{
  __shared__ __align__(16) bf16_t t[64 * 80];
  const int tid = threadIdx.x;
  const unsigned bid = blockIdx.x;
  if (bid < 8192) {
    const size_t i = ((size_t)bid * 256 + tid) * 4;
    f32x4 d = *(const f32x4*)(x + i);
    bf16x4 o;
#pragma unroll
    for (int j = 0; j < 4; ++j) o[j] = (bf16_t)d[j];
    *(bf16x4*)(xb + i) = o;
  } else if (bid < 9216) {
    const unsigned u = bid - 8192;
    transpose_body(Wq, WqT, 2048, 2048, u & 31, u >> 5, tid, t);
  } else if (bid < 9472) {
    const unsigned u = bid - 9216;
    transpose_body(Wdown, WdT, 2048, 512, u & 7, u >> 3, tid, t);
  } else if (bid < 10496) {
    const unsigned u = bid - 9472;
    transpose_body(Wo, WoT, 2048, 2048, u & 31, u >> 5, tid, t);
  } else if (bid < 10752) {
    const unsigned u = bid - 10496;
    transpose_body(Wk, WkT, 512, 2048, u & 31, u >> 5, tid, t);
  } else if (bid < 11008) {
    const unsigned u = bid - 10752;
    transpose_body(Wv, WvT, 512, 2048, u & 31, u >> 5, tid, t);
  } else {
    const size_t v    = (size_t)(bid - 11008) * 256 + tid;
    const size_t flat = v * 4;
    const size_t per  = (size_t)2048 * 512;
    const size_t b    = flat / per, rem = flat % per;
    f32x4 d = *(const f32x4*)(prev + flat);
    bf16x4 o;
#pragma unroll
    for (int j = 0; j < 4; ++j) o[j] = (bf16_t)d[j];
    *(bf16x4*)(latent + b * ((size_t)4096 * 512) + rem) = o;
  }
}

// ---------------------------------------------------------------------------
// m97-class GEMM, BK=64 (round-10 proven body): C = A @ B (+scale), BT input.
// ---------------------------------------------------------------------------
template <typename OutT>
__global__ __launch_bounds__(256) void gemm128(const bf16_t* __restrict__ A,
                                               const bf16_t* __restrict__ BT,
                                               OutT* __restrict__ C,
                                               int M, int N, int K, float scale,
                                               long long zB, long long zC)
{
  __shared__ __align__(16) bf16_t As[128 * 64];
  __shared__ __align__(16) bf16_t Bs[128 * 64];
  const int tid = threadIdx.x;
  unsigned bx, by, bz;
  xcd_remap(bx, by, bz);
  BT += (size_t)bz * zB;
  C  += (size_t)bz * zC;
  const int m0 = by * 128, n0 = bx * 128;
  const int lane = tid & 63, w = tid >> 6;
  const int quad = lane >> 4, l15 = lane & 15;
  const int wm = (w >> 1) * 64, wn = (w & 1) * 64;
  const int s_row = tid >> 3;
  const int g_off = ((tid & 7) ^ (s_row & 7)) * 8;
  const bf16_t* Ap = A  + (size_t)(m0 + s_row) * K + g_off;
  const bf16_t* Bp = BT + (size_t)(n0 + s_row) * K + g_off;
  const int cpos0 = (quad ^ (l15 & 7)) * 8;
  const int cpos1 = ((4 + quad) ^ (l15 & 7)) * 8;

  f32x4 acc[4][4] = {};

  for (int k0 = 0; k0 < K; k0 += 64) {
    __syncthreads();
#pragma unroll
    for (int p = 0; p < 4; ++p) {
      load_lds16(Ap + (size_t)(32 * p) * K + k0, As + (tid + 256 * p) * 8);
      load_lds16(Bp + (size_t)(32 * p) * K + k0, Bs + (tid + 256 * p) * 8);
    }
    __syncthreads();
#pragma unroll
    for (int kk = 0; kk < 2; ++kk) {
      const int cp = kk ? cpos1 : cpos0;
      bf16x8 af[4], bfr[4];
#pragma unroll
      for (int fi = 0; fi < 4; ++fi)
        af[fi] = *(const bf16x8*)&As[(wm + fi * 16 + l15) * 64 + cp];
#pragma unroll
      for (int fj = 0; fj < 4; ++fj)
        bfr[fj] = *(const bf16x8*)&Bs[(wn + fj * 16 + l15) * 64 + cp];
#pragma unroll
      for (int fi = 0; fi < 4; ++fi)
#pragma unroll
        for (int fj = 0; fj < 4; ++fj)
          acc[fi][fj] = MFMA16(af[fi], bfr[fj], acc[fi][fj]);
    }
  }

#pragma unroll
  for (int fi = 0; fi < 4; ++fi)
#pragma unroll
    for (int fj = 0; fj < 4; ++fj)
#pragma unroll
      for (int r = 0; r < 4; ++r) {
        const int row = m0 + wm + fi * 16 + quad * 4 + r;
        const int col = n0 + wn + fj * 16 + l15;
        C[(size_t)row * N + col] = (OutT)(acc[fi][fj][r] * scale);
      }
}

// ---------------------------------------------------------------------------
// Fused q + latpre GEMM (BK=64, round-10 proven): A @ [WqT;WdT] stacked.
// ---------------------------------------------------------------------------
__global__ __launch_bounds__(256) void gemm128_dual(const bf16_t* __restrict__ A,
                                                    const bf16_t* __restrict__ BT,
                                                    bf16_t* __restrict__ C1,
                                                    bf16_t* __restrict__ C2,
                                                    float qscale)
{
  __shared__ __align__(16) bf16_t As[128 * 64];
  __shared__ __align__(16) bf16_t Bs[128 * 64];
  const int tid = threadIdx.x;
  unsigned bx, by, bz;
  xcd_remap(bx, by, bz);
  const int K = 2048;
  const int m0 = by * 128, n0 = bx * 128;
  const int lane = tid & 63, w = tid >> 6;
  const int quad = lane >> 4, l15 = lane & 15;
  const int wm = (w >> 1) * 64, wn = (w & 1) * 64;
  const int s_row = tid >> 3;
  const int g_off = ((tid & 7) ^ (s_row & 7)) * 8;
  const bf16_t* Ap = A  + (size_t)(m0 + s_row) * K + g_off;
  const bf16_t* Bp = BT + (size_t)(n0 + s_row) * K + g_off;
  const int cpos0 = (quad ^ (l15 & 7)) * 8;
  const int cpos1 = ((4 + quad) ^ (l15 & 7)) * 8;

  f32x4 acc[4][4] = {};

  for (int k0 = 0; k0 < K; k0 += 64) {
    __syncthreads();
#pragma unroll
    for (int p = 0; p < 4; ++p) {
      load_lds16(Ap + (size_t)(32 * p) * K + k0, As + (tid + 256 * p) * 8);
      load_lds16(Bp + (size_t)(32 * p) * K + k0, Bs + (tid + 256 * p) * 8);
    }
    __syncthreads();
#pragma unroll
    for (int kk = 0; kk < 2; ++kk) {
      const int cp = kk ? cpos1 : cpos0;
      bf16x8 af[4], bfr[4];
#pragma unroll
      for (int fi = 0; fi < 4; ++fi)
        af[fi] = *(const bf16x8*)&As[(wm + fi * 16 + l15) * 64 + cp];
#pragma unroll
      for (int fj = 0; fj < 4; ++fj)
        bfr[fj] = *(const bf16x8*)&Bs[(wn + fj * 16 + l15) * 64 + cp];
#pragma unroll
      for (int fi = 0; fi < 4; ++fi)
#pragma unroll
        for (int fj = 0; fj < 4; ++fj)
          acc[fi][fj] = MFMA16(af[fi], bfr[fj], acc[fi][fj]);
    }
  }

  const bool isQ = (n0 < 2048);            // block-uniform
  const float sc = isQ ? qscale : 1.0f;
#pragma unroll
  for (int fi = 0; fi < 4; ++fi)
#pragma unroll
    for (int fj = 0; fj < 4; ++fj)
#pragma unroll
      for (int r = 0; r < 4; ++r) {
        const int row = m0 + wm + fi * 16 + quad * 4 + r;
        const int col = n0 + wn + fj * 16 + l15;
        if (isQ)
          C1[(size_t)row * 2048 + col] = (bf16_t)(acc[fi][fj][r] * sc);
        else
          C2[(size_t)row * 512 + (col - 2048)] = (bf16_t)(acc[fi][fj][r] * sc);
      }
}

// ---------------------------------------------------------------------------
// Fused k + vT GEMM (both read latent, K=512, bf16 out; one launch).
//   linear-remapped wg: [0,1024) -> k = latent @ WkT  (M=8192,N=2048)
//                       [1024,2048) -> vT_b = WvT @ latent_b^T (M=2048,N=4096)
// XCD chunking applied on the combined 2048-block space.
// ---------------------------------------------------------------------------
__global__ __launch_bounds__(256) void gemm_kv(const bf16_t* __restrict__ latent,
                                               const bf16_t* __restrict__ WkT,
                                               const bf16_t* __restrict__ WvT,
                                               bf16_t* __restrict__ kbuf,
                                               bf16_t* __restrict__ vTb)
{
  __shared__ __align__(16) bf16_t As[128 * 64];
  __shared__ __align__(16) bf16_t Bs[128 * 64];
  const int tid = threadIdx.x;
  unsigned wg = blockIdx.x;                 // 2048 blocks
  wg = (wg & 7u) * 256u + (wg >> 3);        // XCD-chunked remap
  const bf16_t *A, *BT;
  bf16_t* C;
  int M, N;
  unsigned bx, by;
  if (wg < 1024) {                          // k GEMM
    bx = wg & 15; by = wg >> 4;
    A = latent; BT = WkT; C = kbuf; M = 8192; N = 2048;
  } else {
    const unsigned t2 = wg - 1024;
    const unsigned bz = t2 >> 9, rem = t2 & 511;
    bx = rem & 31; by = rem >> 5;
    A  = WvT;
    BT = latent + (size_t)bz * ((size_t)4096 * 512);
    C  = vTb + (size_t)bz * ((size_t)2048 * 4096);
    M = 2048; N = 4096;
  }
  const int K = 512;
  const int m0 = by * 128, n0 = bx * 128;
  const int lane = tid & 63, w = tid >> 6;
  const int quad = lane >> 4, l15 = lane & 15;
  const int wm = (w >> 1) * 64, wn = (w & 1) * 64;
  const int s_row = tid >> 3;
  const int g_off = ((tid & 7) ^ (s_row & 7)) * 8;
  const bf16_t* Ap = A  + (size_t)(m0 + s_row) * K + g_off;
  const bf16_t* Bp = BT + (size_t)(n0 + s_row) * K + g_off;
  const int cpos0 = (quad ^ (l15 & 7)) * 8;
  const int cpos1 = ((4 + quad) ^ (l15 & 7)) * 8;

  f32x4 acc[4][4] = {};

  for (int k0 = 0; k0 < K; k0 += 64) {
    __syncthreads();
#pragma unroll
    for (int p = 0; p < 4; ++p) {
      load_lds16(Ap + (size_t)(32 * p) * K + k0, As + (tid + 256 * p) * 8);
      load_lds16(Bp + (size_t)(32 * p) * K + k0, Bs + (tid + 256 * p) * 8);
    }
    __syncthreads();
#pragma unroll
    for (int kk = 0; kk < 2; ++kk) {
      const int cp = kk ? cpos1 : cpos0;
      bf16x8 af[4], bfr[4];
#pragma unroll
      for (int fi = 0; fi < 4; ++fi)
        af[fi] = *(const bf16x8*)&As[(wm + fi * 16 + l15) * 64 + cp];
#pragma unroll
      for (int fj = 0; fj < 4; ++fj)
        bfr[fj] = *(const bf16x8*)&Bs[(wn + fj * 16 + l15) * 64 + cp];
#pragma unroll
      for (int fi = 0; fi < 4; ++fi)
#pragma unroll
        for (int fj = 0; fj < 4; ++fj)
          acc[fi][fj] = MFMA16(af[fi], bfr[fj], acc[fi][fj]);
    }
  }

#pragma unroll
  for (int fi = 0; fi < 4; ++fi)
#pragma unroll
    for (int fj = 0; fj < 4; ++fj)
#pragma unroll
      for (int r = 0; r < 4; ++r) {
        const int row = m0 + wm + fi * 16 + quad * 4 + r;
        const int col = n0 + wn + fj * 16 + l15;
        C[(size_t)row * N + col] = (bf16_t)acc[fi][fj][r];
      }
}

// ---------------------------------------------------------------------------
// LayerNorm over 512 (fp32 stats), bf16 in, fp32 g/b, bf16 out into latent
// rows [2048,4096).
// ---------------------------------------------------------------------------
__global__ __launch_bounds__(256) void ln_kernel(const bf16_t* __restrict__ in,
                                                 const float* __restrict__ g_,
                                                 const float* __restrict__ b_,
                                                 bf16_t* __restrict__ latent)
{
  const int row = blockIdx.x;             // 0..4095 (= b*2048 + t)
  const int tid = threadIdx.x;
  const float x0 = (float)in[(size_t)row * 512 + tid];
  const float x1 = (float)in[(size_t)row * 512 + 256 + tid];
  float s  = x0 + x1;
  float sq = x0 * x0 + x1 * x1;
#pragma unroll
  for (int off = 1; off < 64; off <<= 1) {
    s  += __shfl_xor(s, off);
    sq += __shfl_xor(sq, off);
  }
  __shared__ float red[8];
  const int w = tid >> 6;
  if ((tid & 63) == 0) { red[w] = s; red[4 + w] = sq; }
  __syncthreads();
  s  = red[0] + red[1] + red[2] + red[3];
  sq = red[4] + red[5] + red[6] + red[7];
  const float mu   = s * (1.0f / 512.0f);
  const float var  = sq * (1.0f / 512.0f) - mu * mu;
  const float rstd = rsqrtf(var + 1e-5f);
  const int b = row >> 11, tt = row & 2047;
  bf16_t* outp = latent + ((size_t)b * 4096 + 2048 + tt) * 512;
  outp[tid]       = (bf16_t)((x0 - mu) * rstd * g_[tid]       + b_[tid]);
  outp[tid + 256] = (bf16_t)((x1 - mu) * rstd * g_[tid + 256] + b_[tid + 256]);
}

// ---------------------------------------------------------------------------
// Flash attention v7 (round-7 kernel, 237us measured, UNCHANGED).
// ---------------------------------------------------------------------------
__global__ __launch_bounds__(256) void attn7(const bf16_t* __restrict__ q,
                                             const bf16_t* __restrict__ k,
                                             const bf16_t* __restrict__ vT,
                                             bf16_t* __restrict__ out)
{
  __shared__ __align__(16) bf16_t smem[32768];      // Ks0|Ks1|Vs0|Vs1 overlay

  const int tid = threadIdx.x;
  const int lane = tid & 63, w = tid >> 6;
  const int l31 = lane & 31, h5 = lane >> 5;

  // balanced XCD mapping
  const int g = blockIdx.x & 7, j = blockIdx.x >> 3;
  const int jl = j & 31, hsel = j >> 5;
  int qt = jl & 15;
  const int b = jl >> 4;
  if (hsel) qt = 15 - qt;
  const int h = g + 8 * hsel;

  const int q0 = qt * 128;
  const int qg = q0 + l31 * 4 + w;                  // this lane's query row

  // Q^T B-frags: B[k=feat fc*16+h5*8+j][n=q l31]
  bf16x8 qf[8];
  const bf16_t* qb = q + ((size_t)(b * 2048 + qg)) * 2048 + h * 128 + h5 * 8;
#pragma unroll
  for (int fc = 0; fc < 8; ++fc) qf[fc] = *(const bf16x8*)(qb + fc * 16);

  const bf16_t* kbase = k + ((size_t)b * 4096) * 2048 + h * 128;
  const bf16_t* vbase = vT + ((size_t)(b * 16 + h)) * 128 * 4096;

  // staging maps (slot = tid + 256p)
  int ks_key[4], ks_go[4], vs_feat[4], vs_go[4];
#pragma unroll
  for (int p = 0; p < 4; ++p) {
    const int slot = tid + 256 * p;
    const int key = slot >> 4, ph = slot & 15;
    ks_key[p] = key;
    ks_go[p]  = (((ph & 8) | ((ph & 7) ^ (key & 7)))) * 8;
    const int ft = slot >> 3, p2 = slot & 7;
    vs_feat[p] = ft;
    vs_go[p]   = (p2 ^ (ft & 7)) * 8;
  }
  // frag read offsets (elems)
  int kfo[8], vfo[4];
#pragma unroll
  for (int fc = 0; fc < 8; ++fc) {
    const int L = fc * 2 + h5;
    kfo[fc] = l31 * 128 + ((L & 8) | ((L & 7) ^ (l31 & 7))) * 8;
  }
#pragma unroll
  for (int kc = 0; kc < 4; ++kc) {
    const int L = kc * 2 + h5;
    vfo[kc] = l31 * 64 + (L ^ (l31 & 7)) * 8;
  }

  f32x16 o[4] = {};
  float m = -1e30f, l = 0.f;
  const int send = 2048 + q0 + 128;

  // prologue: stage tile 0 into buffer 0
#pragma unroll
  for (int p = 0; p < 4; ++p) {
    load_lds16(kbase + (size_t)ks_key[p] * 2048 + ks_go[p],
               smem + (tid + 256 * p) * 8);
    load_lds16(vbase + (size_t)vs_feat[p] * 4096 + vs_go[p],
               smem + 16384 + (tid + 256 * p) * 8);
  }
  __syncthreads();                                  // tile 0 resident

  int cur = 0;
  for (int s0 = 0; s0 < send; s0 += 64) {
    // stage next tile into the other buffer (DMA overlaps compute below)
    const int s1 = s0 + 64;
    if (s1 < send) {
      const int nxt = (cur ^ 1) * 8192;
#pragma unroll
      for (int p = 0; p < 4; ++p) {
        load_lds16(kbase + (size_t)(s1 + ks_key[p]) * 2048 + ks_go[p],
                   smem + nxt + (tid + 256 * p) * 8);
        load_lds16(vbase + (size_t)vs_feat[p] * 4096 + s1 + vs_go[p],
                   smem + 16384 + nxt + (tid + 256 * p) * 8);
      }
    }
    const bf16_t* Kc = smem + cur * 8192;
    const bf16_t* Vc = smem + 16384 + cur * 8192;

    // S^T tiles: rows = keys 32t + (i&3)+8*(i>>2)+4*h5, col = q = l31
    f32x16 st[2] = {};
    __builtin_amdgcn_s_setprio(1);
#pragma unroll
    for (int fc = 0; fc < 8; ++fc) {
      bf16x8 k0 = *(const bf16x8*)&Kc[kfo[fc]];
      bf16x8 k1 = *(const bf16x8*)&Kc[4096 + kfo[fc]];
      st[0] = MFMA32(k0, qf[fc], st[0]);
      st[1] = MFMA32(k1, qf[fc], st[1]);
    }
    __builtin_amdgcn_s_setprio(0);

    if (s0 + 63 > 2048 + q0) {                      // causal tail masking
#pragma unroll
      for (int t = 0; t < 2; ++t)
#pragma unroll
        for (int i = 0; i < 16; ++i) {
          const int key = s0 + 32 * t + (i & 3) + 8 * (i >> 2) + 4 * h5;
          if (key > 2048 + qg) st[t][i] = -1e30f;
        }
    }

    // tree max over this lane's 32 scores (depth 5)
    float gm[8];
#pragma unroll
    for (int t = 0; t < 2; ++t)
#pragma unroll
      for (int gg = 0; gg < 4; ++gg)
        gm[t * 4 + gg] = fmaxf(fmaxf(st[t][4 * gg + 0], st[t][4 * gg + 1]),
                               fmaxf(st[t][4 * gg + 2], st[t][4 * gg + 3]));
    float mt = fmaxf(fmaxf(fmaxf(gm[0], gm[1]), fmaxf(gm[2], gm[3])),
                     fmaxf(fmaxf(gm[4], gm[5]), fmaxf(gm[6], gm[7])));
    mt = fmaxf(mt, __shfl_xor(mt, 32));

    // defer-max: only rescale when max grew by >8 (log2 domain; p <= 2^8)
    if (__any(mt > m + 8.f)) {
      const float mnew = fmaxf(m, mt);
      const float alpha = fast_exp2(m - mnew);
#pragma unroll
      for (int ft = 0; ft < 4; ++ft)
#pragma unroll
        for (int i = 0; i < 16; ++i) o[ft][i] *= alpha;
      l *= alpha;
      m = mnew;
    }

    // exp2 + pack P into u32 pairs; group g holds keys 32t + 8g + 4h5 + 0..3
    float rs = 0.f;
    unsigned up[2][4][2];
#pragma unroll
    for (int t = 0; t < 2; ++t)
#pragma unroll
      for (int gg = 0; gg < 4; ++gg) {
        const float p0 = fast_exp2(st[t][4 * gg + 0] - m);
        const float p1 = fast_exp2(st[t][4 * gg + 1] - m);
        const float p2 = fast_exp2(st[t][4 * gg + 2] - m);
        const float p3 = fast_exp2(st[t][4 * gg + 3] - m);
        rs += (p0 + p1) + (p2 + p3);
        up[t][gg][0] = pack_bf16(p0, p1);
        up[t][gg][1] = pack_bf16(p2, p3);
      }
    rs += __shfl_xor(rs, 32);
    l += rs;

    // out^T += V^T · P^T ; P^T B-frag built in-register via half-exchange
#pragma unroll
    for (int kc = 0; kc < 4; ++kc) {
      const int t = kc >> 1, gp = (kc & 1) * 2;
      const unsigned a0 = up[t][gp][0],     a1 = up[t][gp][1];
      const unsigned b0 = up[t][gp + 1][0], b1 = up[t][gp + 1][1];
      const unsigned xa0 = __shfl_xor(a0, 32), xa1 = __shfl_xor(a1, 32);
      const unsigned xb0 = __shfl_xor(b0, 32), xb1 = __shfl_xor(b1, 32);
      u32x4 uw;
      uw[0] = h5 ? xb0 : a0;
      uw[1] = h5 ? xb1 : a1;
      uw[2] = h5 ? b0 : xa0;
      uw[3] = h5 ? b1 : xa1;
      union { u32x4 u; bf16x8 v; } pc; pc.u = uw;
      const bf16x8 pf = pc.v;
      __builtin_amdgcn_s_setprio(1);
#pragma unroll
      for (int ft = 0; ft < 4; ++ft) {
        bf16x8 vf = *(const bf16x8*)&Vc[ft * 2048 + vfo[kc]];
        o[ft] = MFMA32(vf, pf, o[ft]);
      }
      __builtin_amdgcn_s_setprio(0);
    }

    __syncthreads();   // compute reads done + next-tile DMA drained
    cur ^= 1;
  }

  // epilogue: normalize, LDS transpose, coalesced store (smem overlay)
  const float inv = 1.0f / l;
  const int rowp_w = w * 32 + l31;
#pragma unroll
  for (int ft = 0; ft < 4; ++ft)
#pragma unroll
    for (int gg = 0; gg < 4; ++gg) {
      bf16x4 pk;
#pragma unroll
      for (int r = 0; r < 4; ++r) pk[r] = (bf16_t)(o[ft][4 * gg + r] * inv);
      *(bf16x4*)&smem[rowp_w * 136 + ft * 32 + gg * 8 + h5 * 4] = pk;
    }
  __syncthreads();
#pragma unroll
  for (int p = 0; p < 8; ++p) {
    const int c = tid + 256 * p;
    const int rowp = c >> 4, chk = c & 15;
    const int ql = (rowp & 31) * 4 + (rowp >> 5);
    bf16x8 d = *(const bf16x8*)&smem[rowp * 136 + chk * 8];
    *(bf16x8*)(out + ((size_t)(b * 2048 + q0 + ql)) * 2048 + h * 128 + chk * 8) = d;
  }
}

// ---------------------------------------------------------------------------
extern "C" void kernel_launch(void* const* d_in, const int* in_sizes, int n_in,
                              void* d_out, int out_size, void* d_ws, size_t ws_size,
                              hipStream_t stream)
{
  (void)in_sizes; (void)n_in; (void)out_size; (void)ws_size;
  const float* x        = (const float*)d_in[0];
  const float* lat_prev = (const float*)d_in[1];
  const float* Wq       = (const float*)d_in[2];
  const float* Wdown    = (const float*)d_in[3];
  const float* Wk_up    = (const float*)d_in[4];
  const float* Wv_up    = (const float*)d_in[5];
  const float* ln_g     = (const float*)d_in[6];
  const float* ln_b     = (const float*)d_in[7];
  const float* Wo       = (const float*)d_in[8];
  float* out = (float*)d_out;

  char* p = (char*)d_ws;
  auto alloc = [&](size_t elems) { bf16_t* r = (bf16_t*)p; p += elems * 2; return r; };
  bf16_t* xb     = alloc((size_t)4096 * 2048);
  bf16_t* WqT    = alloc((size_t)2048 * 2048);   // WqT+WdT contiguous: stacked BT
  bf16_t* WdT    = alloc((size_t)512 * 2048);
  bf16_t* qbuf   = alloc((size_t)4096 * 2048);
  bf16_t* latpre = alloc((size_t)4096 * 512);
  bf16_t* latent = alloc((size_t)2 * 4096 * 512);
  bf16_t* kbuf   = alloc((size_t)8192 * 2048);
  bf16_t* vTb    = alloc((size_t)2 * 2048 * 4096);
  bf16_t* aout   = alloc((size_t)4096 * 2048);
  bf16_t* WoT    = alloc((size_t)2048 * 2048);   // un-aliased (ws >= ~151MB
  bf16_t* WkT    = alloc((size_t)2048 * 512);    //  proven in round 3)
  bf16_t* WvT    = alloc((size_t)2048 * 512);

  const dim3 B(256);
  // 1/sqrt(128) * log2(e): attention scores land in log2 domain
  const float qscale = 0.12751744561825988f;

  // 1) all independent preprocessing in one launch
  prep_all<<<dim3(13056), B, 0, stream>>>(x, xb, Wq, WqT, Wdown, WdT,
                                          Wo, WoT, Wk_up, WkT, Wv_up, WvT,
                                          lat_prev, latent);
  // 2) fused: q = (x@Wq)*qscale ; latpre = x@Wdown
  gemm128_dual<<<dim3(20, 32), B, 0, stream>>>(xb, WqT, qbuf, latpre, qscale);
  // 3) LayerNorm -> latent rows [2048,4096)
  ln_kernel<<<dim3(4096), B, 0, stream>>>(latpre, ln_g, ln_b, latent);
  // 4) fused k + vT GEMM
  gemm_kv<<<dim3(2048), B, 0, stream>>>(latent, WkT, WvT, kbuf, vTb);
  // 5) attention (XCD-grouped, CU-pair-balanced grid) — unchanged
  attn7<<<dim3(512), B, 0, stream>>>(qbuf, kbuf, vTb, aout);
  // 6) output projection (fp32 out)
  gemm128<float><<<dim3(16, 32), B, 0, stream>>>(aout, WoT, out, 4096, 2048, 2048, 1.0f, 0, 0);
}

// Round 14
// 501.846 us; speedup vs baseline: 1.4325x; 1.0099x over previous
//
#include <hip/hip_runtime.h>
#include <hip/hip_bf16.h>

using bf16_t = __bf16;
typedef __bf16 bf16x8 __attribute__((ext_vector_type(8)));
typedef __bf16 bf16x4 __attribute__((ext_vector_type(4)));
typedef __bf16 bf16x2 __attribute__((ext_vector_type(2)));
typedef float  f32x4  __attribute__((ext_vector_type(4)));
typedef float  f32x16 __attribute__((ext_vector_type(16)));
typedef unsigned u32x4 __attribute__((ext_vector_type(4)));

#define MFMA16(a,b,c) __builtin_amdgcn_mfma_f32_16x16x32_bf16((a),(b),(c),0,0,0)
#define MFMA32(a,b,c) __builtin_amdgcn_mfma_f32_32x32x16_bf16((a),(b),(c),0,0,0)

__device__ __forceinline__ void load_lds16(const void* g, void* l) {
  __builtin_amdgcn_global_load_lds(
      (const __attribute__((address_space(1))) unsigned int*)g,
      (__attribute__((address_space(3))) unsigned int*)l, 16, 0, 0);
}

__device__ __forceinline__ unsigned pack_bf16(float a, float b) {
  union { bf16x2 v; unsigned u; } c;
  c.v[0] = (bf16_t)a; c.v[1] = (bf16_t)b;
  return c.u;
}

__device__ __forceinline__ float fast_exp2(float x) {
#if __has_builtin(__builtin_amdgcn_exp2f)
  return __builtin_amdgcn_exp2f(x);
#else
  return exp2f(x);
#endif
}

// XCD-chunked block remap (T1); exact when nwg%8==0 (all grids here).
__device__ __forceinline__ void xcd_remap(unsigned& bx, unsigned& by,
                                          unsigned& bz)
{
  const unsigned nxy = gridDim.x * gridDim.y;
  const unsigned nwg = nxy * gridDim.z;
  unsigned wg = (blockIdx.z * gridDim.y + blockIdx.y) * gridDim.x + blockIdx.x;
  if ((nwg & 7u) == 0u)
    wg = (wg & 7u) * (nwg >> 3) + (wg >> 3);
  bz = wg / nxy; wg -= bz * nxy;
  by = wg / gridDim.x;
  bx = wg - by * gridDim.x;
}

// ---------------------------------------------------------------------------
// Mega-preprocess: one launch for ALL independent prep work (round-11 proven).
// ---------------------------------------------------------------------------
__device__ __forceinline__ void transpose_body(const float* __restrict__ in,
                                               bf16_t* __restrict__ out,
                                               int R, int C, int bx, int by,
                                               int tid, bf16_t* t)
{
  const int r0 = by * 64, c0 = bx * 64;
  const int rr = tid >> 4;                  // 0..15
  const int c4 = (tid & 15) * 4;            // 0..60
#pragma unroll
  for (int i = 0; i < 4; ++i) {
    const int r = rr + i * 16;
    f32x4 d = *(const f32x4*)(in + (size_t)(r0 + r) * C + c0 + c4);
#pragma unroll
    for (int j = 0; j < 4; ++j) t[(c4 + j) * 80 + r] = (bf16_t)d[j];
  }
  __syncthreads();
  const int a  = tid >> 3;                  // 0..31
  const int bc = (tid & 7) * 8;
#pragma unroll
  for (int half = 0; half < 2; ++half) {
    const int cc = a + half * 32;
    bf16x8 d = *(const bf16x8*)&t[cc * 80 + bc];
    *(bf16x8*)(out + (size_t)(c0 + cc) * R + r0 + bc) = d;
  }
}

__global__ __launch_bounds__(256) void prep_all(
    const float* __restrict__ x,     bf16_t* __restrict__ xb,
    const float* __restrict__ Wq,    bf16_t* __restrict__ WqT,
    const float* __restrict__ Wdown, bf16_t* __restrict__ WdT,
    const float* __restrict__ Wo,    bf16_t* __restrict__ WoT,
    const float* __restrict__ Wk,    bf16_t* __restrict__ WkT,
    const float* __restrict__ Wv,    bf16_t* __restrict__ WvT,
    const float* __restrict__ prev,  bf16_t* __restrict__ latent)
{
  __shared__ __align__(16) bf16_t t[64 * 80];
  const int tid = threadIdx.x;
  const unsigned bid = blockIdx.x;
  if (bid < 8192) {
    const size_t i = ((size_t)bid * 256 + tid) * 4;
    f32x4 d = *(const f32x4*)(x + i);
    bf16x4 o;
#pragma unroll
    for (int j = 0; j < 4; ++j) o[j] = (bf16_t)d[j];
    *(bf16x4*)(xb + i) = o;
  } else if (bid < 9216) {
    const unsigned u = bid - 8192;
    transpose_body(Wq, WqT, 2048, 2048, u & 31, u >> 5, tid, t);
  } else if (bid < 9472) {
    const unsigned u = bid - 9216;
    transpose_body(Wdown, WdT, 2048, 512, u & 7, u >> 3, tid, t);
  } else if (bid < 10496) {
    const unsigned u = bid - 9472;
    transpose_body(Wo, WoT, 2048, 2048, u & 31, u >> 5, tid, t);
  } else if (bid < 10752) {
    const unsigned u = bid - 10496;
    transpose_body(Wk, WkT, 512, 2048, u & 31, u >> 5, tid, t);
  } else if (bid < 11008) {
    const unsigned u = bid - 10752;
    transpose_body(Wv, WvT, 512, 2048, u & 31, u >> 5, tid, t);
  } else {
    const size_t v    = (size_t)(bid - 11008) * 256 + tid;
    const size_t flat = v * 4;
    const size_t per  = (size_t)2048 * 512;
    const size_t b    = flat / per, rem = flat % per;
    f32x4 d = *(const f32x4*)(prev + flat);
    bf16x4 o;
#pragma unroll
    for (int j = 0; j < 4; ++j) o[j] = (bf16_t)d[j];
    *(bf16x4*)(latent + b * ((size_t)4096 * 512) + rem) = o;
  }
}

// ---------------------------------------------------------------------------
// GEMM K-loop, BK=32, DOUBLE-BUFFERED (attn7-style 2-phase: stage tile k+1
// into buf^1 while computing buf; ONE barrier per iter). Addressing is the
// round-8-proven BK=32 swizzle map. LDS = 2x(8+8)KB = 32KB/block.
// ---------------------------------------------------------------------------
#define GEMM_DBUF_LOOP(Kvar)                                                  \
  f32x4 acc[4][4] = {};                                                       \
  auto stage = [&](int k0, int buf) {                                         \
    bf16_t* Ad = As + buf * 4096;                                             \
    bf16_t* Bd = Bs + buf * 4096;                                             \
    load_lds16(Ap0 + k0, Ad + tid * 8);                                       \
    load_lds16(Ap1 + k0, Ad + tid * 8 + 2048);                                \
    load_lds16(Bp0 + k0, Bd + tid * 8);                                       \
    load_lds16(Bp1 + k0, Bd + tid * 8 + 2048);                                \
  };                                                                          \
  stage(0, 0);                                                                \
  __syncthreads();                                                            \
  int cur = 0;                                                                \
  for (int k0 = 0; k0 < (Kvar); k0 += 32) {                                   \
    if (k0 + 32 < (Kvar)) stage(k0 + 32, cur ^ 1);                            \
    const bf16_t* Ac = As + cur * 4096;                                       \
    const bf16_t* Bc = Bs + cur * 4096;                                       \
    bf16x8 af[4], bfr[4];                                                     \
    _Pragma("unroll")                                                         \
    for (int fi = 0; fi < 4; ++fi)                                            \
      af[fi] = *(const bf16x8*)&Ac[(wm + fi * 16 + l15) * 32 + quadp];        \
    _Pragma("unroll")                                                         \
    for (int fj = 0; fj < 4; ++fj)                                            \
      bfr[fj] = *(const bf16x8*)&Bc[(wn + fj * 16 + l15) * 32 + quadp];       \
    _Pragma("unroll")                                                         \
    for (int fi = 0; fi < 4; ++fi)                                            \
      _Pragma("unroll")                                                       \
      for (int fj = 0; fj < 4; ++fj)                                          \
        acc[fi][fj] = MFMA16(af[fi], bfr[fj], acc[fi][fj]);                   \
    __syncthreads();                                                          \
    cur ^= 1;                                                                 \
  }

// ---------------------------------------------------------------------------
// m97-class GEMM, BK=32 double-buffered: C = A @ B (+scale), BT input.
// ---------------------------------------------------------------------------
template <typename OutT>
__global__ __launch_bounds__(256) void gemm128(const bf16_t* __restrict__ A,
                                               const bf16_t* __restrict__ BT,
                                               OutT* __restrict__ C,
                                               int M, int N, int K, float scale,
                                               long long zB, long long zC)
{
  __shared__ __align__(16) bf16_t As[2 * 128 * 32];
  __shared__ __align__(16) bf16_t Bs[2 * 128 * 32];
  const int tid = threadIdx.x;
  unsigned bx, by, bz;
  xcd_remap(bx, by, bz);
  BT += (size_t)bz * zB;
  C  += (size_t)bz * zC;
  const int m0 = by * 128, n0 = bx * 128;
  const int lane = tid & 63, w = tid >> 6;
  const int quad = lane >> 4, l15 = lane & 15;
  const int wm = (w >> 1) * 64, wn = (w & 1) * 64;
  const int s_row = tid >> 2;
  const int g_off = ((tid & 3) ^ (s_row & 3)) * 8;
  const int quadp = (quad ^ (l15 & 3)) * 8;
  const bf16_t* Ap0 = A  + (size_t)(m0 + s_row) * K + g_off;
  const bf16_t* Ap1 = A  + (size_t)(m0 + 64 + s_row) * K + g_off;
  const bf16_t* Bp0 = BT + (size_t)(n0 + s_row) * K + g_off;
  const bf16_t* Bp1 = BT + (size_t)(n0 + 64 + s_row) * K + g_off;

  GEMM_DBUF_LOOP(K)

#pragma unroll
  for (int fi = 0; fi < 4; ++fi)
#pragma unroll
    for (int fj = 0; fj < 4; ++fj)
#pragma unroll
      for (int r = 0; r < 4; ++r) {
        const int row = m0 + wm + fi * 16 + quad * 4 + r;
        const int col = n0 + wn + fj * 16 + l15;
        C[(size_t)row * N + col] = (OutT)(acc[fi][fj][r] * scale);
      }
}

// ---------------------------------------------------------------------------
// Fused q + latpre GEMM, BK=32 double-buffered: A @ [WqT;WdT] stacked.
// ---------------------------------------------------------------------------
__global__ __launch_bounds__(256) void gemm128_dual(const bf16_t* __restrict__ A,
                                                    const bf16_t* __restrict__ BT,
                                                    bf16_t* __restrict__ C1,
                                                    bf16_t* __restrict__ C2,
                                                    float qscale)
{
  __shared__ __align__(16) bf16_t As[2 * 128 * 32];
  __shared__ __align__(16) bf16_t Bs[2 * 128 * 32];
  const int tid = threadIdx.x;
  unsigned bx, by, bz;
  xcd_remap(bx, by, bz);
  const int K = 2048;
  const int m0 = by * 128, n0 = bx * 128;
  const int lane = tid & 63, w = tid >> 6;
  const int quad = lane >> 4, l15 = lane & 15;
  const int wm = (w >> 1) * 64, wn = (w & 1) * 64;
  const int s_row = tid >> 2;
  const int g_off = ((tid & 3) ^ (s_row & 3)) * 8;
  const int quadp = (quad ^ (l15 & 3)) * 8;
  const bf16_t* Ap0 = A  + (size_t)(m0 + s_row) * K + g_off;
  const bf16_t* Ap1 = A  + (size_t)(m0 + 64 + s_row) * K + g_off;
  const bf16_t* Bp0 = BT + (size_t)(n0 + s_row) * K + g_off;
  const bf16_t* Bp1 = BT + (size_t)(n0 + 64 + s_row) * K + g_off;

  GEMM_DBUF_LOOP(K)

  const bool isQ = (n0 < 2048);            // block-uniform
  const float sc = isQ ? qscale : 1.0f;
#pragma unroll
  for (int fi = 0; fi < 4; ++fi)
#pragma unroll
    for (int fj = 0; fj < 4; ++fj)
#pragma unroll
      for (int r = 0; r < 4; ++r) {
        const int row = m0 + wm + fi * 16 + quad * 4 + r;
        const int col = n0 + wn + fj * 16 + l15;
        if (isQ)
          C1[(size_t)row * 2048 + col] = (bf16_t)(acc[fi][fj][r] * sc);
        else
          C2[(size_t)row * 512 + (col - 2048)] = (bf16_t)(acc[fi][fj][r] * sc);
      }
}

// ---------------------------------------------------------------------------
// Fused k + vT GEMM, BK=32 double-buffered (both read latent, K=512).
// ---------------------------------------------------------------------------
__global__ __launch_bounds__(256) void gemm_kv(const bf16_t* __restrict__ latent,
                                               const bf16_t* __restrict__ WkT,
                                               const bf16_t* __restrict__ WvT,
                                               bf16_t* __restrict__ kbuf,
                                               bf16_t* __restrict__ vTb)
{
  __shared__ __align__(16) bf16_t As[2 * 128 * 32];
  __shared__ __align__(16) bf16_t Bs[2 * 128 * 32];
  const int tid = threadIdx.x;
  unsigned wg = blockIdx.x;                 // 2048 blocks
  wg = (wg & 7u) * 256u + (wg >> 3);        // XCD-chunked remap
  const bf16_t *A, *BT;
  bf16_t* C;
  int N;
  unsigned bx, by;
  if (wg < 1024) {                          // k GEMM
    bx = wg & 15; by = wg >> 4;
    A = latent; BT = WkT; C = kbuf; N = 2048;
  } else {
    const unsigned t2 = wg - 1024;
    const unsigned bz = t2 >> 9, rem = t2 & 511;
    bx = rem & 31; by = rem >> 5;
    A  = WvT;
    BT = latent + (size_t)bz * ((size_t)4096 * 512);
    C  = vTb + (size_t)bz * ((size_t)2048 * 4096);
    N = 4096;
  }
  const int K = 512;
  const int m0 = by * 128, n0 = bx * 128;
  const int lane = tid & 63, w = tid >> 6;
  const int quad = lane >> 4, l15 = lane & 15;
  const int wm = (w >> 1) * 64, wn = (w & 1) * 64;
  const int s_row = tid >> 2;
  const int g_off = ((tid & 3) ^ (s_row & 3)) * 8;
  const int quadp = (quad ^ (l15 & 3)) * 8;
  const bf16_t* Ap0 = A  + (size_t)(m0 + s_row) * K + g_off;
  const bf16_t* Ap1 = A  + (size_t)(m0 + 64 + s_row) * K + g_off;
  const bf16_t* Bp0 = BT + (size_t)(n0 + s_row) * K + g_off;
  const bf16_t* Bp1 = BT + (size_t)(n0 + 64 + s_row) * K + g_off;

  GEMM_DBUF_LOOP(K)

#pragma unroll
  for (int fi = 0; fi < 4; ++fi)
#pragma unroll
    for (int fj = 0; fj < 4; ++fj)
#pragma unroll
      for (int r = 0; r < 4; ++r) {
        const int row = m0 + wm + fi * 16 + quad * 4 + r;
        const int col = n0 + wn + fj * 16 + l15;
        C[(size_t)row * N + col] = (bf16_t)acc[fi][fj][r];
      }
}

// ---------------------------------------------------------------------------
// LayerNorm over 512 (fp32 stats), bf16 in, fp32 g/b, bf16 out into latent
// rows [2048,4096).
// ---------------------------------------------------------------------------
__global__ __launch_bounds__(256) void ln_kernel(const bf16_t* __restrict__ in,
                                                 const float* __restrict__ g_,
                                                 const float* __restrict__ b_,
                                                 bf16_t* __restrict__ latent)
{
  const int row = blockIdx.x;             // 0..4095 (= b*2048 + t)
  const int tid = threadIdx.x;
  const float x0 = (float)in[(size_t)row * 512 + tid];
  const float x1 = (float)in[(size_t)row * 512 + 256 + tid];
  float s  = x0 + x1;
  float sq = x0 * x0 + x1 * x1;
#pragma unroll
  for (int off = 1; off < 64; off <<= 1) {
    s  += __shfl_xor(s, off);
    sq += __shfl_xor(sq, off);
  }
  __shared__ float red[8];
  const int w = tid >> 6;
  if ((tid & 63) == 0) { red[w] = s; red[4 + w] = sq; }
  __syncthreads();
  s  = red[0] + red[1] + red[2] + red[3];
  sq = red[4] + red[5] + red[6] + red[7];
  const float mu   = s * (1.0f / 512.0f);
  const float var  = sq * (1.0f / 512.0f) - mu * mu;
  const float rstd = rsqrtf(var + 1e-5f);
  const int b = row >> 11, tt = row & 2047;
  bf16_t* outp = latent + ((size_t)b * 4096 + 2048 + tt) * 512;
  outp[tid]       = (bf16_t)((x0 - mu) * rstd * g_[tid]       + b_[tid]);
  outp[tid + 256] = (bf16_t)((x1 - mu) * rstd * g_[tid + 256] + b_[tid + 256]);
}

// ---------------------------------------------------------------------------
// Flash attention v7 (round-7 kernel, 237us measured, UNCHANGED).
// ---------------------------------------------------------------------------
__global__ __launch_bounds__(256) void attn7(const bf16_t* __restrict__ q,
                                             const bf16_t* __restrict__ k,
                                             const bf16_t* __restrict__ vT,
                                             bf16_t* __restrict__ out)
{
  __shared__ __align__(16) bf16_t smem[32768];      // Ks0|Ks1|Vs0|Vs1 overlay

  const int tid = threadIdx.x;
  const int lane = tid & 63, w = tid >> 6;
  const int l31 = lane & 31, h5 = lane >> 5;

  // balanced XCD mapping
  const int g = blockIdx.x & 7, j = blockIdx.x >> 3;
  const int jl = j & 31, hsel = j >> 5;
  int qt = jl & 15;
  const int b = jl >> 4;
  if (hsel) qt = 15 - qt;
  const int h = g + 8 * hsel;

  const int q0 = qt * 128;
  const int qg = q0 + l31 * 4 + w;                  // this lane's query row

  // Q^T B-frags: B[k=feat fc*16+h5*8+j][n=q l31]
  bf16x8 qf[8];
  const bf16_t* qb = q + ((size_t)(b * 2048 + qg)) * 2048 + h * 128 + h5 * 8;
#pragma unroll
  for (int fc = 0; fc < 8; ++fc) qf[fc] = *(const bf16x8*)(qb + fc * 16);

  const bf16_t* kbase = k + ((size_t)b * 4096) * 2048 + h * 128;
  const bf16_t* vbase = vT + ((size_t)(b * 16 + h)) * 128 * 4096;

  // staging maps (slot = tid + 256p)
  int ks_key[4], ks_go[4], vs_feat[4], vs_go[4];
#pragma unroll
  for (int p = 0; p < 4; ++p) {
    const int slot = tid + 256 * p;
    const int key = slot >> 4, ph = slot & 15;
    ks_key[p] = key;
    ks_go[p]  = (((ph & 8) | ((ph & 7) ^ (key & 7)))) * 8;
    const int ft = slot >> 3, p2 = slot & 7;
    vs_feat[p] = ft;
    vs_go[p]   = (p2 ^ (ft & 7)) * 8;
  }
  // frag read offsets (elems)
  int kfo[8], vfo[4];
#pragma unroll
  for (int fc = 0; fc < 8; ++fc) {
    const int L = fc * 2 + h5;
    kfo[fc] = l31 * 128 + ((L & 8) | ((L & 7) ^ (l31 & 7))) * 8;
  }
#pragma unroll
  for (int kc = 0; kc < 4; ++kc) {
    const int L = kc * 2 + h5;
    vfo[kc] = l31 * 64 + (L ^ (l31 & 7)) * 8;
  }

  f32x16 o[4] = {};
  float m = -1e30f, l = 0.f;
  const int send = 2048 + q0 + 128;

  // prologue: stage tile 0 into buffer 0
#pragma unroll
  for (int p = 0; p < 4; ++p) {
    load_lds16(kbase + (size_t)ks_key[p] * 2048 + ks_go[p],
               smem + (tid + 256 * p) * 8);
    load_lds16(vbase + (size_t)vs_feat[p] * 4096 + vs_go[p],
               smem + 16384 + (tid + 256 * p) * 8);
  }
  __syncthreads();                                  // tile 0 resident

  int cur = 0;
  for (int s0 = 0; s0 < send; s0 += 64) {
    // stage next tile into the other buffer (DMA overlaps compute below)
    const int s1 = s0 + 64;
    if (s1 < send) {
      const int nxt = (cur ^ 1) * 8192;
#pragma unroll
      for (int p = 0; p < 4; ++p) {
        load_lds16(kbase + (size_t)(s1 + ks_key[p]) * 2048 + ks_go[p],
                   smem + nxt + (tid + 256 * p) * 8);
        load_lds16(vbase + (size_t)vs_feat[p] * 4096 + s1 + vs_go[p],
                   smem + 16384 + nxt + (tid + 256 * p) * 8);
      }
    }
    const bf16_t* Kc = smem + cur * 8192;
    const bf16_t* Vc = smem + 16384 + cur * 8192;

    // S^T tiles: rows = keys 32t + (i&3)+8*(i>>2)+4*h5, col = q = l31
    f32x16 st[2] = {};
    __builtin_amdgcn_s_setprio(1);
#pragma unroll
    for (int fc = 0; fc < 8; ++fc) {
      bf16x8 k0 = *(const bf16x8*)&Kc[kfo[fc]];
      bf16x8 k1 = *(const bf16x8*)&Kc[4096 + kfo[fc]];
      st[0] = MFMA32(k0, qf[fc], st[0]);
      st[1] = MFMA32(k1, qf[fc], st[1]);
    }
    __builtin_amdgcn_s_setprio(0);

    if (s0 + 63 > 2048 + q0) {                      // causal tail masking
#pragma unroll
      for (int t = 0; t < 2; ++t)
#pragma unroll
        for (int i = 0; i < 16; ++i) {
          const int key = s0 + 32 * t + (i & 3) + 8 * (i >> 2) + 4 * h5;
          if (key > 2048 + qg) st[t][i] = -1e30f;
        }
    }

    // tree max over this lane's 32 scores (depth 5)
    float gm[8];
#pragma unroll
    for (int t = 0; t < 2; ++t)
#pragma unroll
      for (int gg = 0; gg < 4; ++gg)
        gm[t * 4 + gg] = fmaxf(fmaxf(st[t][4 * gg + 0], st[t][4 * gg + 1]),
                               fmaxf(st[t][4 * gg + 2], st[t][4 * gg + 3]));
    float mt = fmaxf(fmaxf(fmaxf(gm[0], gm[1]), fmaxf(gm[2], gm[3])),
                     fmaxf(fmaxf(gm[4], gm[5]), fmaxf(gm[6], gm[7])));
    mt = fmaxf(mt, __shfl_xor(mt, 32));

    // defer-max: only rescale when max grew by >8 (log2 domain; p <= 2^8)
    if (__any(mt > m + 8.f)) {
      const float mnew = fmaxf(m, mt);
      const float alpha = fast_exp2(m - mnew);
#pragma unroll
      for (int ft = 0; ft < 4; ++ft)
#pragma unroll
        for (int i = 0; i < 16; ++i) o[ft][i] *= alpha;
      l *= alpha;
      m = mnew;
    }

    // exp2 + pack P into u32 pairs; group g holds keys 32t + 8g + 4h5 + 0..3
    float rs = 0.f;
    unsigned up[2][4][2];
#pragma unroll
    for (int t = 0; t < 2; ++t)
#pragma unroll
      for (int gg = 0; gg < 4; ++gg) {
        const float p0 = fast_exp2(st[t][4 * gg + 0] - m);
        const float p1 = fast_exp2(st[t][4 * gg + 1] - m);
        const float p2 = fast_exp2(st[t][4 * gg + 2] - m);
        const float p3 = fast_exp2(st[t][4 * gg + 3] - m);
        rs += (p0 + p1) + (p2 + p3);
        up[t][gg][0] = pack_bf16(p0, p1);
        up[t][gg][1] = pack_bf16(p2, p3);
      }
    rs += __shfl_xor(rs, 32);
    l += rs;

    // out^T += V^T · P^T ; P^T B-frag built in-register via half-exchange
#pragma unroll
    for (int kc = 0; kc < 4; ++kc) {
      const int t = kc >> 1, gp = (kc & 1) * 2;
      const unsigned a0 = up[t][gp][0],     a1 = up[t][gp][1];
      const unsigned b0 = up[t][gp + 1][0], b1 = up[t][gp + 1][1];
      const unsigned xa0 = __shfl_xor(a0, 32), xa1 = __shfl_xor(a1, 32);
      const unsigned xb0 = __shfl_xor(b0, 32), xb1 = __shfl_xor(b1, 32);
      u32x4 uw;
      uw[0] = h5 ? xb0 : a0;
      uw[1] = h5 ? xb1 : a1;
      uw[2] = h5 ? b0 : xa0;
      uw[3] = h5 ? b1 : xa1;
      union { u32x4 u; bf16x8 v; } pc; pc.u = uw;
      const bf16x8 pf = pc.v;
      __builtin_amdgcn_s_setprio(1);
#pragma unroll
      for (int ft = 0; ft < 4; ++ft) {
        bf16x8 vf = *(const bf16x8*)&Vc[ft * 2048 + vfo[kc]];
        o[ft] = MFMA32(vf, pf, o[ft]);
      }
      __builtin_amdgcn_s_setprio(0);
    }

    __syncthreads();   // compute reads done + next-tile DMA drained
    cur ^= 1;
  }

  // epilogue: normalize, LDS transpose, coalesced store (smem overlay)
  const float inv = 1.0f / l;
  const int rowp_w = w * 32 + l31;
#pragma unroll
  for (int ft = 0; ft < 4; ++ft)
#pragma unroll
    for (int gg = 0; gg < 4; ++gg) {
      bf16x4 pk;
#pragma unroll
      for (int r = 0; r < 4; ++r) pk[r] = (bf16_t)(o[ft][4 * gg + r] * inv);
      *(bf16x4*)&smem[rowp_w * 136 + ft * 32 + gg * 8 + h5 * 4] = pk;
    }
  __syncthreads();
#pragma unroll
  for (int p = 0; p < 8; ++p) {
    const int c = tid + 256 * p;
    const int rowp = c >> 4, chk = c & 15;
    const int ql = (rowp & 31) * 4 + (rowp >> 5);
    bf16x8 d = *(const bf16x8*)&smem[rowp * 136 + chk * 8];
    *(bf16x8*)(out + ((size_t)(b * 2048 + q0 + ql)) * 2048 + h * 128 + chk * 8) = d;
  }
}

// ---------------------------------------------------------------------------
extern "C" void kernel_launch(void* const* d_in, const int* in_sizes, int n_in,
                              void* d_out, int out_size, void* d_ws, size_t ws_size,
                              hipStream_t stream)
{
  (void)in_sizes; (void)n_in; (void)out_size; (void)ws_size;
  const float* x        = (const float*)d_in[0];
  const float* lat_prev = (const float*)d_in[1];
  const float* Wq       = (const float*)d_in[2];
  const float* Wdown    = (const float*)d_in[3];
  const float* Wk_up    = (const float*)d_in[4];
  const float* Wv_up    = (const float*)d_in[5];
  const float* ln_g     = (const float*)d_in[6];
  const float* ln_b     = (const float*)d_in[7];
  const float* Wo       = (const float*)d_in[8];
  float* out = (float*)d_out;

  char* p = (char*)d_ws;
  auto alloc = [&](size_t elems) { bf16_t* r = (bf16_t*)p; p += elems * 2; return r; };
  bf16_t* xb     = alloc((size_t)4096 * 2048);
  bf16_t* WqT    = alloc((size_t)2048 * 2048);   // WqT+WdT contiguous: stacked BT
  bf16_t* WdT    = alloc((size_t)512 * 2048);
  bf16_t* qbuf   = alloc((size_t)4096 * 2048);
  bf16_t* latpre = alloc((size_t)4096 * 512);
  bf16_t* latent = alloc((size_t)2 * 4096 * 512);
  bf16_t* kbuf   = alloc((size_t)8192 * 2048);
  bf16_t* vTb    = alloc((size_t)2 * 2048 * 4096);
  bf16_t* aout   = alloc((size_t)4096 * 2048);
  bf16_t* WoT    = alloc((size_t)2048 * 2048);   // un-aliased
  bf16_t* WkT    = alloc((size_t)2048 * 512);
  bf16_t* WvT    = alloc((size_t)2048 * 512);

  const dim3 B(256);
  // 1/sqrt(128) * log2(e): attention scores land in log2 domain
  const float qscale = 0.12751744561825988f;

  // 1) all independent preprocessing in one launch
  prep_all<<<dim3(13056), B, 0, stream>>>(x, xb, Wq, WqT, Wdown, WdT,
                                          Wo, WoT, Wk_up, WkT, Wv_up, WvT,
                                          lat_prev, latent);
  // 2) fused: q = (x@Wq)*qscale ; latpre = x@Wdown
  gemm128_dual<<<dim3(20, 32), B, 0, stream>>>(xb, WqT, qbuf, latpre, qscale);
  // 3) LayerNorm -> latent rows [2048,4096)
  ln_kernel<<<dim3(4096), B, 0, stream>>>(latpre, ln_g, ln_b, latent);
  // 4) fused k + vT GEMM
  gemm_kv<<<dim3(2048), B, 0, stream>>>(latent, WkT, WvT, kbuf, vTb);
  // 5) attention (XCD-grouped, CU-pair-balanced grid) — unchanged
  attn7<<<dim3(512), B, 0, stream>>>(qbuf, kbuf, vTb, aout);
  // 6) output projection (fp32 out)
  gemm128<float><<<dim3(16, 32), B, 0, stream>>>(aout, WoT, out, 4096, 2048, 2048, 1.0f, 0, 0);
}

// Round 15
// 497.721 us; speedup vs baseline: 1.4444x; 1.0083x over previous
//
#include <hip/hip_runtime.h>
#include <hip/hip_bf16.h>

using bf16_t = __bf16;
typedef __bf16 bf16x8 __attribute__((ext_vector_type(8)));
typedef __bf16 bf16x4 __attribute__((ext_vector_type(4)));
typedef __bf16 bf16x2 __attribute__((ext_vector_type(2)));
typedef float  f32x4  __attribute__((ext_vector_type(4)));
typedef float  f32x16 __attribute__((ext_vector_type(16)));
typedef unsigned u32x4 __attribute__((ext_vector_type(4)));

#define MFMA16(a,b,c) __builtin_amdgcn_mfma_f32_16x16x32_bf16((a),(b),(c),0,0,0)
#define MFMA32(a,b,c) __builtin_amdgcn_mfma_f32_32x32x16_bf16((a),(b),(c),0,0,0)

__device__ __forceinline__ void load_lds16(const void* g, void* l) {
  __builtin_amdgcn_global_load_lds(
      (const __attribute__((address_space(1))) unsigned int*)g,
      (__attribute__((address_space(3))) unsigned int*)l, 16, 0, 0);
}

__device__ __forceinline__ unsigned pack_bf16(float a, float b) {
  union { bf16x2 v; unsigned u; } c;
  c.v[0] = (bf16_t)a; c.v[1] = (bf16_t)b;
  return c.u;
}

__device__ __forceinline__ float fast_exp2(float x) {
#if __has_builtin(__builtin_amdgcn_exp2f)
  return __builtin_amdgcn_exp2f(x);
#else
  return exp2f(x);
#endif
}

// XCD-chunked block remap (T1); exact when nwg%8==0 (all grids here).
__device__ __forceinline__ void xcd_remap(unsigned& bx, unsigned& by,
                                          unsigned& bz)
{
  const unsigned nxy = gridDim.x * gridDim.y;
  const unsigned nwg = nxy * gridDim.z;
  unsigned wg = (blockIdx.z * gridDim.y + blockIdx.y) * gridDim.x + blockIdx.x;
  if ((nwg & 7u) == 0u)
    wg = (wg & 7u) * (nwg >> 3) + (wg >> 3);
  bz = wg / nxy; wg -= bz * nxy;
  by = wg / gridDim.x;
  bx = wg - by * gridDim.x;
}

// ---------------------------------------------------------------------------
// Mega-preprocess: one launch for ALL independent prep work (round-11 proven).
// ---------------------------------------------------------------------------
__device__ __forceinline__ void transpose_body(const float* __restrict__ in,
                                               bf16_t* __restrict__ out,
                                               int R, int C, int bx, int by,
                                               int tid, bf16_t* t)
{
  const int r0 = by * 64, c0 = bx * 64;
  const int rr = tid >> 4;                  // 0..15
  const int c4 = (tid & 15) * 4;            // 0..60
#pragma unroll
  for (int i = 0; i < 4; ++i) {
    const int r = rr + i * 16;
    f32x4 d = *(const f32x4*)(in + (size_t)(r0 + r) * C + c0 + c4);
#pragma unroll
    for (int j = 0; j < 4; ++j) t[(c4 + j) * 80 + r] = (bf16_t)d[j];
  }
  __syncthreads();
  const int a  = tid >> 3;                  // 0..31
  const int bc = (tid & 7) * 8;
#pragma unroll
  for (int half = 0; half < 2; ++half) {
    const int cc = a + half * 32;
    bf16x8 d = *(const bf16x8*)&t[cc * 80 + bc];
    *(bf16x8*)(out + (size_t)(c0 + cc) * R + r0 + bc) = d;
  }
}

__global__ __launch_bounds__(256) void prep_all(
    const float* __restrict__ x,     bf16_t* __restrict__ xb,
    const float* __restrict__ Wq,    bf16_t* __restrict__ WqT,
    const float* __restrict__ Wdown, bf16_t* __restrict__ WdT,
    const float* __restrict__ Wo,    bf16_t* __restrict__ WoT,
    const float* __restrict__ Wk,    bf16_t* __restrict__ WkT,
    const float* __restrict__ Wv,    bf16_t* __restrict__ WvT,
    const float* __restrict__ prev,  bf16_t* __restrict__ latent)
{
  __shared__ __align__(16) bf16_t t[64 * 80];
  const int tid = threadIdx.x;
  const unsigned bid = blockIdx.x;
  if (bid < 8192) {
    const size_t i = ((size_t)bid * 256 + tid) * 4;
    f32x4 d = *(const f32x4*)(x + i);
    bf16x4 o;
#pragma unroll
    for (int j = 0; j < 4; ++j) o[j] = (bf16_t)d[j];
    *(bf16x4*)(xb + i) = o;
  } else if (bid < 9216) {
    const unsigned u = bid - 8192;
    transpose_body(Wq, WqT, 2048, 2048, u & 31, u >> 5, tid, t);
  } else if (bid < 9472) {
    const unsigned u = bid - 9216;
    transpose_body(Wdown, WdT, 2048, 512, u & 7, u >> 3, tid, t);
  } else if (bid < 10496) {
    const unsigned u = bid - 9472;
    transpose_body(Wo, WoT, 2048, 2048, u & 31, u >> 5, tid, t);
  } else if (bid < 10752) {
    const unsigned u = bid - 10496;
    transpose_body(Wk, WkT, 512, 2048, u & 31, u >> 5, tid, t);
  } else if (bid < 11008) {
    const unsigned u = bid - 10752;
    transpose_body(Wv, WvT, 512, 2048, u & 31, u >> 5, tid, t);
  } else {
    const size_t v    = (size_t)(bid - 11008) * 256 + tid;
    const size_t flat = v * 4;
    const size_t per  = (size_t)2048 * 512;
    const size_t b    = flat / per, rem = flat % per;
    f32x4 d = *(const f32x4*)(prev + flat);
    bf16x4 o;
#pragma unroll
    for (int j = 0; j < 4; ++j) o[j] = (bf16_t)d[j];
    *(bf16x4*)(latent + b * ((size_t)4096 * 512) + rem) = o;
  }
}

// ---------------------------------------------------------------------------
// GEMM K-loop, BK=32, DOUBLE-BUFFERED (round-14 measured config).
// ---------------------------------------------------------------------------
#define GEMM_DBUF_LOOP(Kvar)                                                  \
  f32x4 acc[4][4] = {};                                                       \
  auto stage = [&](int k0, int buf) {                                         \
    bf16_t* Ad = As + buf * 4096;                                             \
    bf16_t* Bd = Bs + buf * 4096;                                             \
    load_lds16(Ap0 + k0, Ad + tid * 8);                                       \
    load_lds16(Ap1 + k0, Ad + tid * 8 + 2048);                                \
    load_lds16(Bp0 + k0, Bd + tid * 8);                                       \
    load_lds16(Bp1 + k0, Bd + tid * 8 + 2048);                                \
  };                                                                          \
  stage(0, 0);                                                                \
  __syncthreads();                                                            \
  int cur = 0;                                                                \
  for (int k0 = 0; k0 < (Kvar); k0 += 32) {                                   \
    if (k0 + 32 < (Kvar)) stage(k0 + 32, cur ^ 1);                            \
    const bf16_t* Ac = As + cur * 4096;                                       \
    const bf16_t* Bc = Bs + cur * 4096;                                       \
    bf16x8 af[4], bfr[4];                                                     \
    _Pragma("unroll")                                                         \
    for (int fi = 0; fi < 4; ++fi)                                            \
      af[fi] = *(const bf16x8*)&Ac[(wm + fi * 16 + l15) * 32 + quadp];        \
    _Pragma("unroll")                                                         \
    for (int fj = 0; fj < 4; ++fj)                                            \
      bfr[fj] = *(const bf16x8*)&Bc[(wn + fj * 16 + l15) * 32 + quadp];       \
    _Pragma("unroll")                                                         \
    for (int fi = 0; fi < 4; ++fi)                                            \
      _Pragma("unroll")                                                       \
      for (int fj = 0; fj < 4; ++fj)                                          \
        acc[fi][fj] = MFMA16(af[fi], bfr[fj], acc[fi][fj]);                   \
    __syncthreads();                                                          \
    cur ^= 1;                                                                 \
  }

// ---------------------------------------------------------------------------
// m97-class GEMM, BK=32 double-buffered: C = A @ B (+scale), BT input.
// ---------------------------------------------------------------------------
template <typename OutT>
__global__ __launch_bounds__(256) void gemm128(const bf16_t* __restrict__ A,
                                               const bf16_t* __restrict__ BT,
                                               OutT* __restrict__ C,
                                               int M, int N, int K, float scale,
                                               long long zB, long long zC)
{
  __shared__ __align__(16) bf16_t As[2 * 128 * 32];
  __shared__ __align__(16) bf16_t Bs[2 * 128 * 32];
  const int tid = threadIdx.x;
  unsigned bx, by, bz;
  xcd_remap(bx, by, bz);
  BT += (size_t)bz * zB;
  C  += (size_t)bz * zC;
  const int m0 = by * 128, n0 = bx * 128;
  const int lane = tid & 63, w = tid >> 6;
  const int quad = lane >> 4, l15 = lane & 15;
  const int wm = (w >> 1) * 64, wn = (w & 1) * 64;
  const int s_row = tid >> 2;
  const int g_off = ((tid & 3) ^ (s_row & 3)) * 8;
  const int quadp = (quad ^ (l15 & 3)) * 8;
  const bf16_t* Ap0 = A  + (size_t)(m0 + s_row) * K + g_off;
  const bf16_t* Ap1 = A  + (size_t)(m0 + 64 + s_row) * K + g_off;
  const bf16_t* Bp0 = BT + (size_t)(n0 + s_row) * K + g_off;
  const bf16_t* Bp1 = BT + (size_t)(n0 + 64 + s_row) * K + g_off;

  GEMM_DBUF_LOOP(K)

#pragma unroll
  for (int fi = 0; fi < 4; ++fi)
#pragma unroll
    for (int fj = 0; fj < 4; ++fj)
#pragma unroll
      for (int r = 0; r < 4; ++r) {
        const int row = m0 + wm + fi * 16 + quad * 4 + r;
        const int col = n0 + wn + fj * 16 + l15;
        C[(size_t)row * N + col] = (OutT)(acc[fi][fj][r] * scale);
      }
}

// ---------------------------------------------------------------------------
// Fused q + latpre GEMM, BK=32 double-buffered: A @ [WqT;WdT] stacked.
// ---------------------------------------------------------------------------
__global__ __launch_bounds__(256) void gemm128_dual(const bf16_t* __restrict__ A,
                                                    const bf16_t* __restrict__ BT,
                                                    bf16_t* __restrict__ C1,
                                                    bf16_t* __restrict__ C2,
                                                    float qscale)
{
  __shared__ __align__(16) bf16_t As[2 * 128 * 32];
  __shared__ __align__(16) bf16_t Bs[2 * 128 * 32];
  const int tid = threadIdx.x;
  unsigned bx, by, bz;
  xcd_remap(bx, by, bz);
  const int K = 2048;
  const int m0 = by * 128, n0 = bx * 128;
  const int lane = tid & 63, w = tid >> 6;
  const int quad = lane >> 4, l15 = lane & 15;
  const int wm = (w >> 1) * 64, wn = (w & 1) * 64;
  const int s_row = tid >> 2;
  const int g_off = ((tid & 3) ^ (s_row & 3)) * 8;
  const int quadp = (quad ^ (l15 & 3)) * 8;
  const bf16_t* Ap0 = A  + (size_t)(m0 + s_row) * K + g_off;
  const bf16_t* Ap1 = A  + (size_t)(m0 + 64 + s_row) * K + g_off;
  const bf16_t* Bp0 = BT + (size_t)(n0 + s_row) * K + g_off;
  const bf16_t* Bp1 = BT + (size_t)(n0 + 64 + s_row) * K + g_off;

  GEMM_DBUF_LOOP(K)

  const bool isQ = (n0 < 2048);            // block-uniform
  const float sc = isQ ? qscale : 1.0f;
#pragma unroll
  for (int fi = 0; fi < 4; ++fi)
#pragma unroll
    for (int fj = 0; fj < 4; ++fj)
#pragma unroll
      for (int r = 0; r < 4; ++r) {
        const int row = m0 + wm + fi * 16 + quad * 4 + r;
        const int col = n0 + wn + fj * 16 + l15;
        if (isQ)
          C1[(size_t)row * 2048 + col] = (bf16_t)(acc[fi][fj][r] * sc);
        else
          C2[(size_t)row * 512 + (col - 2048)] = (bf16_t)(acc[fi][fj][r] * sc);
      }
}

// ---------------------------------------------------------------------------
// Fused k + vT GEMM, BK=32 double-buffered (both read latent, K=512).
// ---------------------------------------------------------------------------
__global__ __launch_bounds__(256) void gemm_kv(const bf16_t* __restrict__ latent,
                                               const bf16_t* __restrict__ WkT,
                                               const bf16_t* __restrict__ WvT,
                                               bf16_t* __restrict__ kbuf,
                                               bf16_t* __restrict__ vTb)
{
  __shared__ __align__(16) bf16_t As[2 * 128 * 32];
  __shared__ __align__(16) bf16_t Bs[2 * 128 * 32];
  const int tid = threadIdx.x;
  unsigned wg = blockIdx.x;                 // 2048 blocks
  wg = (wg & 7u) * 256u + (wg >> 3);        // XCD-chunked remap
  const bf16_t *A, *BT;
  bf16_t* C;
  int N;
  unsigned bx, by;
  if (wg < 1024) {                          // k GEMM
    bx = wg & 15; by = wg >> 4;
    A = latent; BT = WkT; C = kbuf; N = 2048;
  } else {
    const unsigned t2 = wg - 1024;
    const unsigned bz = t2 >> 9, rem = t2 & 511;
    bx = rem & 31; by = rem >> 5;
    A  = WvT;
    BT = latent + (size_t)bz * ((size_t)4096 * 512);
    C  = vTb + (size_t)bz * ((size_t)2048 * 4096);
    N = 4096;
  }
  const int K = 512;
  const int m0 = by * 128, n0 = bx * 128;
  const int lane = tid & 63, w = tid >> 6;
  const int quad = lane >> 4, l15 = lane & 15;
  const int wm = (w >> 1) * 64, wn = (w & 1) * 64;
  const int s_row = tid >> 2;
  const int g_off = ((tid & 3) ^ (s_row & 3)) * 8;
  const int quadp = (quad ^ (l15 & 3)) * 8;
  const bf16_t* Ap0 = A  + (size_t)(m0 + s_row) * K + g_off;
  const bf16_t* Ap1 = A  + (size_t)(m0 + 64 + s_row) * K + g_off;
  const bf16_t* Bp0 = BT + (size_t)(n0 + s_row) * K + g_off;
  const bf16_t* Bp1 = BT + (size_t)(n0 + 64 + s_row) * K + g_off;

  GEMM_DBUF_LOOP(K)

#pragma unroll
  for (int fi = 0; fi < 4; ++fi)
#pragma unroll
    for (int fj = 0; fj < 4; ++fj)
#pragma unroll
      for (int r = 0; r < 4; ++r) {
        const int row = m0 + wm + fi * 16 + quad * 4 + r;
        const int col = n0 + wn + fj * 16 + l15;
        C[(size_t)row * N + col] = (bf16_t)acc[fi][fj][r];
      }
}

// ---------------------------------------------------------------------------
// LayerNorm over 512 (fp32 stats), bf16 in, fp32 g/b, bf16 out into latent
// rows [2048,4096).
// ---------------------------------------------------------------------------
__global__ __launch_bounds__(256) void ln_kernel(const bf16_t* __restrict__ in,
                                                 const float* __restrict__ g_,
                                                 const float* __restrict__ b_,
                                                 bf16_t* __restrict__ latent)
{
  const int row = blockIdx.x;             // 0..4095 (= b*2048 + t)
  const int tid = threadIdx.x;
  const float x0 = (float)in[(size_t)row * 512 + tid];
  const float x1 = (float)in[(size_t)row * 512 + 256 + tid];
  float s  = x0 + x1;
  float sq = x0 * x0 + x1 * x1;
#pragma unroll
  for (int off = 1; off < 64; off <<= 1) {
    s  += __shfl_xor(s, off);
    sq += __shfl_xor(sq, off);
  }
  __shared__ float red[8];
  const int w = tid >> 6;
  if ((tid & 63) == 0) { red[w] = s; red[4 + w] = sq; }
  __syncthreads();
  s  = red[0] + red[1] + red[2] + red[3];
  sq = red[4] + red[5] + red[6] + red[7];
  const float mu   = s * (1.0f / 512.0f);
  const float var  = sq * (1.0f / 512.0f) - mu * mu;
  const float rstd = rsqrtf(var + 1e-5f);
  const int b = row >> 11, tt = row & 2047;
  bf16_t* outp = latent + ((size_t)b * 4096 + 2048 + tt) * 512;
  outp[tid]       = (bf16_t)((x0 - mu) * rstd * g_[tid]       + b_[tid]);
  outp[tid + 256] = (bf16_t)((x1 - mu) * rstd * g_[tid + 256] + b_[tid + 256]);
}

// ---------------------------------------------------------------------------
// Flash attention v8 = attn7 with the PV P-build exchange reduced from
// 4 shfl_xor to 2 per kc (pre-select what the partner half needs, exchange
// once, select into place — bit-exact vs the proven 4-shfl path):
//   lo lane wants [a0,a1, a0_hi,a1_hi]; hi lane wants [b0_lo,b1_lo, b0,b1]
//   sel = h5 ? a : b ; t = shfl_xor(sel, 32)
//   lo: t = a_hi ; hi: t = b_lo  -> 2 bpermutes instead of 4.
// Everything else identical to the 237-240us measured attn7.
// ---------------------------------------------------------------------------
__global__ __launch_bounds__(256) void attn8(const bf16_t* __restrict__ q,
                                             const bf16_t* __restrict__ k,
                                             const bf16_t* __restrict__ vT,
                                             bf16_t* __restrict__ out)
{
  __shared__ __align__(16) bf16_t smem[32768];      // Ks0|Ks1|Vs0|Vs1 overlay

  const int tid = threadIdx.x;
  const int lane = tid & 63, w = tid >> 6;
  const int l31 = lane & 31, h5 = lane >> 5;

  // balanced XCD mapping
  const int g = blockIdx.x & 7, j = blockIdx.x >> 3;
  const int jl = j & 31, hsel = j >> 5;
  int qt = jl & 15;
  const int b = jl >> 4;
  if (hsel) qt = 15 - qt;
  const int h = g + 8 * hsel;

  const int q0 = qt * 128;
  const int qg = q0 + l31 * 4 + w;                  // this lane's query row

  // Q^T B-frags: B[k=feat fc*16+h5*8+j][n=q l31]
  bf16x8 qf[8];
  const bf16_t* qb = q + ((size_t)(b * 2048 + qg)) * 2048 + h * 128 + h5 * 8;
#pragma unroll
  for (int fc = 0; fc < 8; ++fc) qf[fc] = *(const bf16x8*)(qb + fc * 16);

  const bf16_t* kbase = k + ((size_t)b * 4096) * 2048 + h * 128;
  const bf16_t* vbase = vT + ((size_t)(b * 16 + h)) * 128 * 4096;

  // staging maps (slot = tid + 256p)
  int ks_key[4], ks_go[4], vs_feat[4], vs_go[4];
#pragma unroll
  for (int p = 0; p < 4; ++p) {
    const int slot = tid + 256 * p;
    const int key = slot >> 4, ph = slot & 15;
    ks_key[p] = key;
    ks_go[p]  = (((ph & 8) | ((ph & 7) ^ (key & 7)))) * 8;
    const int ft = slot >> 3, p2 = slot & 7;
    vs_feat[p] = ft;
    vs_go[p]   = (p2 ^ (ft & 7)) * 8;
  }
  // frag read offsets (elems)
  int kfo[8], vfo[4];
#pragma unroll
  for (int fc = 0; fc < 8; ++fc) {
    const int L = fc * 2 + h5;
    kfo[fc] = l31 * 128 + ((L & 8) | ((L & 7) ^ (l31 & 7))) * 8;
  }
#pragma unroll
  for (int kc = 0; kc < 4; ++kc) {
    const int L = kc * 2 + h5;
    vfo[kc] = l31 * 64 + (L ^ (l31 & 7)) * 8;
  }

  f32x16 o[4] = {};
  float m = -1e30f, l = 0.f;
  const int send = 2048 + q0 + 128;

  // prologue: stage tile 0 into buffer 0
#pragma unroll
  for (int p = 0; p < 4; ++p) {
    load_lds16(kbase + (size_t)ks_key[p] * 2048 + ks_go[p],
               smem + (tid + 256 * p) * 8);
    load_lds16(vbase + (size_t)vs_feat[p] * 4096 + vs_go[p],
               smem + 16384 + (tid + 256 * p) * 8);
  }
  __syncthreads();                                  // tile 0 resident

  int cur = 0;
  for (int s0 = 0; s0 < send; s0 += 64) {
    // stage next tile into the other buffer (DMA overlaps compute below)
    const int s1 = s0 + 64;
    if (s1 < send) {
      const int nxt = (cur ^ 1) * 8192;
#pragma unroll
      for (int p = 0; p < 4; ++p) {
        load_lds16(kbase + (size_t)(s1 + ks_key[p]) * 2048 + ks_go[p],
                   smem + nxt + (tid + 256 * p) * 8);
        load_lds16(vbase + (size_t)vs_feat[p] * 4096 + s1 + vs_go[p],
                   smem + 16384 + nxt + (tid + 256 * p) * 8);
      }
    }
    const bf16_t* Kc = smem + cur * 8192;
    const bf16_t* Vc = smem + 16384 + cur * 8192;

    // S^T tiles: rows = keys 32t + (i&3)+8*(i>>2)+4*h5, col = q = l31
    f32x16 st[2] = {};
    __builtin_amdgcn_s_setprio(1);
#pragma unroll
    for (int fc = 0; fc < 8; ++fc) {
      bf16x8 k0 = *(const bf16x8*)&Kc[kfo[fc]];
      bf16x8 k1 = *(const bf16x8*)&Kc[4096 + kfo[fc]];
      st[0] = MFMA32(k0, qf[fc], st[0]);
      st[1] = MFMA32(k1, qf[fc], st[1]);
    }
    __builtin_amdgcn_s_setprio(0);

    if (s0 + 63 > 2048 + q0) {                      // causal tail masking
#pragma unroll
      for (int t = 0; t < 2; ++t)
#pragma unroll
        for (int i = 0; i < 16; ++i) {
          const int key = s0 + 32 * t + (i & 3) + 8 * (i >> 2) + 4 * h5;
          if (key > 2048 + qg) st[t][i] = -1e30f;
        }
    }

    // tree max over this lane's 32 scores (depth 5)
    float gm[8];
#pragma unroll
    for (int t = 0; t < 2; ++t)
#pragma unroll
      for (int gg = 0; gg < 4; ++gg)
        gm[t * 4 + gg] = fmaxf(fmaxf(st[t][4 * gg + 0], st[t][4 * gg + 1]),
                               fmaxf(st[t][4 * gg + 2], st[t][4 * gg + 3]));
    float mt = fmaxf(fmaxf(fmaxf(gm[0], gm[1]), fmaxf(gm[2], gm[3])),
                     fmaxf(fmaxf(gm[4], gm[5]), fmaxf(gm[6], gm[7])));
    mt = fmaxf(mt, __shfl_xor(mt, 32));

    // defer-max: only rescale when max grew by >8 (log2 domain; p <= 2^8)
    if (__any(mt > m + 8.f)) {
      const float mnew = fmaxf(m, mt);
      const float alpha = fast_exp2(m - mnew);
#pragma unroll
      for (int ft = 0; ft < 4; ++ft)
#pragma unroll
        for (int i = 0; i < 16; ++i) o[ft][i] *= alpha;
      l *= alpha;
      m = mnew;
    }

    // exp2 + pack P into u32 pairs; group g holds keys 32t + 8g + 4h5 + 0..3
    float rs = 0.f;
    unsigned up[2][4][2];
#pragma unroll
    for (int t = 0; t < 2; ++t)
#pragma unroll
      for (int gg = 0; gg < 4; ++gg) {
        const float p0 = fast_exp2(st[t][4 * gg + 0] - m);
        const float p1 = fast_exp2(st[t][4 * gg + 1] - m);
        const float p2 = fast_exp2(st[t][4 * gg + 2] - m);
        const float p3 = fast_exp2(st[t][4 * gg + 3] - m);
        rs += (p0 + p1) + (p2 + p3);
        up[t][gg][0] = pack_bf16(p0, p1);
        up[t][gg][1] = pack_bf16(p2, p3);
      }
    rs += __shfl_xor(rs, 32);
    l += rs;

    // out^T += V^T · P^T ; P^T B-frag via 2-shfl half-exchange (see header)
#pragma unroll
    for (int kc = 0; kc < 4; ++kc) {
      const int t = kc >> 1, gp = (kc & 1) * 2;
      const unsigned a0 = up[t][gp][0],     a1 = up[t][gp][1];
      const unsigned b0 = up[t][gp + 1][0], b1 = up[t][gp + 1][1];
      const unsigned sel0 = h5 ? a0 : b0;        // value partner half needs
      const unsigned sel1 = h5 ? a1 : b1;
      const unsigned t0 = __shfl_xor(sel0, 32);  // lo: a0_hi ; hi: b0_lo
      const unsigned t1 = __shfl_xor(sel1, 32);  // lo: a1_hi ; hi: b1_lo
      u32x4 uw;
      uw[0] = h5 ? t0 : a0;
      uw[1] = h5 ? t1 : a1;
      uw[2] = h5 ? b0 : t0;
      uw[3] = h5 ? b1 : t1;
      union { u32x4 u; bf16x8 v; } pc; pc.u = uw;
      const bf16x8 pf = pc.v;
      __builtin_amdgcn_s_setprio(1);
#pragma unroll
      for (int ft = 0; ft < 4; ++ft) {
        bf16x8 vf = *(const bf16x8*)&Vc[ft * 2048 + vfo[kc]];
        o[ft] = MFMA32(vf, pf, o[ft]);
      }
      __builtin_amdgcn_s_setprio(0);
    }

    __syncthreads();   // compute reads done + next-tile DMA drained
    cur ^= 1;
  }

  // epilogue: normalize, LDS transpose, coalesced store (smem overlay)
  const float inv = 1.0f / l;
  const int rowp_w = w * 32 + l31;
#pragma unroll
  for (int ft = 0; ft < 4; ++ft)
#pragma unroll
    for (int gg = 0; gg < 4; ++gg) {
      bf16x4 pk;
#pragma unroll
      for (int r = 0; r < 4; ++r) pk[r] = (bf16_t)(o[ft][4 * gg + r] * inv);
      *(bf16x4*)&smem[rowp_w * 136 + ft * 32 + gg * 8 + h5 * 4] = pk;
    }
  __syncthreads();
#pragma unroll
  for (int p = 0; p < 8; ++p) {
    const int c = tid + 256 * p;
    const int rowp = c >> 4, chk = c & 15;
    const int ql = (rowp & 31) * 4 + (rowp >> 5);
    bf16x8 d = *(const bf16x8*)&smem[rowp * 136 + chk * 8];
    *(bf16x8*)(out + ((size_t)(b * 2048 + q0 + ql)) * 2048 + h * 128 + chk * 8) = d;
  }
}

// ---------------------------------------------------------------------------
extern "C" void kernel_launch(void* const* d_in, const int* in_sizes, int n_in,
                              void* d_out, int out_size, void* d_ws, size_t ws_size,
                              hipStream_t stream)
{
  (void)in_sizes; (void)n_in; (void)out_size; (void)ws_size;
  const float* x        = (const float*)d_in[0];
  const float* lat_prev = (const float*)d_in[1];
  const float* Wq       = (const float*)d_in[2];
  const float* Wdown    = (const float*)d_in[3];
  const float* Wk_up    = (const float*)d_in[4];
  const float* Wv_up    = (const float*)d_in[5];
  const float* ln_g     = (const float*)d_in[6];
  const float* ln_b     = (const float*)d_in[7];
  const float* Wo       = (const float*)d_in[8];
  float* out = (float*)d_out;

  char* p = (char*)d_ws;
  auto alloc = [&](size_t elems) { bf16_t* r = (bf16_t*)p; p += elems * 2; return r; };
  bf16_t* xb     = alloc((size_t)4096 * 2048);
  bf16_t* WqT    = alloc((size_t)2048 * 2048);   // WqT+WdT contiguous: stacked BT
  bf16_t* WdT    = alloc((size_t)512 * 2048);
  bf16_t* qbuf   = alloc((size_t)4096 * 2048);
  bf16_t* latpre = alloc((size_t)4096 * 512);
  bf16_t* latent = alloc((size_t)2 * 4096 * 512);
  bf16_t* kbuf   = alloc((size_t)8192 * 2048);
  bf16_t* vTb    = alloc((size_t)2 * 2048 * 4096);
  bf16_t* aout   = alloc((size_t)4096 * 2048);
  bf16_t* WoT    = alloc((size_t)2048 * 2048);   // un-aliased
  bf16_t* WkT    = alloc((size_t)2048 * 512);
  bf16_t* WvT    = alloc((size_t)2048 * 512);

  const dim3 B(256);
  // 1/sqrt(128) * log2(e): attention scores land in log2 domain
  const float qscale = 0.12751744561825988f;

  // 1) all independent preprocessing in one launch
  prep_all<<<dim3(13056), B, 0, stream>>>(x, xb, Wq, WqT, Wdown, WdT,
                                          Wo, WoT, Wk_up, WkT, Wv_up, WvT,
                                          lat_prev, latent);
  // 2) fused: q = (x@Wq)*qscale ; latpre = x@Wdown
  gemm128_dual<<<dim3(20, 32), B, 0, stream>>>(xb, WqT, qbuf, latpre, qscale);
  // 3) LayerNorm -> latent rows [2048,4096)
  ln_kernel<<<dim3(4096), B, 0, stream>>>(latpre, ln_g, ln_b, latent);
  // 4) fused k + vT GEMM
  gemm_kv<<<dim3(2048), B, 0, stream>>>(latent, WkT, WvT, kbuf, vTb);
  // 5) attention (XCD-grouped grid, 2-shfl P-build)
  attn8<<<dim3(512), B, 0, stream>>>(qbuf, kbuf, vTb, aout);
  // 6) output projection (fp32 out)
  gemm128<float><<<dim3(16, 32), B, 0, stream>>>(aout, WoT, out, 4096, 2048, 2048, 1.0f, 0, 0);
}